// Round 1
// baseline (2270.322 us; speedup 1.0000x reference)
//
#include <hip/hip_runtime.h>
#include <cstdint>
#include <cstddef>

// ---------------------------------------------------------------------------
// GSF-DTA forward: 2x GCNConv (protein), 2x GCNConv (drug), 2 seq MLPs, head.
// CSR-by-dst built on device once per graph (shared by both conv layers);
// aggregation is gather-based (deterministic per-node sum, no f32 atomics).
// ---------------------------------------------------------------------------

#define SCAN_T 256
#define SCAN_E 2048   // elements per scan block (8 per thread)

__global__ void deg_count(const int* __restrict__ dst, int E, int* __restrict__ cnt) {
    int e = blockIdx.x * blockDim.x + threadIdx.x;
    int stride = gridDim.x * blockDim.x;
    for (; e < E; e += stride) atomicAdd(&cnt[dst[e]], 1);
}

__global__ void dinv_k(const int* __restrict__ cnt, float* __restrict__ dinv, int n) {
    int i = blockIdx.x * blockDim.x + threadIdx.x;
    if (i < n) dinv[i] = rsqrtf((float)(cnt[i] + 1));   // +1 self-loop; always > 0
}

__global__ void scan_block_sums(const int* __restrict__ cnt, int n, int* __restrict__ bsum) {
    int b = blockIdx.x, t = threadIdx.x;
    int base = b * SCAN_E;
    int s = 0;
    for (int i = t; i < SCAN_E; i += SCAN_T) {
        int idx = base + i;
        if (idx < n) s += cnt[idx];
    }
    __shared__ int sh[SCAN_T];
    sh[t] = s; __syncthreads();
    for (int off = SCAN_T / 2; off > 0; off >>= 1) {
        if (t < off) sh[t] += sh[t + off];
        __syncthreads();
    }
    if (t == 0) bsum[b] = sh[0];
}

__global__ void scan_offsets(int* __restrict__ bsum, int nblk, int* __restrict__ rowptr, int n) {
    // single thread: exclusive scan of block sums (<=64 blocks), in place
    int run = 0;
    for (int i = 0; i < nblk; ++i) { int v = bsum[i]; bsum[i] = run; run += v; }
    rowptr[n] = run;   // == E
}

__global__ void scan_write(const int* __restrict__ cnt, int n,
                           const int* __restrict__ boff, int* __restrict__ rowptr) {
    int b = blockIdx.x, t = threadIdx.x;
    int base = b * SCAN_E + t * 8;
    int v[8]; int tot = 0;
    #pragma unroll
    for (int j = 0; j < 8; ++j) {
        int idx = base + j;
        v[j] = (idx < n) ? cnt[idx] : 0;
        tot += v[j];
    }
    __shared__ int sh[SCAN_T];
    sh[t] = tot; __syncthreads();
    // inclusive Hillis-Steele over thread totals
    for (int off = 1; off < SCAN_T; off <<= 1) {
        int add = (t >= off) ? sh[t - off] : 0;
        __syncthreads();
        sh[t] += add;
        __syncthreads();
    }
    int excl = sh[t] - tot + boff[b];
    #pragma unroll
    for (int j = 0; j < 8; ++j) {
        int idx = base + j;
        if (idx < n) rowptr[idx] = excl;
        excl += v[j];
    }
}

__global__ void scatter_edges(const int* __restrict__ src, const int* __restrict__ dst, int E,
                              const int* __restrict__ rowptr, int* __restrict__ cursor,
                              int* __restrict__ col) {
    int e = blockIdx.x * blockDim.x + threadIdx.x;
    int stride = gridDim.x * blockDim.x;
    for (; e < E; e += stride) {
        int d = dst[e];
        int p = atomicAdd(&cursor[d], 1);
        col[rowptr[d] + p] = src[e];
    }
}

// out[n,128] = x[n,IN] @ W[IN,128]   (W staged in LDS; 64 rows per block)
template <int IN>
__global__ __launch_bounds__(256) void xw_matmul(const float* __restrict__ x,
                                                 const float* __restrict__ W,
                                                 float* __restrict__ out, int n) {
    __shared__ float Wl[IN * 128];
    __shared__ float xl[16 * IN];
    const int tid = threadIdx.x;
    for (int i = tid; i < IN * 128; i += 256) Wl[i] = W[i];

    const int tx = tid & 15;     // 16 column groups of 8
    const int ty = tid >> 4;     // 16 rows per tile
    const int c0 = tx * 8;
    int r0 = blockIdx.x * 64;

    for (int rt = 0; rt < 4; ++rt, r0 += 16) {
        __syncthreads();   // W ready (first iter) / xl safe to overwrite
        for (int i = tid; i < 16 * IN; i += 256) {
            int rr = i / IN, kk = i - rr * IN;
            int row = r0 + rr;
            xl[rr * IN + kk] = (row < n) ? x[(size_t)row * IN + kk] : 0.f;
        }
        __syncthreads();
        float acc[8];
        #pragma unroll
        for (int j = 0; j < 8; ++j) acc[j] = 0.f;
        const float* xrow = &xl[ty * IN];
        #pragma unroll 8
        for (int k = 0; k < IN; ++k) {
            float xv = xrow[k];
            const float4 w0 = *(const float4*)&Wl[k * 128 + c0];
            const float4 w1 = *(const float4*)&Wl[k * 128 + c0 + 4];
            acc[0] = fmaf(xv, w0.x, acc[0]);
            acc[1] = fmaf(xv, w0.y, acc[1]);
            acc[2] = fmaf(xv, w0.z, acc[2]);
            acc[3] = fmaf(xv, w0.w, acc[3]);
            acc[4] = fmaf(xv, w1.x, acc[4]);
            acc[5] = fmaf(xv, w1.y, acc[5]);
            acc[6] = fmaf(xv, w1.z, acc[6]);
            acc[7] = fmaf(xv, w1.w, acc[7]);
        }
        int row = r0 + ty;
        if (row < n) {
            float4* o = (float4*)&out[(size_t)row * 128 + c0];
            o[0] = make_float4(acc[0], acc[1], acc[2], acc[3]);
            o[1] = make_float4(acc[4], acc[5], acc[6], acc[7]);
        }
    }
}

// one node per 128-thread block; thread = feature.
// out[d,t] = relu( dinv[d]*( sum_e dinv[src]*xw[src,t] + dinv[d]*xw[d,t] ) + b[t] )
__global__ __launch_bounds__(128) void gcn_agg(const float* __restrict__ xw,
                                               const int* __restrict__ rowptr,
                                               const int* __restrict__ col,
                                               const float* __restrict__ dinv,
                                               const float* __restrict__ bias,
                                               float* __restrict__ out) {
    const int d = blockIdx.x;
    const int t = threadIdx.x;
    __shared__ int   cs[128];
    __shared__ float wsh[128];
    const int beg = rowptr[d], end = rowptr[d + 1];
    const float dv = dinv[d];
    float acc = dv * xw[(size_t)d * 128 + t];   // self-loop term (pre dv scale)
    for (int base = beg; base < end; base += 128) {
        int m = end - base; if (m > 128) m = 128;
        if (t < m) {
            int s = col[base + t];
            cs[t] = s;
            wsh[t] = dinv[s];
        }
        __syncthreads();
        #pragma unroll 4
        for (int j = 0; j < m; ++j)
            acc = fmaf(wsh[j], xw[(size_t)cs[j] * 128 + t], acc);
        __syncthreads();
    }
    float r = fmaf(dv, acc, bias[t]);
    out[(size_t)d * 128 + t] = fmaxf(r, 0.f);
}

__global__ void mean_partial(const float* __restrict__ h, int n, float* __restrict__ partial) {
    int t = threadIdx.x;           // 128
    int b = blockIdx.x;
    float s = 0.f;
    for (int r = b; r < n; r += gridDim.x) s += h[(size_t)r * 128 + t];
    partial[b * 128 + t] = s;
}

__global__ void mean_finish(const float* __restrict__ partial, int nb, float inv_n,
                            float* __restrict__ out) {
    int t = threadIdx.x;           // 128
    float s = 0.f;
    for (int i = 0; i < nb; ++i) s += partial[i * 128 + t];
    out[t] = s * inv_n;
}

__global__ void seq_mlp(const float* __restrict__ seq, int IN,
                        const float* __restrict__ w1, const float* __restrict__ b1,
                        const float* __restrict__ w2, const float* __restrict__ b2,
                        float* __restrict__ out) {
    int t = threadIdx.x;           // 128
    __shared__ float h[128];
    float acc = 0.f;
    for (int k = 0; k < IN; ++k) acc = fmaf(seq[k], w1[k * 128 + t], acc);
    h[t] = fmaxf(acc + b1[t], 0.f);
    __syncthreads();
    float acc2 = 0.f;
    #pragma unroll 8
    for (int k = 0; k < 128; ++k) acc2 = fmaf(h[k], w2[k * 128 + t], acc2);
    out[t] = fmaxf(acc2 + b2[t], 0.f);
}

__global__ void head_mlp(const float* __restrict__ pm, const float* __restrict__ dm,
                         const float* __restrict__ ps, const float* __restrict__ ds2,
                         const float* __restrict__ fc1w, const float* __restrict__ fc1b,
                         const float* __restrict__ fc2w, const float* __restrict__ fc2b,
                         float* __restrict__ out) {
    int t = threadIdx.x;           // 128
    __shared__ float comb[512];
    __shared__ float red[128];
    comb[t]       = pm[t];
    comb[128 + t] = dm[t];
    comb[256 + t] = ps[t];
    comb[384 + t] = ds2[t];
    __syncthreads();
    float acc = 0.f;
    #pragma unroll 8
    for (int k = 0; k < 512; ++k) acc = fmaf(comb[k], fc1w[k * 128 + t], acc);
    float h = fmaxf(acc + fc1b[t], 0.f);
    red[t] = h * fc2w[t];
    __syncthreads();
    for (int off = 64; off > 0; off >>= 1) {
        if (t < off) red[t] += red[t + off];
        __syncthreads();
    }
    if (t == 0) out[0] = red[0] + fc2b[0];
}

static inline size_t align_up(size_t x, size_t a) { return (x + a - 1) / a * a; }

extern "C" void kernel_launch(void* const* d_in, const int* in_sizes, int n_in,
                              void* d_out, int out_size, void* d_ws, size_t ws_size,
                              hipStream_t stream) {
    const float* px   = (const float*)d_in[0];
    const int*   pei  = (const int*)d_in[1];
    const float* dx   = (const float*)d_in[2];
    const int*   dei  = (const int*)d_in[3];
    const float* pseq = (const float*)d_in[4];
    const float* dseq = (const float*)d_in[5];
    const float* pc1w = (const float*)d_in[6];  const float* pc1b = (const float*)d_in[7];
    const float* pc2w = (const float*)d_in[8];  const float* pc2b = (const float*)d_in[9];
    const float* dc1w = (const float*)d_in[10]; const float* dc1b = (const float*)d_in[11];
    const float* dc2w = (const float*)d_in[12]; const float* dc2b = (const float*)d_in[13];
    const float* psw1 = (const float*)d_in[14]; const float* psb1 = (const float*)d_in[15];
    const float* psw2 = (const float*)d_in[16]; const float* psb2 = (const float*)d_in[17];
    const float* dsw1 = (const float*)d_in[18]; const float* dsb1 = (const float*)d_in[19];
    const float* dsw2 = (const float*)d_in[20]; const float* dsb2 = (const float*)d_in[21];
    const float* fc1w = (const float*)d_in[22]; const float* fc1b = (const float*)d_in[23];
    const float* fc2w = (const float*)d_in[24]; const float* fc2b = (const float*)d_in[25];

    const int Np = in_sizes[0] / 128, Ep = in_sizes[1] / 2;
    const int Nd = in_sizes[2] / 64,  Ed = in_sizes[3] / 2;
    const int Psd = in_sizes[4], Dsd = in_sizes[5];

    char* w = (char*)d_ws;
    size_t off = 0;
    auto carve = [&](size_t bytes) -> void* {
        void* p = w + off;
        off = align_up(off + bytes, 256);
        return p;
    };
    float* bufA    = (float*)carve((size_t)Np * 128 * 4);
    float* bufB    = (float*)carve((size_t)Np * 128 * 4);
    int*   col     = (int*)carve((size_t)Ep * 4);
    int*   rowptr  = (int*)carve(((size_t)Np + 1) * 4);
    int*   cnt     = (int*)carve((size_t)Np * 4);
    int*   cursor  = (int*)carve((size_t)Np * 4);
    float* dinv    = (float*)carve((size_t)Np * 4);
    int*   bsum    = (int*)carve(4096);
    float* partial = (float*)carve((size_t)512 * 128 * 4);
    float* pmean   = (float*)carve(512);
    float* dmean   = (float*)carve(512);
    float* pseqo   = (float*)carve(512);
    float* dseqo   = (float*)carve(512);
    (void)ws_size; (void)n_in; (void)out_size;

    auto run_gcn = [&](const float* x, const int* ei, int n, int E, int IN,
                       const float* W1, const float* b1,
                       const float* W2, const float* b2, float* meano) {
        const int* srcp = ei;
        const int* dstp = ei + E;
        int nbE = (E + 255) / 256; if (nbE > 4096) nbE = 4096;
        int nblk = (n + SCAN_E - 1) / SCAN_E;

        hipMemsetAsync(cnt, 0, (size_t)n * 4, stream);
        deg_count<<<nbE, 256, 0, stream>>>(dstp, E, cnt);
        dinv_k<<<(n + 255) / 256, 256, 0, stream>>>(cnt, dinv, n);
        scan_block_sums<<<nblk, SCAN_T, 0, stream>>>(cnt, n, bsum);
        scan_offsets<<<1, 1, 0, stream>>>(bsum, nblk, rowptr, n);
        scan_write<<<nblk, SCAN_T, 0, stream>>>(cnt, n, bsum, rowptr);
        hipMemsetAsync(cursor, 0, (size_t)n * 4, stream);
        scatter_edges<<<nbE, 256, 0, stream>>>(srcp, dstp, E, rowptr, cursor, col);

        // conv1
        if (IN == 128) xw_matmul<128><<<(n + 63) / 64, 256, 0, stream>>>(x, W1, bufA, n);
        else           xw_matmul<64><<<(n + 63) / 64, 256, 0, stream>>>(x, W1, bufA, n);
        gcn_agg<<<n, 128, 0, stream>>>(bufA, rowptr, col, dinv, b1, bufB);
        // conv2
        xw_matmul<128><<<(n + 63) / 64, 256, 0, stream>>>(bufB, W2, bufA, n);
        gcn_agg<<<n, 128, 0, stream>>>(bufA, rowptr, col, dinv, b2, bufB);
        // mean over nodes
        mean_partial<<<512, 128, 0, stream>>>(bufB, n, partial);
        mean_finish<<<1, 128, 0, stream>>>(partial, 512, 1.0f / (float)n, meano);
    };

    run_gcn(px, pei, Np, Ep, 128, pc1w, pc1b, pc2w, pc2b, pmean);
    run_gcn(dx, dei, Nd, Ed, 64,  dc1w, dc1b, dc2w, dc2b, dmean);

    seq_mlp<<<1, 128, 0, stream>>>(pseq, Psd, psw1, psb1, psw2, psb2, pseqo);
    seq_mlp<<<1, 128, 0, stream>>>(dseq, Dsd, dsw1, dsb1, dsw2, dsb2, dseqo);

    head_mlp<<<1, 128, 0, stream>>>(pmean, dmean, pseqo, dseqo,
                                    fc1w, fc1b, fc2w, fc2b, (float*)d_out);
}

// Round 2
// 1886.274 us; speedup vs baseline: 1.2036x; 1.2036x over previous
//
#include <hip/hip_runtime.h>
#include <cstdint>
#include <cstddef>

// ---------------------------------------------------------------------------
// GSF-DTA forward: 2x GCNConv (protein), 2x GCNConv (drug), 2 seq MLPs, head.
// CSR-by-dst built on device once per graph (shared by both conv layers);
// aggregation is gather-based (deterministic per-node sum, no f32 atomics).
// R2: parallelized seq-MLP/head/mean (were single-block latency-bound),
//     deeper unroll in gcn_agg gather loop.
// ---------------------------------------------------------------------------

#define SCAN_T 256
#define SCAN_E 2048   // elements per scan block (8 per thread)

__global__ void deg_count(const int* __restrict__ dst, int E, int* __restrict__ cnt) {
    int e = blockIdx.x * blockDim.x + threadIdx.x;
    int stride = gridDim.x * blockDim.x;
    for (; e < E; e += stride) atomicAdd(&cnt[dst[e]], 1);
}

__global__ void dinv_k(const int* __restrict__ cnt, float* __restrict__ dinv, int n) {
    int i = blockIdx.x * blockDim.x + threadIdx.x;
    if (i < n) dinv[i] = rsqrtf((float)(cnt[i] + 1));   // +1 self-loop; always > 0
}

__global__ void scan_block_sums(const int* __restrict__ cnt, int n, int* __restrict__ bsum) {
    int b = blockIdx.x, t = threadIdx.x;
    int base = b * SCAN_E;
    int s = 0;
    for (int i = t; i < SCAN_E; i += SCAN_T) {
        int idx = base + i;
        if (idx < n) s += cnt[idx];
    }
    __shared__ int sh[SCAN_T];
    sh[t] = s; __syncthreads();
    for (int off = SCAN_T / 2; off > 0; off >>= 1) {
        if (t < off) sh[t] += sh[t + off];
        __syncthreads();
    }
    if (t == 0) bsum[b] = sh[0];
}

__global__ void scan_offsets(int* __restrict__ bsum, int nblk, int* __restrict__ rowptr, int n) {
    // single thread: exclusive scan of block sums (<=64 blocks), in place
    int run = 0;
    for (int i = 0; i < nblk; ++i) { int v = bsum[i]; bsum[i] = run; run += v; }
    rowptr[n] = run;   // == E
}

__global__ void scan_write(const int* __restrict__ cnt, int n,
                           const int* __restrict__ boff, int* __restrict__ rowptr) {
    int b = blockIdx.x, t = threadIdx.x;
    int base = b * SCAN_E + t * 8;
    int v[8]; int tot = 0;
    #pragma unroll
    for (int j = 0; j < 8; ++j) {
        int idx = base + j;
        v[j] = (idx < n) ? cnt[idx] : 0;
        tot += v[j];
    }
    __shared__ int sh[SCAN_T];
    sh[t] = tot; __syncthreads();
    // inclusive Hillis-Steele over thread totals
    for (int off = 1; off < SCAN_T; off <<= 1) {
        int add = (t >= off) ? sh[t - off] : 0;
        __syncthreads();
        sh[t] += add;
        __syncthreads();
    }
    int excl = sh[t] - tot + boff[b];
    #pragma unroll
    for (int j = 0; j < 8; ++j) {
        int idx = base + j;
        if (idx < n) rowptr[idx] = excl;
        excl += v[j];
    }
}

__global__ void scatter_edges(const int* __restrict__ src, const int* __restrict__ dst, int E,
                              const int* __restrict__ rowptr, int* __restrict__ cursor,
                              int* __restrict__ col) {
    int e = blockIdx.x * blockDim.x + threadIdx.x;
    int stride = gridDim.x * blockDim.x;
    for (; e < E; e += stride) {
        int d = dst[e];
        int p = atomicAdd(&cursor[d], 1);
        col[rowptr[d] + p] = src[e];
    }
}

// out[n,128] = x[n,IN] @ W[IN,128]   (W staged in LDS; 64 rows per block)
template <int IN>
__global__ __launch_bounds__(256) void xw_matmul(const float* __restrict__ x,
                                                 const float* __restrict__ W,
                                                 float* __restrict__ out, int n) {
    __shared__ float Wl[IN * 128];
    __shared__ float xl[16 * IN];
    const int tid = threadIdx.x;
    for (int i = tid; i < IN * 128; i += 256) Wl[i] = W[i];

    const int tx = tid & 15;     // 16 column groups of 8
    const int ty = tid >> 4;     // 16 rows per tile
    const int c0 = tx * 8;
    int r0 = blockIdx.x * 64;

    for (int rt = 0; rt < 4; ++rt, r0 += 16) {
        __syncthreads();   // W ready (first iter) / xl safe to overwrite
        for (int i = tid; i < 16 * IN; i += 256) {
            int rr = i / IN, kk = i - rr * IN;
            int row = r0 + rr;
            xl[rr * IN + kk] = (row < n) ? x[(size_t)row * IN + kk] : 0.f;
        }
        __syncthreads();
        float acc[8];
        #pragma unroll
        for (int j = 0; j < 8; ++j) acc[j] = 0.f;
        const float* xrow = &xl[ty * IN];
        #pragma unroll 8
        for (int k = 0; k < IN; ++k) {
            float xv = xrow[k];
            const float4 w0 = *(const float4*)&Wl[k * 128 + c0];
            const float4 w1 = *(const float4*)&Wl[k * 128 + c0 + 4];
            acc[0] = fmaf(xv, w0.x, acc[0]);
            acc[1] = fmaf(xv, w0.y, acc[1]);
            acc[2] = fmaf(xv, w0.z, acc[2]);
            acc[3] = fmaf(xv, w0.w, acc[3]);
            acc[4] = fmaf(xv, w1.x, acc[4]);
            acc[5] = fmaf(xv, w1.y, acc[5]);
            acc[6] = fmaf(xv, w1.z, acc[6]);
            acc[7] = fmaf(xv, w1.w, acc[7]);
        }
        int row = r0 + ty;
        if (row < n) {
            float4* o = (float4*)&out[(size_t)row * 128 + c0];
            o[0] = make_float4(acc[0], acc[1], acc[2], acc[3]);
            o[1] = make_float4(acc[4], acc[5], acc[6], acc[7]);
        }
    }
}

// one node per 128-thread block; thread = feature.
// out[d,t] = relu( dinv[d]*( sum_e dinv[src]*xw[src,t] + dinv[d]*xw[d,t] ) + b[t] )
__global__ __launch_bounds__(128) void gcn_agg(const float* __restrict__ xw,
                                               const int* __restrict__ rowptr,
                                               const int* __restrict__ col,
                                               const float* __restrict__ dinv,
                                               const float* __restrict__ bias,
                                               float* __restrict__ out) {
    const int d = blockIdx.x;
    const int t = threadIdx.x;
    __shared__ int   cs[128];
    __shared__ float wsh[128];
    const int beg = rowptr[d], end = rowptr[d + 1];
    const float dv = dinv[d];
    float acc = dv * xw[(size_t)d * 128 + t];   // self-loop term (pre dv scale)
    for (int base = beg; base < end; base += 128) {
        int m = end - base; if (m > 128) m = 128;
        if (t < m) {
            int s = col[base + t];
            cs[t] = s;
            wsh[t] = dinv[s];
        }
        __syncthreads();
        #pragma unroll 8
        for (int j = 0; j < m; ++j)
            acc = fmaf(wsh[j], xw[(size_t)cs[j] * 128 + t], acc);
        __syncthreads();
    }
    float r = fmaf(dv, acc, bias[t]);
    out[(size_t)d * 128 + t] = fmaxf(r, 0.f);
}

#define MEAN_NB 128
__global__ __launch_bounds__(128) void mean_partial(const float* __restrict__ h, int n,
                                                    float* __restrict__ partial) {
    int t = threadIdx.x;           // 128
    int b = blockIdx.x;
    float s = 0.f;
    for (int r = b; r < n; r += MEAN_NB) s += h[(size_t)r * 128 + t];
    partial[b * 128 + t] = s;
}

__global__ __launch_bounds__(128) void mean_finish(const float* __restrict__ partial, float inv_n,
                                                   float* __restrict__ out) {
    int t = threadIdx.x;           // 128
    float s = 0.f;
    #pragma unroll 8
    for (int i = 0; i < MEAN_NB; ++i) s += partial[i * 128 + t];
    out[t] = s * inv_n;
}

// ---- parallel MLP: layer-1 partial over 64 k-slices --------------------------
#define MLP_NB 64
__global__ __launch_bounds__(256) void mlp_l1_partial(const float* __restrict__ in,
                                                      const float* __restrict__ w1, int IN,
                                                      float* __restrict__ partial) {
    const int b = blockIdx.x;            // 64 blocks
    const int t = threadIdx.x;           // 256
    const int f = t & 127;
    const int half = t >> 7;
    const int kpb = IN / MLP_NB;
    const int k0 = b * kpb;
    float acc = 0.f;
    #pragma unroll 4
    for (int k = k0 + half; k < k0 + kpb; k += 2)
        acc = fmaf(in[k], w1[(size_t)k * 128 + f], acc);
    __shared__ float sh[256];
    sh[t] = acc; __syncthreads();
    if (half == 0) partial[b * 128 + f] = sh[f] + sh[128 + f];
}

// finish for seq MLP: h = relu(sum partial + b1); out = relu(h @ w2 + b2)
__global__ __launch_bounds__(128) void mlp_seq_finish(const float* __restrict__ partial,
                                                      const float* __restrict__ b1,
                                                      const float* __restrict__ w2,
                                                      const float* __restrict__ b2,
                                                      float* __restrict__ out) {
    const int t = threadIdx.x;           // 128
    __shared__ float h[128];
    float s = 0.f;
    #pragma unroll 8
    for (int i = 0; i < MLP_NB; ++i) s += partial[i * 128 + t];
    h[t] = fmaxf(s + b1[t], 0.f);
    __syncthreads();
    float acc = 0.f;
    #pragma unroll 8
    for (int k = 0; k < 128; ++k) acc = fmaf(h[k], w2[k * 128 + t], acc);
    out[t] = fmaxf(acc + b2[t], 0.f);
}

// finish for head: h = relu(sum partial + fc1b); out = h . fc2w + fc2b  (scalar)
__global__ __launch_bounds__(128) void head_finish(const float* __restrict__ partial,
                                                   const float* __restrict__ fc1b,
                                                   const float* __restrict__ fc2w,
                                                   const float* __restrict__ fc2b,
                                                   float* __restrict__ out) {
    const int t = threadIdx.x;           // 128
    __shared__ float red[128];
    float s = 0.f;
    #pragma unroll 8
    for (int i = 0; i < MLP_NB; ++i) s += partial[i * 128 + t];
    float h = fmaxf(s + fc1b[t], 0.f);
    red[t] = h * fc2w[t];
    __syncthreads();
    for (int off = 64; off > 0; off >>= 1) {
        if (t < off) red[t] += red[t + off];
        __syncthreads();
    }
    if (t == 0) out[0] = red[0] + fc2b[0];
}

__global__ void concat4(const float* __restrict__ a, const float* __restrict__ b,
                        const float* __restrict__ c, const float* __restrict__ d,
                        float* __restrict__ out) {
    int t = threadIdx.x;                 // 128
    out[t] = a[t]; out[128 + t] = b[t]; out[256 + t] = c[t]; out[384 + t] = d[t];
}

static inline size_t align_up(size_t x, size_t a) { return (x + a - 1) / a * a; }

extern "C" void kernel_launch(void* const* d_in, const int* in_sizes, int n_in,
                              void* d_out, int out_size, void* d_ws, size_t ws_size,
                              hipStream_t stream) {
    const float* px   = (const float*)d_in[0];
    const int*   pei  = (const int*)d_in[1];
    const float* dx   = (const float*)d_in[2];
    const int*   dei  = (const int*)d_in[3];
    const float* pseq = (const float*)d_in[4];
    const float* dseq = (const float*)d_in[5];
    const float* pc1w = (const float*)d_in[6];  const float* pc1b = (const float*)d_in[7];
    const float* pc2w = (const float*)d_in[8];  const float* pc2b = (const float*)d_in[9];
    const float* dc1w = (const float*)d_in[10]; const float* dc1b = (const float*)d_in[11];
    const float* dc2w = (const float*)d_in[12]; const float* dc2b = (const float*)d_in[13];
    const float* psw1 = (const float*)d_in[14]; const float* psb1 = (const float*)d_in[15];
    const float* psw2 = (const float*)d_in[16]; const float* psb2 = (const float*)d_in[17];
    const float* dsw1 = (const float*)d_in[18]; const float* dsb1 = (const float*)d_in[19];
    const float* dsw2 = (const float*)d_in[20]; const float* dsb2 = (const float*)d_in[21];
    const float* fc1w = (const float*)d_in[22]; const float* fc1b = (const float*)d_in[23];
    const float* fc2w = (const float*)d_in[24]; const float* fc2b = (const float*)d_in[25];

    const int Np = in_sizes[0] / 128, Ep = in_sizes[1] / 2;
    const int Nd = in_sizes[2] / 64,  Ed = in_sizes[3] / 2;
    const int Psd = in_sizes[4], Dsd = in_sizes[5];

    char* w = (char*)d_ws;
    size_t off = 0;
    auto carve = [&](size_t bytes) -> void* {
        void* p = w + off;
        off = align_up(off + bytes, 256);
        return p;
    };
    float* bufA    = (float*)carve((size_t)Np * 128 * 4);
    float* bufB    = (float*)carve((size_t)Np * 128 * 4);
    int*   col     = (int*)carve((size_t)Ep * 4);
    int*   rowptr  = (int*)carve(((size_t)Np + 1) * 4);
    int*   cnt     = (int*)carve((size_t)Np * 4);
    int*   cursor  = (int*)carve((size_t)Np * 4);
    float* dinv    = (float*)carve((size_t)Np * 4);
    int*   bsum    = (int*)carve(4096);
    float* partial = (float*)carve((size_t)MEAN_NB * 128 * 4);
    float* mlpp    = (float*)carve((size_t)MLP_NB * 128 * 4);
    float* pmean   = (float*)carve(512);
    float* dmean   = (float*)carve(512);
    float* pseqo   = (float*)carve(512);
    float* dseqo   = (float*)carve(512);
    float* comb    = (float*)carve(2048);
    (void)ws_size; (void)n_in; (void)out_size;

    auto run_gcn = [&](const float* x, const int* ei, int n, int E, int IN,
                       const float* W1, const float* b1,
                       const float* W2, const float* b2, float* meano) {
        const int* srcp = ei;
        const int* dstp = ei + E;
        int nbE = (E + 255) / 256; if (nbE > 4096) nbE = 4096;
        int nblk = (n + SCAN_E - 1) / SCAN_E;

        hipMemsetAsync(cnt, 0, (size_t)n * 4, stream);
        deg_count<<<nbE, 256, 0, stream>>>(dstp, E, cnt);
        dinv_k<<<(n + 255) / 256, 256, 0, stream>>>(cnt, dinv, n);
        scan_block_sums<<<nblk, SCAN_T, 0, stream>>>(cnt, n, bsum);
        scan_offsets<<<1, 1, 0, stream>>>(bsum, nblk, rowptr, n);
        scan_write<<<nblk, SCAN_T, 0, stream>>>(cnt, n, bsum, rowptr);
        hipMemsetAsync(cursor, 0, (size_t)n * 4, stream);
        scatter_edges<<<nbE, 256, 0, stream>>>(srcp, dstp, E, rowptr, cursor, col);

        // conv1
        if (IN == 128) xw_matmul<128><<<(n + 63) / 64, 256, 0, stream>>>(x, W1, bufA, n);
        else           xw_matmul<64><<<(n + 63) / 64, 256, 0, stream>>>(x, W1, bufA, n);
        gcn_agg<<<n, 128, 0, stream>>>(bufA, rowptr, col, dinv, b1, bufB);
        // conv2
        xw_matmul<128><<<(n + 63) / 64, 256, 0, stream>>>(bufB, W2, bufA, n);
        gcn_agg<<<n, 128, 0, stream>>>(bufA, rowptr, col, dinv, b2, bufB);
        // mean over nodes
        mean_partial<<<MEAN_NB, 128, 0, stream>>>(bufB, n, partial);
        mean_finish<<<1, 128, 0, stream>>>(partial, 1.0f / (float)n, meano);
    };

    run_gcn(px, pei, Np, Ep, 128, pc1w, pc1b, pc2w, pc2b, pmean);
    run_gcn(dx, dei, Nd, Ed, 64,  dc1w, dc1b, dc2w, dc2b, dmean);

    // seq MLPs (parallelized)
    mlp_l1_partial<<<MLP_NB, 256, 0, stream>>>(pseq, psw1, Psd, mlpp);
    mlp_seq_finish<<<1, 128, 0, stream>>>(mlpp, psb1, psw2, psb2, pseqo);
    mlp_l1_partial<<<MLP_NB, 256, 0, stream>>>(dseq, dsw1, Dsd, mlpp);
    mlp_seq_finish<<<1, 128, 0, stream>>>(mlpp, dsb1, dsw2, dsb2, dseqo);

    // head
    concat4<<<1, 128, 0, stream>>>(pmean, dmean, pseqo, dseqo, comb);
    mlp_l1_partial<<<MLP_NB, 256, 0, stream>>>(comb, fc1w, 512, mlpp);
    head_finish<<<1, 128, 0, stream>>>(mlpp, fc1b, fc2w, fc2b, (float*)d_out);
}

// Round 3
// 1409.227 us; speedup vs baseline: 1.6110x; 1.3385x over previous
//
#include <hip/hip_runtime.h>
#include <cstdint>
#include <cstddef>

// ---------------------------------------------------------------------------
// GSF-DTA forward: 2x GCNConv (protein), 2x GCNConv (drug), 2 seq MLPs, head.
// CSR-by-dst built on device once per graph (shared by both conv layers).
// R3: bf16 message table with dinv folded in (halves gather traffic, removes
//     dinv gathers); rank-based scatter (no cursor atomics, no memset).
// ---------------------------------------------------------------------------

#define SCAN_T 256
#define SCAN_E 2048   // elements per scan block (8 per thread)

static __device__ __forceinline__ float bf2f(unsigned short u) {
    union { unsigned int i; float f; } v; v.i = ((unsigned int)u) << 16; return v.f;
}
static __device__ __forceinline__ unsigned short f2bf(float f) {
    union { float f; unsigned int i; } v; v.f = f;
    unsigned int r = v.i + 0x7fffu + ((v.i >> 16) & 1u);   // round-nearest-even
    return (unsigned short)(r >> 16);
}

__global__ void deg_count_rank(const int* __restrict__ dst, int E,
                               int* __restrict__ cnt, int* __restrict__ rank) {
    int e = blockIdx.x * blockDim.x + threadIdx.x;
    int stride = gridDim.x * blockDim.x;
    for (; e < E; e += stride) rank[e] = atomicAdd(&cnt[dst[e]], 1);
}

__global__ void dinv_k(const int* __restrict__ cnt, float* __restrict__ dinv, int n) {
    int i = blockIdx.x * blockDim.x + threadIdx.x;
    if (i < n) dinv[i] = rsqrtf((float)(cnt[i] + 1));   // +1 self-loop; always > 0
}

__global__ void scan_block_sums(const int* __restrict__ cnt, int n, int* __restrict__ bsum) {
    int b = blockIdx.x, t = threadIdx.x;
    int base = b * SCAN_E;
    int s = 0;
    for (int i = t; i < SCAN_E; i += SCAN_T) {
        int idx = base + i;
        if (idx < n) s += cnt[idx];
    }
    __shared__ int sh[SCAN_T];
    sh[t] = s; __syncthreads();
    for (int off = SCAN_T / 2; off > 0; off >>= 1) {
        if (t < off) sh[t] += sh[t + off];
        __syncthreads();
    }
    if (t == 0) bsum[b] = sh[0];
}

__global__ void scan_offsets(int* __restrict__ bsum, int nblk, int* __restrict__ rowptr, int n) {
    int run = 0;
    for (int i = 0; i < nblk; ++i) { int v = bsum[i]; bsum[i] = run; run += v; }
    rowptr[n] = run;   // == E
}

__global__ void scan_write(const int* __restrict__ cnt, int n,
                           const int* __restrict__ boff, int* __restrict__ rowptr) {
    int b = blockIdx.x, t = threadIdx.x;
    int base = b * SCAN_E + t * 8;
    int v[8]; int tot = 0;
    #pragma unroll
    for (int j = 0; j < 8; ++j) {
        int idx = base + j;
        v[j] = (idx < n) ? cnt[idx] : 0;
        tot += v[j];
    }
    __shared__ int sh[SCAN_T];
    sh[t] = tot; __syncthreads();
    for (int off = 1; off < SCAN_T; off <<= 1) {
        int add = (t >= off) ? sh[t - off] : 0;
        __syncthreads();
        sh[t] += add;
        __syncthreads();
    }
    int excl = sh[t] - tot + boff[b];
    #pragma unroll
    for (int j = 0; j < 8; ++j) {
        int idx = base + j;
        if (idx < n) rowptr[idx] = excl;
        excl += v[j];
    }
}

__global__ void scatter_edges(const int* __restrict__ src, const int* __restrict__ dst,
                              const int* __restrict__ rank, int E,
                              const int* __restrict__ rowptr, int* __restrict__ col) {
    int e = blockIdx.x * blockDim.x + threadIdx.x;
    int stride = gridDim.x * blockDim.x;
    for (; e < E; e += stride)
        col[rowptr[dst[e]] + rank[e]] = src[e];
}

// out[n,128] (bf16) = dinv[row] * (x[n,IN] @ W[IN,128])   (W staged in LDS)
template <int IN>
__global__ __launch_bounds__(256) void xw_matmul(const float* __restrict__ x,
                                                 const float* __restrict__ W,
                                                 const float* __restrict__ dinv,
                                                 unsigned short* __restrict__ out, int n) {
    __shared__ float Wl[IN * 128];
    __shared__ float xl[16 * IN];
    const int tid = threadIdx.x;
    for (int i = tid; i < IN * 128; i += 256) Wl[i] = W[i];

    const int tx = tid & 15;     // 16 column groups of 8
    const int ty = tid >> 4;     // 16 rows per tile
    const int c0 = tx * 8;
    int r0 = blockIdx.x * 64;

    for (int rt = 0; rt < 4; ++rt, r0 += 16) {
        __syncthreads();
        for (int i = tid; i < 16 * IN; i += 256) {
            int rr = i / IN, kk = i - rr * IN;
            int row = r0 + rr;
            xl[rr * IN + kk] = (row < n) ? x[(size_t)row * IN + kk] : 0.f;
        }
        __syncthreads();
        float acc[8];
        #pragma unroll
        for (int j = 0; j < 8; ++j) acc[j] = 0.f;
        const float* xrow = &xl[ty * IN];
        #pragma unroll 8
        for (int k = 0; k < IN; ++k) {
            float xv = xrow[k];
            const float4 w0 = *(const float4*)&Wl[k * 128 + c0];
            const float4 w1 = *(const float4*)&Wl[k * 128 + c0 + 4];
            acc[0] = fmaf(xv, w0.x, acc[0]);
            acc[1] = fmaf(xv, w0.y, acc[1]);
            acc[2] = fmaf(xv, w0.z, acc[2]);
            acc[3] = fmaf(xv, w0.w, acc[3]);
            acc[4] = fmaf(xv, w1.x, acc[4]);
            acc[5] = fmaf(xv, w1.y, acc[5]);
            acc[6] = fmaf(xv, w1.z, acc[6]);
            acc[7] = fmaf(xv, w1.w, acc[7]);
        }
        int row = r0 + ty;
        if (row < n) {
            float s = dinv[row];
            uint4 pk;
            pk.x = (unsigned)f2bf(acc[0] * s) | ((unsigned)f2bf(acc[1] * s) << 16);
            pk.y = (unsigned)f2bf(acc[2] * s) | ((unsigned)f2bf(acc[3] * s) << 16);
            pk.z = (unsigned)f2bf(acc[4] * s) | ((unsigned)f2bf(acc[5] * s) << 16);
            pk.w = (unsigned)f2bf(acc[6] * s) | ((unsigned)f2bf(acc[7] * s) << 16);
            *(uint4*)&out[(size_t)row * 128 + c0] = pk;
        }
    }
}

// one node per 128-thread block; thread = feature.
// out[d,t] = relu( dinv[d] * ( sum_e xwn[src_e,t] + xwn[d,t] ) + b[t] )
__global__ __launch_bounds__(128) void gcn_agg(const unsigned short* __restrict__ xwn,
                                               const int* __restrict__ rowptr,
                                               const int* __restrict__ col,
                                               const float* __restrict__ dinv,
                                               const float* __restrict__ bias,
                                               float* __restrict__ out) {
    const int d = blockIdx.x;
    const int t = threadIdx.x;
    __shared__ int cs[128];
    const int beg = rowptr[d], end = rowptr[d + 1];
    const float dv = dinv[d];
    float acc = bf2f(xwn[(size_t)d * 128 + t]);   // self-loop term
    for (int base = beg; base < end; base += 128) {
        int m = end - base; if (m > 128) m = 128;
        if (t < m) cs[t] = col[base + t];
        __syncthreads();
        #pragma unroll 8
        for (int j = 0; j < m; ++j)
            acc += bf2f(xwn[(size_t)cs[j] * 128 + t]);
        __syncthreads();
    }
    float r = fmaf(dv, acc, bias[t]);
    out[(size_t)d * 128 + t] = fmaxf(r, 0.f);
}

#define MEAN_NB 128
__global__ __launch_bounds__(128) void mean_partial(const float* __restrict__ h, int n,
                                                    float* __restrict__ partial) {
    int t = threadIdx.x;           // 128
    int b = blockIdx.x;
    float s = 0.f;
    for (int r = b; r < n; r += MEAN_NB) s += h[(size_t)r * 128 + t];
    partial[b * 128 + t] = s;
}

__global__ __launch_bounds__(128) void mean_finish(const float* __restrict__ partial, float inv_n,
                                                   float* __restrict__ out) {
    int t = threadIdx.x;           // 128
    float s = 0.f;
    #pragma unroll 8
    for (int i = 0; i < MEAN_NB; ++i) s += partial[i * 128 + t];
    out[t] = s * inv_n;
}

// ---- parallel MLP: layer-1 partial over 64 k-slices --------------------------
#define MLP_NB 64
__global__ __launch_bounds__(256) void mlp_l1_partial(const float* __restrict__ in,
                                                      const float* __restrict__ w1, int IN,
                                                      float* __restrict__ partial) {
    const int b = blockIdx.x;            // 64 blocks
    const int t = threadIdx.x;           // 256
    const int f = t & 127;
    const int half = t >> 7;
    const int kpb = IN / MLP_NB;
    const int k0 = b * kpb;
    float acc = 0.f;
    #pragma unroll 4
    for (int k = k0 + half; k < k0 + kpb; k += 2)
        acc = fmaf(in[k], w1[(size_t)k * 128 + f], acc);
    __shared__ float sh[256];
    sh[t] = acc; __syncthreads();
    if (half == 0) partial[b * 128 + f] = sh[f] + sh[128 + f];
}

__global__ __launch_bounds__(128) void mlp_seq_finish(const float* __restrict__ partial,
                                                      const float* __restrict__ b1,
                                                      const float* __restrict__ w2,
                                                      const float* __restrict__ b2,
                                                      float* __restrict__ out) {
    const int t = threadIdx.x;           // 128
    __shared__ float h[128];
    float s = 0.f;
    #pragma unroll 8
    for (int i = 0; i < MLP_NB; ++i) s += partial[i * 128 + t];
    h[t] = fmaxf(s + b1[t], 0.f);
    __syncthreads();
    float acc = 0.f;
    #pragma unroll 8
    for (int k = 0; k < 128; ++k) acc = fmaf(h[k], w2[k * 128 + t], acc);
    out[t] = fmaxf(acc + b2[t], 0.f);
}

__global__ __launch_bounds__(128) void head_finish(const float* __restrict__ partial,
                                                   const float* __restrict__ fc1b,
                                                   const float* __restrict__ fc2w,
                                                   const float* __restrict__ fc2b,
                                                   float* __restrict__ out) {
    const int t = threadIdx.x;           // 128
    __shared__ float red[128];
    float s = 0.f;
    #pragma unroll 8
    for (int i = 0; i < MLP_NB; ++i) s += partial[i * 128 + t];
    float h = fmaxf(s + fc1b[t], 0.f);
    red[t] = h * fc2w[t];
    __syncthreads();
    for (int off = 64; off > 0; off >>= 1) {
        if (t < off) red[t] += red[t + off];
        __syncthreads();
    }
    if (t == 0) out[0] = red[0] + fc2b[0];
}

__global__ void concat4(const float* __restrict__ a, const float* __restrict__ b,
                        const float* __restrict__ c, const float* __restrict__ d,
                        float* __restrict__ out) {
    int t = threadIdx.x;                 // 128
    out[t] = a[t]; out[128 + t] = b[t]; out[256 + t] = c[t]; out[384 + t] = d[t];
}

static inline size_t align_up(size_t x, size_t a) { return (x + a - 1) / a * a; }

extern "C" void kernel_launch(void* const* d_in, const int* in_sizes, int n_in,
                              void* d_out, int out_size, void* d_ws, size_t ws_size,
                              hipStream_t stream) {
    const float* px   = (const float*)d_in[0];
    const int*   pei  = (const int*)d_in[1];
    const float* dx   = (const float*)d_in[2];
    const int*   dei  = (const int*)d_in[3];
    const float* pseq = (const float*)d_in[4];
    const float* dseq = (const float*)d_in[5];
    const float* pc1w = (const float*)d_in[6];  const float* pc1b = (const float*)d_in[7];
    const float* pc2w = (const float*)d_in[8];  const float* pc2b = (const float*)d_in[9];
    const float* dc1w = (const float*)d_in[10]; const float* dc1b = (const float*)d_in[11];
    const float* dc2w = (const float*)d_in[12]; const float* dc2b = (const float*)d_in[13];
    const float* psw1 = (const float*)d_in[14]; const float* psb1 = (const float*)d_in[15];
    const float* psw2 = (const float*)d_in[16]; const float* psb2 = (const float*)d_in[17];
    const float* dsw1 = (const float*)d_in[18]; const float* dsb1 = (const float*)d_in[19];
    const float* dsw2 = (const float*)d_in[20]; const float* dsb2 = (const float*)d_in[21];
    const float* fc1w = (const float*)d_in[22]; const float* fc1b = (const float*)d_in[23];
    const float* fc2w = (const float*)d_in[24]; const float* fc2b = (const float*)d_in[25];

    const int Np = in_sizes[0] / 128, Ep = in_sizes[1] / 2;
    const int Nd = in_sizes[2] / 64,  Ed = in_sizes[3] / 2;
    const int Psd = in_sizes[4], Dsd = in_sizes[5];

    char* w = (char*)d_ws;
    size_t off = 0;
    auto carve = [&](size_t bytes) -> void* {
        void* p = w + off;
        off = align_up(off + bytes, 256);
        return p;
    };
    unsigned short* bufA = (unsigned short*)carve((size_t)Np * 128 * 2);  // bf16 msg table
    float* bufB    = (float*)carve((size_t)Np * 128 * 4);
    int*   col     = (int*)carve((size_t)Ep * 4);
    int*   rank    = (int*)carve((size_t)Ep * 4);
    int*   rowptr  = (int*)carve(((size_t)Np + 1) * 4);
    int*   cnt     = (int*)carve((size_t)Np * 4);
    float* dinv    = (float*)carve((size_t)Np * 4);
    int*   bsum    = (int*)carve(4096);
    float* partial = (float*)carve((size_t)MEAN_NB * 128 * 4);
    float* mlpp    = (float*)carve((size_t)MLP_NB * 128 * 4);
    float* pmean   = (float*)carve(512);
    float* dmean   = (float*)carve(512);
    float* pseqo   = (float*)carve(512);
    float* dseqo   = (float*)carve(512);
    float* comb    = (float*)carve(2048);
    (void)ws_size; (void)n_in; (void)out_size;

    auto run_gcn = [&](const float* x, const int* ei, int n, int E, int IN,
                       const float* W1, const float* b1,
                       const float* W2, const float* b2, float* meano) {
        const int* srcp = ei;
        const int* dstp = ei + E;
        int nbE = (E + 255) / 256; if (nbE > 4096) nbE = 4096;
        int nblk = (n + SCAN_E - 1) / SCAN_E;

        hipMemsetAsync(cnt, 0, (size_t)n * 4, stream);
        deg_count_rank<<<nbE, 256, 0, stream>>>(dstp, E, cnt, rank);
        dinv_k<<<(n + 255) / 256, 256, 0, stream>>>(cnt, dinv, n);
        scan_block_sums<<<nblk, SCAN_T, 0, stream>>>(cnt, n, bsum);
        scan_offsets<<<1, 1, 0, stream>>>(bsum, nblk, rowptr, n);
        scan_write<<<nblk, SCAN_T, 0, stream>>>(cnt, n, bsum, rowptr);
        scatter_edges<<<nbE, 256, 0, stream>>>(srcp, dstp, rank, E, rowptr, col);

        // conv1
        if (IN == 128) xw_matmul<128><<<(n + 63) / 64, 256, 0, stream>>>(x, W1, dinv, bufA, n);
        else           xw_matmul<64><<<(n + 63) / 64, 256, 0, stream>>>(x, W1, dinv, bufA, n);
        gcn_agg<<<n, 128, 0, stream>>>(bufA, rowptr, col, dinv, b1, bufB);
        // conv2
        xw_matmul<128><<<(n + 63) / 64, 256, 0, stream>>>(bufB, W2, dinv, bufA, n);
        gcn_agg<<<n, 128, 0, stream>>>(bufA, rowptr, col, dinv, b2, bufB);
        // mean over nodes
        mean_partial<<<MEAN_NB, 128, 0, stream>>>(bufB, n, partial);
        mean_finish<<<1, 128, 0, stream>>>(partial, 1.0f / (float)n, meano);
    };

    run_gcn(px, pei, Np, Ep, 128, pc1w, pc1b, pc2w, pc2b, pmean);
    run_gcn(dx, dei, Nd, Ed, 64,  dc1w, dc1b, dc2w, dc2b, dmean);

    // seq MLPs (parallelized)
    mlp_l1_partial<<<MLP_NB, 256, 0, stream>>>(pseq, psw1, Psd, mlpp);
    mlp_seq_finish<<<1, 128, 0, stream>>>(mlpp, psb1, psw2, psb2, pseqo);
    mlp_l1_partial<<<MLP_NB, 256, 0, stream>>>(dseq, dsw1, Dsd, mlpp);
    mlp_seq_finish<<<1, 128, 0, stream>>>(mlpp, dsb1, dsw2, dsb2, dseqo);

    // head
    concat4<<<1, 128, 0, stream>>>(pmean, dmean, pseqo, dseqo, comb);
    mlp_l1_partial<<<MLP_NB, 256, 0, stream>>>(comb, fc1w, 512, mlpp);
    head_finish<<<1, 128, 0, stream>>>(mlpp, fc1b, fc2w, fc2b, (float*)d_out);
}

// Round 4
// 1066.410 us; speedup vs baseline: 2.1289x; 1.3215x over previous
//
#include <hip/hip_runtime.h>
#include <cstdint>
#include <cstddef>

// ---------------------------------------------------------------------------
// GSF-DTA forward: 2x GCNConv (protein), 2x GCNConv (drug), 2 seq MLPs, head.
// R4: CSR build via 2-level bucket sort (no global atomics, L2-friendly
//     writes, produces rowptr/dinv/col directly); fast coalesced mean.
// gcn_agg: bf16 message table with dinv folded in (from R3).
// ---------------------------------------------------------------------------

#define NCB 256     // chunk blocks for edge passes
#define BSH 9       // bucket shift: 512 nodes per bucket (needs n <= 131072)
#define BW  512     // 1 << BSH

static __device__ __forceinline__ float bf2f(unsigned short u) {
    union { unsigned int i; float f; } v; v.i = ((unsigned int)u) << 16; return v.f;
}
static __device__ __forceinline__ unsigned short f2bf(float f) {
    union { float f; unsigned int i; } v; v.f = f;
    unsigned int r = v.i + 0x7fffu + ((v.i >> 16) & 1u);   // round-nearest-even
    return (unsigned short)(r >> 16);
}

// ---- CSR build: bucket sort by dst ------------------------------------------
__global__ __launch_bounds__(256) void csr_hist(const int* __restrict__ dst, int E, int chunk,
                                                int* __restrict__ bcnt) {
    __shared__ int h[256];
    const int t = threadIdx.x, blk = blockIdx.x;
    h[t] = 0; __syncthreads();
    const int e0 = blk * chunk;
    const int e1 = min(E, e0 + chunk);
    for (int e = e0 + t; e < e1; e += 256) atomicAdd(&h[dst[e] >> BSH], 1);
    __syncthreads();
    bcnt[blk * 256 + t] = h[t];
}

__global__ __launch_bounds__(256) void csr_scan(int* __restrict__ bcnt, int* __restrict__ bbase) {
    const int t = threadIdx.x;
    int run = 0;
    for (int blk = 0; blk < NCB; ++blk) {
        int idx = blk * 256 + t;
        int v = bcnt[idx]; bcnt[idx] = run; run += v;
    }
    __shared__ int sh[256];
    sh[t] = run; __syncthreads();
    for (int off = 1; off < 256; off <<= 1) {
        int add = (t >= off) ? sh[t - off] : 0;
        __syncthreads(); sh[t] += add; __syncthreads();
    }
    bbase[t] = sh[t] - run;              // exclusive scan over buckets
    if (t == 255) bbase[256] = sh[255];  // == E
}

__global__ __launch_bounds__(256) void csr_place(const int* __restrict__ src,
                                                 const int* __restrict__ dst, int E, int chunk,
                                                 const int* __restrict__ bcnt,
                                                 const int* __restrict__ bbase,
                                                 unsigned* __restrict__ ebuf) {
    __shared__ int cur[256];
    const int t = threadIdx.x, blk = blockIdx.x;
    cur[t] = bbase[t] + bcnt[blk * 256 + t];
    __syncthreads();
    const int e0 = blk * chunk;
    const int e1 = min(E, e0 + chunk);
    for (int e = e0 + t; e < e1; e += 256) {
        int d = dst[e];
        int b = d >> BSH;
        int pos = atomicAdd(&cur[b], 1);
        ebuf[pos] = ((unsigned)src[e] << BSH) | (unsigned)(d & (BW - 1));
    }
}

// one block per bucket: per-node histogram -> dinv + rowptr, then scatter col.
__global__ __launch_bounds__(256) void csr_finish(const unsigned* __restrict__ ebuf,
                                                  const int* __restrict__ bbase,
                                                  int n, int E,
                                                  int* __restrict__ rowptr,
                                                  float* __restrict__ dinv,
                                                  int* __restrict__ col) {
    __shared__ int hist[BW];
    __shared__ int cur[BW];
    __shared__ int sh[256];
    const int t = threadIdx.x, b = blockIdx.x;
    const int nb = b << BSH;
    const int w = min(BW, n - nb);
    const int rb = bbase[b], re = bbase[b + 1];
    hist[2 * t] = 0; hist[2 * t + 1] = 0;
    __syncthreads();
    for (int i = rb + t; i < re; i += 256) atomicAdd(&hist[ebuf[i] & (BW - 1)], 1);
    __syncthreads();
    const int a0 = hist[2 * t], a1 = hist[2 * t + 1];
    if (2 * t     < w) dinv[nb + 2 * t]     = rsqrtf((float)(a0 + 1));
    if (2 * t + 1 < w) dinv[nb + 2 * t + 1] = rsqrtf((float)(a1 + 1));
    sh[t] = a0 + a1; __syncthreads();
    for (int off = 1; off < 256; off <<= 1) {
        int add = (t >= off) ? sh[t - off] : 0;
        __syncthreads(); sh[t] += add; __syncthreads();
    }
    int base = t ? sh[t - 1] : 0;
    const int p0 = rb + base, p1 = rb + base + a0;
    if (2 * t     < w) rowptr[nb + 2 * t]     = p0;
    if (2 * t + 1 < w) rowptr[nb + 2 * t + 1] = p1;
    cur[2 * t] = p0; cur[2 * t + 1] = p1;
    __syncthreads();
    for (int i = rb + t; i < re; i += 256) {
        unsigned r = ebuf[i];
        int pos = atomicAdd(&cur[r & (BW - 1)], 1);
        col[pos] = (int)(r >> BSH);
    }
    if (b == 0 && t == 0) rowptr[n] = E;
}

// ---- x@W, scaled by dinv, bf16 output ---------------------------------------
template <int IN>
__global__ __launch_bounds__(256) void xw_matmul(const float* __restrict__ x,
                                                 const float* __restrict__ W,
                                                 const float* __restrict__ dinv,
                                                 unsigned short* __restrict__ out, int n) {
    __shared__ float Wl[IN * 128];
    __shared__ float xl[16 * IN];
    const int tid = threadIdx.x;
    for (int i = tid; i < IN * 128; i += 256) Wl[i] = W[i];

    const int tx = tid & 15;
    const int ty = tid >> 4;
    const int c0 = tx * 8;
    int r0 = blockIdx.x * 64;

    for (int rt = 0; rt < 4; ++rt, r0 += 16) {
        __syncthreads();
        for (int i = tid; i < 16 * IN; i += 256) {
            int rr = i / IN, kk = i - rr * IN;
            int row = r0 + rr;
            xl[rr * IN + kk] = (row < n) ? x[(size_t)row * IN + kk] : 0.f;
        }
        __syncthreads();
        float acc[8];
        #pragma unroll
        for (int j = 0; j < 8; ++j) acc[j] = 0.f;
        const float* xrow = &xl[ty * IN];
        #pragma unroll 8
        for (int k = 0; k < IN; ++k) {
            float xv = xrow[k];
            const float4 w0 = *(const float4*)&Wl[k * 128 + c0];
            const float4 w1 = *(const float4*)&Wl[k * 128 + c0 + 4];
            acc[0] = fmaf(xv, w0.x, acc[0]);
            acc[1] = fmaf(xv, w0.y, acc[1]);
            acc[2] = fmaf(xv, w0.z, acc[2]);
            acc[3] = fmaf(xv, w0.w, acc[3]);
            acc[4] = fmaf(xv, w1.x, acc[4]);
            acc[5] = fmaf(xv, w1.y, acc[5]);
            acc[6] = fmaf(xv, w1.z, acc[6]);
            acc[7] = fmaf(xv, w1.w, acc[7]);
        }
        int row = r0 + ty;
        if (row < n) {
            float s = dinv[row];
            uint4 pk;
            pk.x = (unsigned)f2bf(acc[0] * s) | ((unsigned)f2bf(acc[1] * s) << 16);
            pk.y = (unsigned)f2bf(acc[2] * s) | ((unsigned)f2bf(acc[3] * s) << 16);
            pk.z = (unsigned)f2bf(acc[4] * s) | ((unsigned)f2bf(acc[5] * s) << 16);
            pk.w = (unsigned)f2bf(acc[6] * s) | ((unsigned)f2bf(acc[7] * s) << 16);
            *(uint4*)&out[(size_t)row * 128 + c0] = pk;
        }
    }
}

// ---- aggregation: one node per 128-thread block -----------------------------
__global__ __launch_bounds__(128) void gcn_agg(const unsigned short* __restrict__ xwn,
                                               const int* __restrict__ rowptr,
                                               const int* __restrict__ col,
                                               const float* __restrict__ dinv,
                                               const float* __restrict__ bias,
                                               float* __restrict__ out) {
    const int d = blockIdx.x;
    const int t = threadIdx.x;
    __shared__ int cs[128];
    const int beg = rowptr[d], end = rowptr[d + 1];
    const float dv = dinv[d];
    float acc = bf2f(xwn[(size_t)d * 128 + t]);   // self-loop term
    for (int base = beg; base < end; base += 128) {
        int m = end - base; if (m > 128) m = 128;
        if (t < m) cs[t] = col[base + t];
        __syncthreads();
        #pragma unroll 8
        for (int j = 0; j < m; ++j)
            acc += bf2f(xwn[(size_t)cs[j] * 128 + t]);
        __syncthreads();
    }
    float r = fmaf(dv, acc, bias[t]);
    out[(size_t)d * 128 + t] = fmaxf(r, 0.f);
}

// ---- mean over rows (coalesced float4) --------------------------------------
#define MP_NB 1024
__global__ __launch_bounds__(256) void mean_partial(const float* __restrict__ h, int n,
                                                    float* __restrict__ partial) {
    const int t = threadIdx.x, b = blockIdx.x;
    const int rpb = (n + MP_NB - 1) / MP_NB;
    const int r0 = b * rpb, r1 = min(n, r0 + rpb);
    const int c4 = (t & 31) * 4;
    float4 acc = make_float4(0.f, 0.f, 0.f, 0.f);
    for (int r = r0 + (t >> 5); r < r1; r += 8) {
        float4 v = *(const float4*)&h[(size_t)r * 128 + c4];
        acc.x += v.x; acc.y += v.y; acc.z += v.z; acc.w += v.w;
    }
    __shared__ float4 sh[256];
    sh[t] = acc; __syncthreads();
    for (int off = 128; off >= 32; off >>= 1) {
        if (t < off) {
            float4 a = sh[t], o = sh[t + off];
            a.x += o.x; a.y += o.y; a.z += o.z; a.w += o.w;
            sh[t] = a;
        }
        __syncthreads();
    }
    if (t < 32) *(float4*)&partial[(size_t)b * 128 + c4] = sh[t];
}

__global__ __launch_bounds__(256) void mean_finish(const float* __restrict__ partial, float inv_n,
                                                   float* __restrict__ out) {
    const int t = threadIdx.x;
    const int c4 = (t & 31) * 4;
    float4 acc = make_float4(0.f, 0.f, 0.f, 0.f);
    for (int r = (t >> 5); r < MP_NB; r += 8) {
        float4 v = *(const float4*)&partial[(size_t)r * 128 + c4];
        acc.x += v.x; acc.y += v.y; acc.z += v.z; acc.w += v.w;
    }
    __shared__ float4 sh[256];
    sh[t] = acc; __syncthreads();
    for (int off = 128; off >= 32; off >>= 1) {
        if (t < off) {
            float4 a = sh[t], o = sh[t + off];
            a.x += o.x; a.y += o.y; a.z += o.z; a.w += o.w;
            sh[t] = a;
        }
        __syncthreads();
    }
    if (t < 32) {
        float4 a = sh[t];
        a.x *= inv_n; a.y *= inv_n; a.z *= inv_n; a.w *= inv_n;
        *(float4*)&out[c4] = a;
    }
}

// ---- parallel MLP: layer-1 partial over 64 k-slices -------------------------
#define MLP_NB 64
__global__ __launch_bounds__(256) void mlp_l1_partial(const float* __restrict__ in,
                                                      const float* __restrict__ w1, int IN,
                                                      float* __restrict__ partial) {
    const int b = blockIdx.x;
    const int t = threadIdx.x;
    const int f = t & 127;
    const int half = t >> 7;
    const int kpb = IN / MLP_NB;
    const int k0 = b * kpb;
    float acc = 0.f;
    #pragma unroll 4
    for (int k = k0 + half; k < k0 + kpb; k += 2)
        acc = fmaf(in[k], w1[(size_t)k * 128 + f], acc);
    __shared__ float sh[256];
    sh[t] = acc; __syncthreads();
    if (half == 0) partial[b * 128 + f] = sh[f] + sh[128 + f];
}

__global__ __launch_bounds__(128) void mlp_seq_finish(const float* __restrict__ partial,
                                                      const float* __restrict__ b1,
                                                      const float* __restrict__ w2,
                                                      const float* __restrict__ b2,
                                                      float* __restrict__ out) {
    const int t = threadIdx.x;
    __shared__ float h[128];
    float s = 0.f;
    #pragma unroll 8
    for (int i = 0; i < MLP_NB; ++i) s += partial[i * 128 + t];
    h[t] = fmaxf(s + b1[t], 0.f);
    __syncthreads();
    float acc = 0.f;
    #pragma unroll 8
    for (int k = 0; k < 128; ++k) acc = fmaf(h[k], w2[k * 128 + t], acc);
    out[t] = fmaxf(acc + b2[t], 0.f);
}

__global__ __launch_bounds__(128) void head_finish(const float* __restrict__ partial,
                                                   const float* __restrict__ fc1b,
                                                   const float* __restrict__ fc2w,
                                                   const float* __restrict__ fc2b,
                                                   float* __restrict__ out) {
    const int t = threadIdx.x;
    __shared__ float red[128];
    float s = 0.f;
    #pragma unroll 8
    for (int i = 0; i < MLP_NB; ++i) s += partial[i * 128 + t];
    float h = fmaxf(s + fc1b[t], 0.f);
    red[t] = h * fc2w[t];
    __syncthreads();
    for (int off = 64; off > 0; off >>= 1) {
        if (t < off) red[t] += red[t + off];
        __syncthreads();
    }
    if (t == 0) out[0] = red[0] + fc2b[0];
}

__global__ void concat4(const float* __restrict__ a, const float* __restrict__ b,
                        const float* __restrict__ c, const float* __restrict__ d,
                        float* __restrict__ out) {
    int t = threadIdx.x;
    out[t] = a[t]; out[128 + t] = b[t]; out[256 + t] = c[t]; out[384 + t] = d[t];
}

static inline size_t align_up(size_t x, size_t a) { return (x + a - 1) / a * a; }

extern "C" void kernel_launch(void* const* d_in, const int* in_sizes, int n_in,
                              void* d_out, int out_size, void* d_ws, size_t ws_size,
                              hipStream_t stream) {
    const float* px   = (const float*)d_in[0];
    const int*   pei  = (const int*)d_in[1];
    const float* dx   = (const float*)d_in[2];
    const int*   dei  = (const int*)d_in[3];
    const float* pseq = (const float*)d_in[4];
    const float* dseq = (const float*)d_in[5];
    const float* pc1w = (const float*)d_in[6];  const float* pc1b = (const float*)d_in[7];
    const float* pc2w = (const float*)d_in[8];  const float* pc2b = (const float*)d_in[9];
    const float* dc1w = (const float*)d_in[10]; const float* dc1b = (const float*)d_in[11];
    const float* dc2w = (const float*)d_in[12]; const float* dc2b = (const float*)d_in[13];
    const float* psw1 = (const float*)d_in[14]; const float* psb1 = (const float*)d_in[15];
    const float* psw2 = (const float*)d_in[16]; const float* psb2 = (const float*)d_in[17];
    const float* dsw1 = (const float*)d_in[18]; const float* dsb1 = (const float*)d_in[19];
    const float* dsw2 = (const float*)d_in[20]; const float* dsb2 = (const float*)d_in[21];
    const float* fc1w = (const float*)d_in[22]; const float* fc1b = (const float*)d_in[23];
    const float* fc2w = (const float*)d_in[24]; const float* fc2b = (const float*)d_in[25];

    const int Np = in_sizes[0] / 128, Ep = in_sizes[1] / 2;
    const int Nd = in_sizes[2] / 64,  Ed = in_sizes[3] / 2;
    const int Psd = in_sizes[4], Dsd = in_sizes[5];

    char* w = (char*)d_ws;
    size_t off = 0;
    auto carve = [&](size_t bytes) -> void* {
        void* p = w + off;
        off = align_up(off + bytes, 256);
        return p;
    };
    unsigned short* bufA = (unsigned short*)carve((size_t)Np * 128 * 2);  // bf16 msg table
    float* bufB    = (float*)carve((size_t)Np * 128 * 4);
    int*   col     = (int*)carve((size_t)Ep * 4);
    unsigned* ebuf = (unsigned*)carve((size_t)Ep * 4);
    int*   bcnt    = (int*)carve((size_t)NCB * 256 * 4);
    int*   bbase   = (int*)carve(257 * 4);
    int*   rowptr  = (int*)carve(((size_t)Np + 1) * 4);
    float* dinv    = (float*)carve((size_t)Np * 4);
    float* partial = (float*)carve((size_t)MP_NB * 128 * 4);
    float* mlpp    = (float*)carve((size_t)MLP_NB * 128 * 4);
    float* pmean   = (float*)carve(512);
    float* dmean   = (float*)carve(512);
    float* pseqo   = (float*)carve(512);
    float* dseqo   = (float*)carve(512);
    float* comb    = (float*)carve(2048);
    (void)ws_size; (void)n_in; (void)out_size;

    auto run_gcn = [&](const float* x, const int* ei, int n, int E, int IN,
                       const float* W1, const float* b1,
                       const float* W2, const float* b2, float* meano) {
        const int* srcp = ei;
        const int* dstp = ei + E;
        const int chunk = (((E + NCB - 1) / NCB) + 255) & ~255;
        const int nbk = (n + BW - 1) >> BSH;

        csr_hist <<<NCB, 256, 0, stream>>>(dstp, E, chunk, bcnt);
        csr_scan <<<1, 256, 0, stream>>>(bcnt, bbase);
        csr_place<<<NCB, 256, 0, stream>>>(srcp, dstp, E, chunk, bcnt, bbase, ebuf);
        csr_finish<<<nbk, 256, 0, stream>>>(ebuf, bbase, n, E, rowptr, dinv, col);

        // conv1
        if (IN == 128) xw_matmul<128><<<(n + 63) / 64, 256, 0, stream>>>(x, W1, dinv, bufA, n);
        else           xw_matmul<64><<<(n + 63) / 64, 256, 0, stream>>>(x, W1, dinv, bufA, n);
        gcn_agg<<<n, 128, 0, stream>>>(bufA, rowptr, col, dinv, b1, bufB);
        // conv2
        xw_matmul<128><<<(n + 63) / 64, 256, 0, stream>>>(bufB, W2, dinv, bufA, n);
        gcn_agg<<<n, 128, 0, stream>>>(bufA, rowptr, col, dinv, b2, bufB);
        // mean over nodes
        mean_partial<<<MP_NB, 256, 0, stream>>>(bufB, n, partial);
        mean_finish<<<1, 256, 0, stream>>>(partial, 1.0f / (float)n, meano);
    };

    run_gcn(px, pei, Np, Ep, 128, pc1w, pc1b, pc2w, pc2b, pmean);
    run_gcn(dx, dei, Nd, Ed, 64,  dc1w, dc1b, dc2w, dc2b, dmean);

    // seq MLPs (parallelized)
    mlp_l1_partial<<<MLP_NB, 256, 0, stream>>>(pseq, psw1, Psd, mlpp);
    mlp_seq_finish<<<1, 128, 0, stream>>>(mlpp, psb1, psw2, psb2, pseqo);
    mlp_l1_partial<<<MLP_NB, 256, 0, stream>>>(dseq, dsw1, Dsd, mlpp);
    mlp_seq_finish<<<1, 128, 0, stream>>>(mlpp, dsb1, dsw2, dsb2, dseqo);

    // head
    concat4<<<1, 128, 0, stream>>>(pmean, dmean, pseqo, dseqo, comb);
    mlp_l1_partial<<<MLP_NB, 256, 0, stream>>>(comb, fc1w, 512, mlpp);
    head_finish<<<1, 128, 0, stream>>>(mlpp, fc1b, fc2w, fc2b, (float*)d_out);
}

// Round 5
// 845.131 us; speedup vs baseline: 2.6864x; 1.2618x over previous
//
#include <hip/hip_runtime.h>
#include <cstdint>
#include <cstddef>

// ---------------------------------------------------------------------------
// GSF-DTA forward: 2x GCNConv (protein), 2x GCNConv (drug), 2 seq MLPs, head.
// R5: xw matmul -> MFMA 16x16x32 bf16 (was f32 VALU, 174us, 18% occ, bank
//     conflicts). W staged bf16-transposed in LDS w/ chunk-XOR swizzle.
// CSR build: 2-level bucket sort (R4). gcn_agg: bf16 gather (R3).
// ---------------------------------------------------------------------------

#define NCB 256     // chunk blocks for edge passes
#define BSH 9       // bucket shift: 512 nodes per bucket (needs n <= 131072)
#define BW  512     // 1 << BSH

typedef __attribute__((ext_vector_type(8))) short bf16x8;
typedef __attribute__((ext_vector_type(4))) float f32x4;

static __device__ __forceinline__ float bf2f(unsigned short u) {
    union { unsigned int i; float f; } v; v.i = ((unsigned int)u) << 16; return v.f;
}
static __device__ __forceinline__ unsigned short f2bf(float f) {
    union { float f; unsigned int i; } v; v.f = f;
    unsigned int r = v.i + 0x7fffu + ((v.i >> 16) & 1u);   // round-nearest-even
    return (unsigned short)(r >> 16);
}

// ---- CSR build: bucket sort by dst ------------------------------------------
__global__ __launch_bounds__(256) void csr_hist(const int* __restrict__ dst, int E, int chunk,
                                                int* __restrict__ bcnt) {
    __shared__ int h[256];
    const int t = threadIdx.x, blk = blockIdx.x;
    h[t] = 0; __syncthreads();
    const int e0 = blk * chunk;
    const int e1 = min(E, e0 + chunk);
    for (int e = e0 + t; e < e1; e += 256) atomicAdd(&h[dst[e] >> BSH], 1);
    __syncthreads();
    bcnt[blk * 256 + t] = h[t];
}

__global__ __launch_bounds__(256) void csr_scan(int* __restrict__ bcnt, int* __restrict__ bbase) {
    const int t = threadIdx.x;
    int run = 0;
    for (int blk = 0; blk < NCB; ++blk) {
        int idx = blk * 256 + t;
        int v = bcnt[idx]; bcnt[idx] = run; run += v;
    }
    __shared__ int sh[256];
    sh[t] = run; __syncthreads();
    for (int off = 1; off < 256; off <<= 1) {
        int add = (t >= off) ? sh[t - off] : 0;
        __syncthreads(); sh[t] += add; __syncthreads();
    }
    bbase[t] = sh[t] - run;              // exclusive scan over buckets
    if (t == 255) bbase[256] = sh[255];  // == E
}

__global__ __launch_bounds__(256) void csr_place(const int* __restrict__ src,
                                                 const int* __restrict__ dst, int E, int chunk,
                                                 const int* __restrict__ bcnt,
                                                 const int* __restrict__ bbase,
                                                 unsigned* __restrict__ ebuf) {
    __shared__ int cur[256];
    const int t = threadIdx.x, blk = blockIdx.x;
    cur[t] = bbase[t] + bcnt[blk * 256 + t];
    __syncthreads();
    const int e0 = blk * chunk;
    const int e1 = min(E, e0 + chunk);
    for (int e = e0 + t; e < e1; e += 256) {
        int d = dst[e];
        int b = d >> BSH;
        int pos = atomicAdd(&cur[b], 1);
        ebuf[pos] = ((unsigned)src[e] << BSH) | (unsigned)(d & (BW - 1));
    }
}

// one block per bucket: per-node histogram -> dinv + rowptr, then scatter col.
__global__ __launch_bounds__(256) void csr_finish(const unsigned* __restrict__ ebuf,
                                                  const int* __restrict__ bbase,
                                                  int n, int E,
                                                  int* __restrict__ rowptr,
                                                  float* __restrict__ dinv,
                                                  int* __restrict__ col) {
    __shared__ int hist[BW];
    __shared__ int cur[BW];
    __shared__ int sh[256];
    const int t = threadIdx.x, b = blockIdx.x;
    const int nb = b << BSH;
    const int w = min(BW, n - nb);
    const int rb = bbase[b], re = bbase[b + 1];
    hist[2 * t] = 0; hist[2 * t + 1] = 0;
    __syncthreads();
    for (int i = rb + t; i < re; i += 256) atomicAdd(&hist[ebuf[i] & (BW - 1)], 1);
    __syncthreads();
    const int a0 = hist[2 * t], a1 = hist[2 * t + 1];
    if (2 * t     < w) dinv[nb + 2 * t]     = rsqrtf((float)(a0 + 1));
    if (2 * t + 1 < w) dinv[nb + 2 * t + 1] = rsqrtf((float)(a1 + 1));
    sh[t] = a0 + a1; __syncthreads();
    for (int off = 1; off < 256; off <<= 1) {
        int add = (t >= off) ? sh[t - off] : 0;
        __syncthreads(); sh[t] += add; __syncthreads();
    }
    int base = t ? sh[t - 1] : 0;
    const int p0 = rb + base, p1 = rb + base + a0;
    if (2 * t     < w) rowptr[nb + 2 * t]     = p0;
    if (2 * t + 1 < w) rowptr[nb + 2 * t + 1] = p1;
    cur[2 * t] = p0; cur[2 * t + 1] = p1;
    __syncthreads();
    for (int i = rb + t; i < re; i += 256) {
        unsigned r = ebuf[i];
        int pos = atomicAdd(&cur[r & (BW - 1)], 1);
        col[pos] = (int)(r >> BSH);
    }
    if (b == 0 && t == 0) rowptr[n] = E;
}

// ---- x@W via MFMA bf16; out = bf16( dinv[row] * (x@W) ) ---------------------
// Block: 256 threads = 4 waves; 64 rows x 128 cols per block.
// W[K][128] staged to LDS as Wt[col][k] bf16, 16B-chunk XOR-swizzled.
template <int K>
__global__ __launch_bounds__(256) void xw_mfma(const float* __restrict__ x,
                                               const float* __restrict__ W,
                                               const float* __restrict__ dinv,
                                               unsigned short* __restrict__ out, int n) {
    constexpr int CH = K / 8;          // 16B chunks per column
    constexpr int KS = K / 32;         // mfma k-steps
    __shared__ short Wt[128 * K];
    const int tid = threadIdx.x;

    // stage: thread handles one (col, ch) pair = 8 consecutive k for one col
    for (int i = tid; i < 128 * CH; i += 256) {
        const int col = i / CH, ch = i % CH;
        bf16x8 v;
        #pragma unroll
        for (int j = 0; j < 8; ++j) v[j] = (short)f2bf(W[(ch * 8 + j) * 128 + col]);
        *(bf16x8*)&Wt[(col * CH + (ch ^ (col & (CH - 1)))) * 8] = v;
    }
    __syncthreads();

    const int wv = tid >> 6, ln = tid & 63;
    const int r0 = blockIdx.x * 64 + wv * 16;
    const int row = r0 + (ln & 15);
    const int kg = (ln >> 4) * 8;

    bf16x8 a[KS];
    if (row < n) {
        const float* xr = x + (size_t)row * K;
        #pragma unroll
        for (int ks = 0; ks < KS; ++ks) {
            float4 u0 = *(const float4*)&xr[ks * 32 + kg];
            float4 u1 = *(const float4*)&xr[ks * 32 + kg + 4];
            bf16x8 v;
            v[0] = (short)f2bf(u0.x); v[1] = (short)f2bf(u0.y);
            v[2] = (short)f2bf(u0.z); v[3] = (short)f2bf(u0.w);
            v[4] = (short)f2bf(u1.x); v[5] = (short)f2bf(u1.y);
            v[6] = (short)f2bf(u1.z); v[7] = (short)f2bf(u1.w);
            a[ks] = v;
        }
    } else {
        #pragma unroll
        for (int ks = 0; ks < KS; ++ks) {
            bf16x8 v;
            #pragma unroll
            for (int j = 0; j < 8; ++j) v[j] = 0;
            a[ks] = v;
        }
    }

    // dinv for this lane's 4 output rows
    const int rw0 = r0 + (ln >> 4) * 4;
    float dv[4];
    #pragma unroll
    for (int r = 0; r < 4; ++r) dv[r] = (rw0 + r < n) ? dinv[rw0 + r] : 0.f;

    const int cl = ln & 15;
    #pragma unroll
    for (int nt = 0; nt < 8; ++nt) {
        const int col = nt * 16 + cl;
        f32x4 c = {0.f, 0.f, 0.f, 0.f};
        #pragma unroll
        for (int ks = 0; ks < KS; ++ks) {
            const int ch = ks * 4 + (ln >> 4);
            bf16x8 b = *(const bf16x8*)&Wt[(col * CH + (ch ^ (col & (CH - 1)))) * 8];
            c = __builtin_amdgcn_mfma_f32_16x16x32_bf16(a[ks], b, c, 0, 0, 0);
        }
        #pragma unroll
        for (int r = 0; r < 4; ++r) {
            const int rr = rw0 + r;
            if (rr < n) out[(size_t)rr * 128 + col] = f2bf(c[r] * dv[r]);
        }
    }
}

// ---- aggregation: one node per 128-thread block -----------------------------
__global__ __launch_bounds__(128) void gcn_agg(const unsigned short* __restrict__ xwn,
                                               const int* __restrict__ rowptr,
                                               const int* __restrict__ col,
                                               const float* __restrict__ dinv,
                                               const float* __restrict__ bias,
                                               float* __restrict__ out) {
    const int d = blockIdx.x;
    const int t = threadIdx.x;
    __shared__ int cs[128];
    const int beg = rowptr[d], end = rowptr[d + 1];
    const float dv = dinv[d];
    float acc = bf2f(xwn[(size_t)d * 128 + t]);   // self-loop term
    for (int base = beg; base < end; base += 128) {
        int m = end - base; if (m > 128) m = 128;
        if (t < m) cs[t] = col[base + t];
        __syncthreads();
        #pragma unroll 8
        for (int j = 0; j < m; ++j)
            acc += bf2f(xwn[(size_t)cs[j] * 128 + t]);
        __syncthreads();
    }
    float r = fmaf(dv, acc, bias[t]);
    out[(size_t)d * 128 + t] = fmaxf(r, 0.f);
}

// ---- mean over rows (coalesced float4) --------------------------------------
#define MP_NB 1024
__global__ __launch_bounds__(256) void mean_partial(const float* __restrict__ h, int n,
                                                    float* __restrict__ partial) {
    const int t = threadIdx.x, b = blockIdx.x;
    const int rpb = (n + MP_NB - 1) / MP_NB;
    const int r0 = b * rpb, r1 = min(n, r0 + rpb);
    const int c4 = (t & 31) * 4;
    float4 acc = make_float4(0.f, 0.f, 0.f, 0.f);
    for (int r = r0 + (t >> 5); r < r1; r += 8) {
        float4 v = *(const float4*)&h[(size_t)r * 128 + c4];
        acc.x += v.x; acc.y += v.y; acc.z += v.z; acc.w += v.w;
    }
    __shared__ float4 sh[256];
    sh[t] = acc; __syncthreads();
    for (int off = 128; off >= 32; off >>= 1) {
        if (t < off) {
            float4 a = sh[t], o = sh[t + off];
            a.x += o.x; a.y += o.y; a.z += o.z; a.w += o.w;
            sh[t] = a;
        }
        __syncthreads();
    }
    if (t < 32) *(float4*)&partial[(size_t)b * 128 + c4] = sh[t];
}

__global__ __launch_bounds__(256) void mean_finish(const float* __restrict__ partial, float inv_n,
                                                   float* __restrict__ out) {
    const int t = threadIdx.x;
    const int c4 = (t & 31) * 4;
    float4 acc = make_float4(0.f, 0.f, 0.f, 0.f);
    for (int r = (t >> 5); r < MP_NB; r += 8) {
        float4 v = *(const float4*)&partial[(size_t)r * 128 + c4];
        acc.x += v.x; acc.y += v.y; acc.z += v.z; acc.w += v.w;
    }
    __shared__ float4 sh[256];
    sh[t] = acc; __syncthreads();
    for (int off = 128; off >= 32; off >>= 1) {
        if (t < off) {
            float4 a = sh[t], o = sh[t + off];
            a.x += o.x; a.y += o.y; a.z += o.z; a.w += o.w;
            sh[t] = a;
        }
        __syncthreads();
    }
    if (t < 32) {
        float4 a = sh[t];
        a.x *= inv_n; a.y *= inv_n; a.z *= inv_n; a.w *= inv_n;
        *(float4*)&out[c4] = a;
    }
}

// ---- parallel MLP: layer-1 partial over 64 k-slices -------------------------
#define MLP_NB 64
__global__ __launch_bounds__(256) void mlp_l1_partial(const float* __restrict__ in,
                                                      const float* __restrict__ w1, int IN,
                                                      float* __restrict__ partial) {
    const int b = blockIdx.x;
    const int t = threadIdx.x;
    const int f = t & 127;
    const int half = t >> 7;
    const int kpb = IN / MLP_NB;
    const int k0 = b * kpb;
    float acc = 0.f;
    #pragma unroll 4
    for (int k = k0 + half; k < k0 + kpb; k += 2)
        acc = fmaf(in[k], w1[(size_t)k * 128 + f], acc);
    __shared__ float sh[256];
    sh[t] = acc; __syncthreads();
    if (half == 0) partial[b * 128 + f] = sh[f] + sh[128 + f];
}

__global__ __launch_bounds__(128) void mlp_seq_finish(const float* __restrict__ partial,
                                                      const float* __restrict__ b1,
                                                      const float* __restrict__ w2,
                                                      const float* __restrict__ b2,
                                                      float* __restrict__ out) {
    const int t = threadIdx.x;
    __shared__ float h[128];
    float s = 0.f;
    #pragma unroll 8
    for (int i = 0; i < MLP_NB; ++i) s += partial[i * 128 + t];
    h[t] = fmaxf(s + b1[t], 0.f);
    __syncthreads();
    float acc = 0.f;
    #pragma unroll 8
    for (int k = 0; k < 128; ++k) acc = fmaf(h[k], w2[k * 128 + t], acc);
    out[t] = fmaxf(acc + b2[t], 0.f);
}

__global__ __launch_bounds__(128) void head_finish(const float* __restrict__ partial,
                                                   const float* __restrict__ fc1b,
                                                   const float* __restrict__ fc2w,
                                                   const float* __restrict__ fc2b,
                                                   float* __restrict__ out) {
    const int t = threadIdx.x;
    __shared__ float red[128];
    float s = 0.f;
    #pragma unroll 8
    for (int i = 0; i < MLP_NB; ++i) s += partial[i * 128 + t];
    float h = fmaxf(s + fc1b[t], 0.f);
    red[t] = h * fc2w[t];
    __syncthreads();
    for (int off = 64; off > 0; off >>= 1) {
        if (t < off) red[t] += red[t + off];
        __syncthreads();
    }
    if (t == 0) out[0] = red[0] + fc2b[0];
}

__global__ void concat4(const float* __restrict__ a, const float* __restrict__ b,
                        const float* __restrict__ c, const float* __restrict__ d,
                        float* __restrict__ out) {
    int t = threadIdx.x;
    out[t] = a[t]; out[128 + t] = b[t]; out[256 + t] = c[t]; out[384 + t] = d[t];
}

static inline size_t align_up(size_t x, size_t a) { return (x + a - 1) / a * a; }

extern "C" void kernel_launch(void* const* d_in, const int* in_sizes, int n_in,
                              void* d_out, int out_size, void* d_ws, size_t ws_size,
                              hipStream_t stream) {
    const float* px   = (const float*)d_in[0];
    const int*   pei  = (const int*)d_in[1];
    const float* dx   = (const float*)d_in[2];
    const int*   dei  = (const int*)d_in[3];
    const float* pseq = (const float*)d_in[4];
    const float* dseq = (const float*)d_in[5];
    const float* pc1w = (const float*)d_in[6];  const float* pc1b = (const float*)d_in[7];
    const float* pc2w = (const float*)d_in[8];  const float* pc2b = (const float*)d_in[9];
    const float* dc1w = (const float*)d_in[10]; const float* dc1b = (const float*)d_in[11];
    const float* dc2w = (const float*)d_in[12]; const float* dc2b = (const float*)d_in[13];
    const float* psw1 = (const float*)d_in[14]; const float* psb1 = (const float*)d_in[15];
    const float* psw2 = (const float*)d_in[16]; const float* psb2 = (const float*)d_in[17];
    const float* dsw1 = (const float*)d_in[18]; const float* dsb1 = (const float*)d_in[19];
    const float* dsw2 = (const float*)d_in[20]; const float* dsb2 = (const float*)d_in[21];
    const float* fc1w = (const float*)d_in[22]; const float* fc1b = (const float*)d_in[23];
    const float* fc2w = (const float*)d_in[24]; const float* fc2b = (const float*)d_in[25];

    const int Np = in_sizes[0] / 128, Ep = in_sizes[1] / 2;
    const int Nd = in_sizes[2] / 64,  Ed = in_sizes[3] / 2;
    const int Psd = in_sizes[4], Dsd = in_sizes[5];

    char* w = (char*)d_ws;
    size_t off = 0;
    auto carve = [&](size_t bytes) -> void* {
        void* p = w + off;
        off = align_up(off + bytes, 256);
        return p;
    };
    unsigned short* bufA = (unsigned short*)carve((size_t)Np * 128 * 2);  // bf16 msg table
    float* bufB    = (float*)carve((size_t)Np * 128 * 4);
    int*   col     = (int*)carve((size_t)Ep * 4);
    unsigned* ebuf = (unsigned*)carve((size_t)Ep * 4);
    int*   bcnt    = (int*)carve((size_t)NCB * 256 * 4);
    int*   bbase   = (int*)carve(257 * 4);
    int*   rowptr  = (int*)carve(((size_t)Np + 1) * 4);
    float* dinv    = (float*)carve((size_t)Np * 4);
    float* partial = (float*)carve((size_t)MP_NB * 128 * 4);
    float* mlpp    = (float*)carve((size_t)MLP_NB * 128 * 4);
    float* pmean   = (float*)carve(512);
    float* dmean   = (float*)carve(512);
    float* pseqo   = (float*)carve(512);
    float* dseqo   = (float*)carve(512);
    float* comb    = (float*)carve(2048);
    (void)ws_size; (void)n_in; (void)out_size;

    auto run_gcn = [&](const float* x, const int* ei, int n, int E, int IN,
                       const float* W1, const float* b1,
                       const float* W2, const float* b2, float* meano) {
        const int* srcp = ei;
        const int* dstp = ei + E;
        const int chunk = (((E + NCB - 1) / NCB) + 255) & ~255;
        const int nbk = (n + BW - 1) >> BSH;

        csr_hist <<<NCB, 256, 0, stream>>>(dstp, E, chunk, bcnt);
        csr_scan <<<1, 256, 0, stream>>>(bcnt, bbase);
        csr_place<<<NCB, 256, 0, stream>>>(srcp, dstp, E, chunk, bcnt, bbase, ebuf);
        csr_finish<<<nbk, 256, 0, stream>>>(ebuf, bbase, n, E, rowptr, dinv, col);

        // conv1
        if (IN == 128) xw_mfma<128><<<(n + 63) / 64, 256, 0, stream>>>(x, W1, dinv, bufA, n);
        else           xw_mfma<64><<<(n + 63) / 64, 256, 0, stream>>>(x, W1, dinv, bufA, n);
        gcn_agg<<<n, 128, 0, stream>>>(bufA, rowptr, col, dinv, b1, bufB);
        // conv2
        xw_mfma<128><<<(n + 63) / 64, 256, 0, stream>>>(bufB, W2, dinv, bufA, n);
        gcn_agg<<<n, 128, 0, stream>>>(bufA, rowptr, col, dinv, b2, bufB);
        // mean over nodes
        mean_partial<<<MP_NB, 256, 0, stream>>>(bufB, n, partial);
        mean_finish<<<1, 256, 0, stream>>>(partial, 1.0f / (float)n, meano);
    };

    run_gcn(px, pei, Np, Ep, 128, pc1w, pc1b, pc2w, pc2b, pmean);
    run_gcn(dx, dei, Nd, Ed, 64,  dc1w, dc1b, dc2w, dc2b, dmean);

    // seq MLPs (parallelized)
    mlp_l1_partial<<<MLP_NB, 256, 0, stream>>>(pseq, psw1, Psd, mlpp);
    mlp_seq_finish<<<1, 128, 0, stream>>>(mlpp, psb1, psw2, psb2, pseqo);
    mlp_l1_partial<<<MLP_NB, 256, 0, stream>>>(dseq, dsw1, Dsd, mlpp);
    mlp_seq_finish<<<1, 128, 0, stream>>>(mlpp, dsb1, dsw2, dsb2, dseqo);

    // head
    concat4<<<1, 128, 0, stream>>>(pmean, dmean, pseqo, dseqo, comb);
    mlp_l1_partial<<<MLP_NB, 256, 0, stream>>>(comb, fc1w, 512, mlpp);
    head_finish<<<1, 128, 0, stream>>>(mlpp, fc1b, fc2w, fc2b, (float*)d_out);
}

// Round 6
// 783.443 us; speedup vs baseline: 2.8979x; 1.0787x over previous
//
#include <hip/hip_runtime.h>
#include <cstdint>
#include <cstddef>

// ---------------------------------------------------------------------------
// GSF-DTA forward: 2x GCNConv (protein), 2x GCNConv (drug), 2 seq MLPs, head.
// R6: fp16 message table + wave-per-node barrier-free gather with v_pk_add_f16
//     (gcn_agg was 54% VALU-busy with 2B loads + barriers at mean degree 32).
//     xw matmul -> MFMA 16x16x32 f16; conv1->conv2 hidden state kept in f16.
// CSR build: 2-level bucket sort (R4).
// ---------------------------------------------------------------------------

#define NCB 256     // chunk blocks for edge passes
#define BSH 9       // bucket shift: 512 nodes per bucket (needs n <= 131072)
#define BW  512     // 1 << BSH

typedef __attribute__((ext_vector_type(8))) _Float16 f16x8;
typedef __attribute__((ext_vector_type(2))) _Float16 f16x2;
typedef __attribute__((ext_vector_type(4))) float f32x4;

static __device__ __forceinline__ unsigned short f2h(float f) {
    _Float16 h = (_Float16)f;
    return __builtin_bit_cast(unsigned short, h);
}

// ---- CSR build: bucket sort by dst ------------------------------------------
__global__ __launch_bounds__(256) void csr_hist(const int* __restrict__ dst, int E, int chunk,
                                                int* __restrict__ bcnt) {
    __shared__ int h[256];
    const int t = threadIdx.x, blk = blockIdx.x;
    h[t] = 0; __syncthreads();
    const int e0 = blk * chunk;
    const int e1 = min(E, e0 + chunk);
    for (int e = e0 + t; e < e1; e += 256) atomicAdd(&h[dst[e] >> BSH], 1);
    __syncthreads();
    bcnt[blk * 256 + t] = h[t];
}

__global__ __launch_bounds__(256) void csr_scan(int* __restrict__ bcnt, int* __restrict__ bbase) {
    const int t = threadIdx.x;
    int run = 0;
    for (int blk = 0; blk < NCB; ++blk) {
        int idx = blk * 256 + t;
        int v = bcnt[idx]; bcnt[idx] = run; run += v;
    }
    __shared__ int sh[256];
    sh[t] = run; __syncthreads();
    for (int off = 1; off < 256; off <<= 1) {
        int add = (t >= off) ? sh[t - off] : 0;
        __syncthreads(); sh[t] += add; __syncthreads();
    }
    bbase[t] = sh[t] - run;              // exclusive scan over buckets
    if (t == 255) bbase[256] = sh[255];  // == E
}

__global__ __launch_bounds__(256) void csr_place(const int* __restrict__ src,
                                                 const int* __restrict__ dst, int E, int chunk,
                                                 const int* __restrict__ bcnt,
                                                 const int* __restrict__ bbase,
                                                 unsigned* __restrict__ ebuf) {
    __shared__ int cur[256];
    const int t = threadIdx.x, blk = blockIdx.x;
    cur[t] = bbase[t] + bcnt[blk * 256 + t];
    __syncthreads();
    const int e0 = blk * chunk;
    const int e1 = min(E, e0 + chunk);
    for (int e = e0 + t; e < e1; e += 256) {
        int d = dst[e];
        int b = d >> BSH;
        int pos = atomicAdd(&cur[b], 1);
        ebuf[pos] = ((unsigned)src[e] << BSH) | (unsigned)(d & (BW - 1));
    }
}

// one block per bucket: per-node histogram -> dinv + rowptr, then scatter col.
__global__ __launch_bounds__(256) void csr_finish(const unsigned* __restrict__ ebuf,
                                                  const int* __restrict__ bbase,
                                                  int n, int E,
                                                  int* __restrict__ rowptr,
                                                  float* __restrict__ dinv,
                                                  int* __restrict__ col) {
    __shared__ int hist[BW];
    __shared__ int cur[BW];
    __shared__ int sh[256];
    const int t = threadIdx.x, b = blockIdx.x;
    const int nb = b << BSH;
    const int w = min(BW, n - nb);
    const int rb = bbase[b], re = bbase[b + 1];
    hist[2 * t] = 0; hist[2 * t + 1] = 0;
    __syncthreads();
    for (int i = rb + t; i < re; i += 256) atomicAdd(&hist[ebuf[i] & (BW - 1)], 1);
    __syncthreads();
    const int a0 = hist[2 * t], a1 = hist[2 * t + 1];
    if (2 * t     < w) dinv[nb + 2 * t]     = rsqrtf((float)(a0 + 1));
    if (2 * t + 1 < w) dinv[nb + 2 * t + 1] = rsqrtf((float)(a1 + 1));
    sh[t] = a0 + a1; __syncthreads();
    for (int off = 1; off < 256; off <<= 1) {
        int add = (t >= off) ? sh[t - off] : 0;
        __syncthreads(); sh[t] += add; __syncthreads();
    }
    int base = t ? sh[t - 1] : 0;
    const int p0 = rb + base, p1 = rb + base + a0;
    if (2 * t     < w) rowptr[nb + 2 * t]     = p0;
    if (2 * t + 1 < w) rowptr[nb + 2 * t + 1] = p1;
    cur[2 * t] = p0; cur[2 * t + 1] = p1;
    __syncthreads();
    for (int i = rb + t; i < re; i += 256) {
        unsigned r = ebuf[i];
        int pos = atomicAdd(&cur[r & (BW - 1)], 1);
        col[pos] = (int)(r >> BSH);
    }
    if (b == 0 && t == 0) rowptr[n] = E;
}

// ---- x@W via MFMA f16; out(f16) = dinv[row] * (x@W) -------------------------
// Block: 256 threads = 4 waves; 64 rows x 128 cols per block.
// W[K][128] staged to LDS as Wt[col][k] f16, 16B-chunk XOR-swizzled.
template <int K, bool IN16>
__global__ __launch_bounds__(256) void xw_mfma(const void* __restrict__ xv,
                                               const float* __restrict__ W,
                                               const float* __restrict__ dinv,
                                               unsigned short* __restrict__ out, int n) {
    constexpr int CH = K / 8;          // 16B chunks per column
    constexpr int KS = K / 32;         // mfma k-steps
    __shared__ _Float16 Wt[128 * K];
    const int tid = threadIdx.x;

    for (int i = tid; i < 128 * CH; i += 256) {
        const int col = i / CH, ch = i % CH;
        f16x8 v;
        #pragma unroll
        for (int j = 0; j < 8; ++j) v[j] = (_Float16)W[(ch * 8 + j) * 128 + col];
        *(f16x8*)&Wt[(col * CH + (ch ^ (col & (CH - 1)))) * 8] = v;
    }
    __syncthreads();

    const int wv = tid >> 6, ln = tid & 63;
    const int r0 = blockIdx.x * 64 + wv * 16;
    const int row = r0 + (ln & 15);
    const int kg = (ln >> 4) * 8;

    f16x8 a[KS];
    if (row < n) {
        if constexpr (IN16) {
            const unsigned short* xr = (const unsigned short*)xv + (size_t)row * K;
            #pragma unroll
            for (int ks = 0; ks < KS; ++ks)
                a[ks] = *(const f16x8*)&xr[ks * 32 + kg];
        } else {
            const float* xr = (const float*)xv + (size_t)row * K;
            #pragma unroll
            for (int ks = 0; ks < KS; ++ks) {
                float4 u0 = *(const float4*)&xr[ks * 32 + kg];
                float4 u1 = *(const float4*)&xr[ks * 32 + kg + 4];
                f16x8 v;
                v[0] = (_Float16)u0.x; v[1] = (_Float16)u0.y;
                v[2] = (_Float16)u0.z; v[3] = (_Float16)u0.w;
                v[4] = (_Float16)u1.x; v[5] = (_Float16)u1.y;
                v[6] = (_Float16)u1.z; v[7] = (_Float16)u1.w;
                a[ks] = v;
            }
        }
    } else {
        #pragma unroll
        for (int ks = 0; ks < KS; ++ks) {
            f16x8 v;
            #pragma unroll
            for (int j = 0; j < 8; ++j) v[j] = (_Float16)0.f;
            a[ks] = v;
        }
    }

    const int rw0 = r0 + (ln >> 4) * 4;
    float dv[4];
    #pragma unroll
    for (int r = 0; r < 4; ++r) dv[r] = (rw0 + r < n) ? dinv[rw0 + r] : 0.f;

    const int cl = ln & 15;
    #pragma unroll
    for (int nt = 0; nt < 8; ++nt) {
        const int col = nt * 16 + cl;
        f32x4 c = {0.f, 0.f, 0.f, 0.f};
        #pragma unroll
        for (int ks = 0; ks < KS; ++ks) {
            const int ch = ks * 4 + (ln >> 4);
            f16x8 b = *(const f16x8*)&Wt[(col * CH + (ch ^ (col & (CH - 1)))) * 8];
            c = __builtin_amdgcn_mfma_f32_16x16x32_f16(a[ks], b, c, 0, 0, 0);
        }
        #pragma unroll
        for (int r = 0; r < 4; ++r) {
            const int rr = rw0 + r;
            if (rr < n) out[(size_t)rr * 128 + col] = f2h(c[r] * dv[r]);
        }
    }
}

// ---- aggregation: one WAVE per node, no barriers, packed f16 adds -----------
// tab rows: 128 f16 = 64 uints; lane ln owns features 2ln, 2ln+1.
template <bool OUT16>
__global__ __launch_bounds__(256) void gcn_agg(const unsigned* __restrict__ tab,
                                               const int* __restrict__ rowptr,
                                               const int* __restrict__ col,
                                               const float* __restrict__ dinv,
                                               const float* __restrict__ bias,
                                               void* __restrict__ outv, int n) {
    const int wv = threadIdx.x >> 6, ln = threadIdx.x & 63;
    const int d = blockIdx.x * 4 + wv;
    if (d >= n) return;
    const int beg = rowptr[d], end = rowptr[d + 1];

    f16x2 acc0 = __builtin_bit_cast(f16x2, tab[(size_t)d * 64 + ln]);   // self-loop
    f16x2 acc1; acc1[0] = (_Float16)0.f; acc1[1] = (_Float16)0.f;

    int j = beg;
    #pragma unroll 8
    for (; j + 1 < end; j += 2) {
        int s0 = col[j];
        int s1 = col[j + 1];
        acc0 += __builtin_bit_cast(f16x2, tab[(size_t)s0 * 64 + ln]);
        acc1 += __builtin_bit_cast(f16x2, tab[(size_t)s1 * 64 + ln]);
    }
    if (j < end) {
        int s = col[j];
        acc0 += __builtin_bit_cast(f16x2, tab[(size_t)s * 64 + ln]);
    }

    const float a0 = (float)acc0[0] + (float)acc1[0];
    const float a1 = (float)acc0[1] + (float)acc1[1];
    const float dv = dinv[d];
    const float2 bb = *(const float2*)&bias[2 * ln];
    const float r0 = fmaxf(fmaf(dv, a0, bb.x), 0.f);
    const float r1 = fmaxf(fmaf(dv, a1, bb.y), 0.f);
    if constexpr (OUT16) {
        ushort2 o; o.x = f2h(r0); o.y = f2h(r1);
        ((ushort2*)outv)[(size_t)d * 64 + ln] = o;
    } else {
        ((float2*)outv)[(size_t)d * 64 + ln] = make_float2(r0, r1);
    }
}

// ---- mean over rows (coalesced float4) --------------------------------------
#define MP_NB 1024
__global__ __launch_bounds__(256) void mean_partial(const float* __restrict__ h, int n,
                                                    float* __restrict__ partial) {
    const int t = threadIdx.x, b = blockIdx.x;
    const int rpb = (n + MP_NB - 1) / MP_NB;
    const int r0 = b * rpb, r1 = min(n, r0 + rpb);
    const int c4 = (t & 31) * 4;
    float4 acc = make_float4(0.f, 0.f, 0.f, 0.f);
    for (int r = r0 + (t >> 5); r < r1; r += 8) {
        float4 v = *(const float4*)&h[(size_t)r * 128 + c4];
        acc.x += v.x; acc.y += v.y; acc.z += v.z; acc.w += v.w;
    }
    __shared__ float4 sh[256];
    sh[t] = acc; __syncthreads();
    for (int off = 128; off >= 32; off >>= 1) {
        if (t < off) {
            float4 a = sh[t], o = sh[t + off];
            a.x += o.x; a.y += o.y; a.z += o.z; a.w += o.w;
            sh[t] = a;
        }
        __syncthreads();
    }
    if (t < 32) *(float4*)&partial[(size_t)b * 128 + c4] = sh[t];
}

__global__ __launch_bounds__(256) void mean_finish(const float* __restrict__ partial, float inv_n,
                                                   float* __restrict__ out) {
    const int t = threadIdx.x;
    const int c4 = (t & 31) * 4;
    float4 acc = make_float4(0.f, 0.f, 0.f, 0.f);
    for (int r = (t >> 5); r < MP_NB; r += 8) {
        float4 v = *(const float4*)&partial[(size_t)r * 128 + c4];
        acc.x += v.x; acc.y += v.y; acc.z += v.z; acc.w += v.w;
    }
    __shared__ float4 sh[256];
    sh[t] = acc; __syncthreads();
    for (int off = 128; off >= 32; off >>= 1) {
        if (t < off) {
            float4 a = sh[t], o = sh[t + off];
            a.x += o.x; a.y += o.y; a.z += o.z; a.w += o.w;
            sh[t] = a;
        }
        __syncthreads();
    }
    if (t < 32) {
        float4 a = sh[t];
        a.x *= inv_n; a.y *= inv_n; a.z *= inv_n; a.w *= inv_n;
        *(float4*)&out[c4] = a;
    }
}

// ---- parallel MLP: layer-1 partial over 64 k-slices -------------------------
#define MLP_NB 64
__global__ __launch_bounds__(256) void mlp_l1_partial(const float* __restrict__ in,
                                                      const float* __restrict__ w1, int IN,
                                                      float* __restrict__ partial) {
    const int b = blockIdx.x;
    const int t = threadIdx.x;
    const int f = t & 127;
    const int half = t >> 7;
    const int kpb = IN / MLP_NB;
    const int k0 = b * kpb;
    float acc = 0.f;
    #pragma unroll 4
    for (int k = k0 + half; k < k0 + kpb; k += 2)
        acc = fmaf(in[k], w1[(size_t)k * 128 + f], acc);
    __shared__ float sh[256];
    sh[t] = acc; __syncthreads();
    if (half == 0) partial[b * 128 + f] = sh[f] + sh[128 + f];
}

__global__ __launch_bounds__(128) void mlp_seq_finish(const float* __restrict__ partial,
                                                      const float* __restrict__ b1,
                                                      const float* __restrict__ w2,
                                                      const float* __restrict__ b2,
                                                      float* __restrict__ out) {
    const int t = threadIdx.x;
    __shared__ float h[128];
    float s = 0.f;
    #pragma unroll 8
    for (int i = 0; i < MLP_NB; ++i) s += partial[i * 128 + t];
    h[t] = fmaxf(s + b1[t], 0.f);
    __syncthreads();
    float acc = 0.f;
    #pragma unroll 8
    for (int k = 0; k < 128; ++k) acc = fmaf(h[k], w2[k * 128 + t], acc);
    out[t] = fmaxf(acc + b2[t], 0.f);
}

__global__ __launch_bounds__(128) void head_finish(const float* __restrict__ partial,
                                                   const float* __restrict__ fc1b,
                                                   const float* __restrict__ fc2w,
                                                   const float* __restrict__ fc2b,
                                                   float* __restrict__ out) {
    const int t = threadIdx.x;
    __shared__ float red[128];
    float s = 0.f;
    #pragma unroll 8
    for (int i = 0; i < MLP_NB; ++i) s += partial[i * 128 + t];
    float h = fmaxf(s + fc1b[t], 0.f);
    red[t] = h * fc2w[t];
    __syncthreads();
    for (int off = 64; off > 0; off >>= 1) {
        if (t < off) red[t] += red[t + off];
        __syncthreads();
    }
    if (t == 0) out[0] = red[0] + fc2b[0];
}

__global__ void concat4(const float* __restrict__ a, const float* __restrict__ b,
                        const float* __restrict__ c, const float* __restrict__ d,
                        float* __restrict__ out) {
    int t = threadIdx.x;
    out[t] = a[t]; out[128 + t] = b[t]; out[256 + t] = c[t]; out[384 + t] = d[t];
}

static inline size_t align_up(size_t x, size_t a) { return (x + a - 1) / a * a; }

extern "C" void kernel_launch(void* const* d_in, const int* in_sizes, int n_in,
                              void* d_out, int out_size, void* d_ws, size_t ws_size,
                              hipStream_t stream) {
    const float* px   = (const float*)d_in[0];
    const int*   pei  = (const int*)d_in[1];
    const float* dx   = (const float*)d_in[2];
    const int*   dei  = (const int*)d_in[3];
    const float* pseq = (const float*)d_in[4];
    const float* dseq = (const float*)d_in[5];
    const float* pc1w = (const float*)d_in[6];  const float* pc1b = (const float*)d_in[7];
    const float* pc2w = (const float*)d_in[8];  const float* pc2b = (const float*)d_in[9];
    const float* dc1w = (const float*)d_in[10]; const float* dc1b = (const float*)d_in[11];
    const float* dc2w = (const float*)d_in[12]; const float* dc2b = (const float*)d_in[13];
    const float* psw1 = (const float*)d_in[14]; const float* psb1 = (const float*)d_in[15];
    const float* psw2 = (const float*)d_in[16]; const float* psb2 = (const float*)d_in[17];
    const float* dsw1 = (const float*)d_in[18]; const float* dsb1 = (const float*)d_in[19];
    const float* dsw2 = (const float*)d_in[20]; const float* dsb2 = (const float*)d_in[21];
    const float* fc1w = (const float*)d_in[22]; const float* fc1b = (const float*)d_in[23];
    const float* fc2w = (const float*)d_in[24]; const float* fc2b = (const float*)d_in[25];

    const int Np = in_sizes[0] / 128, Ep = in_sizes[1] / 2;
    const int Nd = in_sizes[2] / 64,  Ed = in_sizes[3] / 2;
    const int Psd = in_sizes[4], Dsd = in_sizes[5];

    char* w = (char*)d_ws;
    size_t off = 0;
    auto carve = [&](size_t bytes) -> void* {
        void* p = w + off;
        off = align_up(off + bytes, 256);
        return p;
    };
    unsigned short* bufA = (unsigned short*)carve((size_t)Np * 128 * 2);  // f16 msg table
    float* bufB    = (float*)carve((size_t)Np * 128 * 4);                 // h1(f16)/h2(f32)
    int*   col     = (int*)carve((size_t)Ep * 4);
    unsigned* ebuf = (unsigned*)carve((size_t)Ep * 4);
    int*   bcnt    = (int*)carve((size_t)NCB * 256 * 4);
    int*   bbase   = (int*)carve(257 * 4);
    int*   rowptr  = (int*)carve(((size_t)Np + 1) * 4);
    float* dinv    = (float*)carve((size_t)Np * 4);
    float* partial = (float*)carve((size_t)MP_NB * 128 * 4);
    float* mlpp    = (float*)carve((size_t)MLP_NB * 128 * 4);
    float* pmean   = (float*)carve(512);
    float* dmean   = (float*)carve(512);
    float* pseqo   = (float*)carve(512);
    float* dseqo   = (float*)carve(512);
    float* comb    = (float*)carve(2048);
    (void)ws_size; (void)n_in; (void)out_size;

    auto run_gcn = [&](const float* x, const int* ei, int n, int E, int IN,
                       const float* W1, const float* b1,
                       const float* W2, const float* b2, float* meano) {
        const int* srcp = ei;
        const int* dstp = ei + E;
        const int chunk = (((E + NCB - 1) / NCB) + 255) & ~255;
        const int nbk = (n + BW - 1) >> BSH;
        const int nwb = (n + 3) / 4;   // wave-per-node blocks

        csr_hist <<<NCB, 256, 0, stream>>>(dstp, E, chunk, bcnt);
        csr_scan <<<1, 256, 0, stream>>>(bcnt, bbase);
        csr_place<<<NCB, 256, 0, stream>>>(srcp, dstp, E, chunk, bcnt, bbase, ebuf);
        csr_finish<<<nbk, 256, 0, stream>>>(ebuf, bbase, n, E, rowptr, dinv, col);

        // conv1: x (f32) @ W1 -> f16 table; agg -> h1 (f16)
        if (IN == 128) xw_mfma<128, false><<<(n + 63) / 64, 256, 0, stream>>>(x, W1, dinv, bufA, n);
        else           xw_mfma<64,  false><<<(n + 63) / 64, 256, 0, stream>>>(x, W1, dinv, bufA, n);
        gcn_agg<true><<<nwb, 256, 0, stream>>>((const unsigned*)bufA, rowptr, col, dinv, b1, bufB, n);
        // conv2: h1 (f16) @ W2 -> f16 table; agg -> h2 (f32)
        xw_mfma<128, true><<<(n + 63) / 64, 256, 0, stream>>>(bufB, W2, dinv, bufA, n);
        gcn_agg<false><<<nwb, 256, 0, stream>>>((const unsigned*)bufA, rowptr, col, dinv, b2, bufB, n);
        // mean over nodes
        mean_partial<<<MP_NB, 256, 0, stream>>>(bufB, n, partial);
        mean_finish<<<1, 256, 0, stream>>>(partial, 1.0f / (float)n, meano);
    };

    run_gcn(px, pei, Np, Ep, 128, pc1w, pc1b, pc2w, pc2b, pmean);
    run_gcn(dx, dei, Nd, Ed, 64,  dc1w, dc1b, dc2w, dc2b, dmean);

    // seq MLPs (parallelized)
    mlp_l1_partial<<<MLP_NB, 256, 0, stream>>>(pseq, psw1, Psd, mlpp);
    mlp_seq_finish<<<1, 128, 0, stream>>>(mlpp, psb1, psw2, psb2, pseqo);
    mlp_l1_partial<<<MLP_NB, 256, 0, stream>>>(dseq, dsw1, Dsd, mlpp);
    mlp_seq_finish<<<1, 128, 0, stream>>>(mlpp, dsb1, dsw2, dsb2, dseqo);

    // head
    concat4<<<1, 128, 0, stream>>>(pmean, dmean, pseqo, dseqo, comb);
    mlp_l1_partial<<<MLP_NB, 256, 0, stream>>>(comb, fc1w, 512, mlpp);
    head_finish<<<1, 128, 0, stream>>>(mlpp, fc1b, fc2w, fc2b, (float*)d_out);
}

// Round 7
// 771.240 us; speedup vs baseline: 2.9437x; 1.0158x over previous
//
#include <hip/hip_runtime.h>
#include <cstdint>
#include <cstddef>

// ---------------------------------------------------------------------------
// GSF-DTA forward: 2x GCNConv (protein), 2x GCNConv (drug), 2 seq MLPs, head.
// R7: quad-edge gather in gcn_agg — each VMEM instruction gathers 16B/lane
//     from 4 edges (1KB/wave vs 256B), cross-group merge via shfl_xor.
//     h2 stored f16; packed f16 mean. (R6 agg was issue-rate bound: 48% HBM,
//     33% VALU, 72% occ — neither pipe saturated.)
// xw matmul: MFMA 16x16x32 f16 (R6). CSR build: 2-level bucket sort (R4).
// ---------------------------------------------------------------------------

#define NCB 256     // chunk blocks for edge passes
#define BSH 9       // bucket shift: 512 nodes per bucket (needs n <= 131072)
#define BW  512     // 1 << BSH

typedef __attribute__((ext_vector_type(8))) _Float16 f16x8;
typedef __attribute__((ext_vector_type(2))) _Float16 f16x2;
typedef __attribute__((ext_vector_type(4))) float f32x4;

static __device__ __forceinline__ unsigned short f2h(float f) {
    _Float16 h = (_Float16)f;
    return __builtin_bit_cast(unsigned short, h);
}
static __device__ __forceinline__ f16x2 u2h(unsigned u) {
    return __builtin_bit_cast(f16x2, u);
}
static __device__ __forceinline__ unsigned h2u(f16x2 h) {
    return __builtin_bit_cast(unsigned, h);
}

// ---- CSR build: bucket sort by dst ------------------------------------------
__global__ __launch_bounds__(256) void csr_hist(const int* __restrict__ dst, int E, int chunk,
                                                int* __restrict__ bcnt) {
    __shared__ int h[256];
    const int t = threadIdx.x, blk = blockIdx.x;
    h[t] = 0; __syncthreads();
    const int e0 = blk * chunk;
    const int e1 = min(E, e0 + chunk);
    for (int e = e0 + t; e < e1; e += 256) atomicAdd(&h[dst[e] >> BSH], 1);
    __syncthreads();
    bcnt[blk * 256 + t] = h[t];
}

__global__ __launch_bounds__(256) void csr_scan(int* __restrict__ bcnt, int* __restrict__ bbase) {
    const int t = threadIdx.x;
    int run = 0;
    for (int blk = 0; blk < NCB; ++blk) {
        int idx = blk * 256 + t;
        int v = bcnt[idx]; bcnt[idx] = run; run += v;
    }
    __shared__ int sh[256];
    sh[t] = run; __syncthreads();
    for (int off = 1; off < 256; off <<= 1) {
        int add = (t >= off) ? sh[t - off] : 0;
        __syncthreads(); sh[t] += add; __syncthreads();
    }
    bbase[t] = sh[t] - run;              // exclusive scan over buckets
    if (t == 255) bbase[256] = sh[255];  // == E
}

__global__ __launch_bounds__(256) void csr_place(const int* __restrict__ src,
                                                 const int* __restrict__ dst, int E, int chunk,
                                                 const int* __restrict__ bcnt,
                                                 const int* __restrict__ bbase,
                                                 unsigned* __restrict__ ebuf) {
    __shared__ int cur[256];
    const int t = threadIdx.x, blk = blockIdx.x;
    cur[t] = bbase[t] + bcnt[blk * 256 + t];
    __syncthreads();
    const int e0 = blk * chunk;
    const int e1 = min(E, e0 + chunk);
    for (int e = e0 + t; e < e1; e += 256) {
        int d = dst[e];
        int b = d >> BSH;
        int pos = atomicAdd(&cur[b], 1);
        ebuf[pos] = ((unsigned)src[e] << BSH) | (unsigned)(d & (BW - 1));
    }
}

// one block per bucket: per-node histogram -> dinv + rowptr, then scatter col.
__global__ __launch_bounds__(256) void csr_finish(const unsigned* __restrict__ ebuf,
                                                  const int* __restrict__ bbase,
                                                  int n, int E,
                                                  int* __restrict__ rowptr,
                                                  float* __restrict__ dinv,
                                                  int* __restrict__ col) {
    __shared__ int hist[BW];
    __shared__ int cur[BW];
    __shared__ int sh[256];
    const int t = threadIdx.x, b = blockIdx.x;
    const int nb = b << BSH;
    const int w = min(BW, n - nb);
    const int rb = bbase[b], re = bbase[b + 1];
    hist[2 * t] = 0; hist[2 * t + 1] = 0;
    __syncthreads();
    for (int i = rb + t; i < re; i += 256) atomicAdd(&hist[ebuf[i] & (BW - 1)], 1);
    __syncthreads();
    const int a0 = hist[2 * t], a1 = hist[2 * t + 1];
    if (2 * t     < w) dinv[nb + 2 * t]     = rsqrtf((float)(a0 + 1));
    if (2 * t + 1 < w) dinv[nb + 2 * t + 1] = rsqrtf((float)(a1 + 1));
    sh[t] = a0 + a1; __syncthreads();
    for (int off = 1; off < 256; off <<= 1) {
        int add = (t >= off) ? sh[t - off] : 0;
        __syncthreads(); sh[t] += add; __syncthreads();
    }
    int base = t ? sh[t - 1] : 0;
    const int p0 = rb + base, p1 = rb + base + a0;
    if (2 * t     < w) rowptr[nb + 2 * t]     = p0;
    if (2 * t + 1 < w) rowptr[nb + 2 * t + 1] = p1;
    cur[2 * t] = p0; cur[2 * t + 1] = p1;
    __syncthreads();
    for (int i = rb + t; i < re; i += 256) {
        unsigned r = ebuf[i];
        int pos = atomicAdd(&cur[r & (BW - 1)], 1);
        col[pos] = (int)(r >> BSH);
    }
    if (b == 0 && t == 0) rowptr[n] = E;
}

// ---- x@W via MFMA f16; out(f16) = dinv[row] * (x@W) -------------------------
// Block: 256 threads = 4 waves; 64 rows x 128 cols per block.
// W[K][128] staged to LDS as Wt[col][k] f16, 16B-chunk XOR-swizzled.
template <int K, bool IN16>
__global__ __launch_bounds__(256) void xw_mfma(const void* __restrict__ xv,
                                               const float* __restrict__ W,
                                               const float* __restrict__ dinv,
                                               unsigned short* __restrict__ out, int n) {
    constexpr int CH = K / 8;          // 16B chunks per column
    constexpr int KS = K / 32;         // mfma k-steps
    __shared__ _Float16 Wt[128 * K];
    const int tid = threadIdx.x;

    for (int i = tid; i < 128 * CH; i += 256) {
        const int col = i / CH, ch = i % CH;
        f16x8 v;
        #pragma unroll
        for (int j = 0; j < 8; ++j) v[j] = (_Float16)W[(ch * 8 + j) * 128 + col];
        *(f16x8*)&Wt[(col * CH + (ch ^ (col & (CH - 1)))) * 8] = v;
    }
    __syncthreads();

    const int wv = tid >> 6, ln = tid & 63;
    const int r0 = blockIdx.x * 64 + wv * 16;
    const int row = r0 + (ln & 15);
    const int kg = (ln >> 4) * 8;

    f16x8 a[KS];
    if (row < n) {
        if constexpr (IN16) {
            const unsigned short* xr = (const unsigned short*)xv + (size_t)row * K;
            #pragma unroll
            for (int ks = 0; ks < KS; ++ks)
                a[ks] = *(const f16x8*)&xr[ks * 32 + kg];
        } else {
            const float* xr = (const float*)xv + (size_t)row * K;
            #pragma unroll
            for (int ks = 0; ks < KS; ++ks) {
                float4 u0 = *(const float4*)&xr[ks * 32 + kg];
                float4 u1 = *(const float4*)&xr[ks * 32 + kg + 4];
                f16x8 v;
                v[0] = (_Float16)u0.x; v[1] = (_Float16)u0.y;
                v[2] = (_Float16)u0.z; v[3] = (_Float16)u0.w;
                v[4] = (_Float16)u1.x; v[5] = (_Float16)u1.y;
                v[6] = (_Float16)u1.z; v[7] = (_Float16)u1.w;
                a[ks] = v;
            }
        }
    } else {
        #pragma unroll
        for (int ks = 0; ks < KS; ++ks) {
            f16x8 v;
            #pragma unroll
            for (int j = 0; j < 8; ++j) v[j] = (_Float16)0.f;
            a[ks] = v;
        }
    }

    const int rw0 = r0 + (ln >> 4) * 4;
    float dv[4];
    #pragma unroll
    for (int r = 0; r < 4; ++r) dv[r] = (rw0 + r < n) ? dinv[rw0 + r] : 0.f;

    const int cl = ln & 15;
    #pragma unroll
    for (int nt = 0; nt < 8; ++nt) {
        const int col = nt * 16 + cl;
        f32x4 c = {0.f, 0.f, 0.f, 0.f};
        #pragma unroll
        for (int ks = 0; ks < KS; ++ks) {
            const int ch = ks * 4 + (ln >> 4);
            f16x8 b = *(const f16x8*)&Wt[(col * CH + (ch ^ (col & (CH - 1)))) * 8];
            c = __builtin_amdgcn_mfma_f32_16x16x32_f16(a[ks], b, c, 0, 0, 0);
        }
        #pragma unroll
        for (int r = 0; r < 4; ++r) {
            const int rr = rw0 + r;
            if (rr < n) out[(size_t)rr * 128 + col] = f2h(c[r] * dv[r]);
        }
    }
}

// ---- aggregation: one WAVE per node, quad-edge gather -----------------------
// tab row = 16 uint4 (128 f16). lane = (group g = ln>>4, chunk c = ln&15).
// Per iteration the wave processes 4 edges: lane loads uint4 of row col[j+g].
// After the loop, shfl_xor(16/32) merges the 4 groups. Output f16.
__global__ __launch_bounds__(256) void gcn_agg4(const uint4* __restrict__ tab,
                                                const int* __restrict__ rowptr,
                                                const int* __restrict__ col,
                                                const float* __restrict__ dinv,
                                                const float* __restrict__ bias,
                                                uint4* __restrict__ out, int n) {
    const int wv = threadIdx.x >> 6, ln = threadIdx.x & 63;
    const int d = blockIdx.x * 4 + wv;
    if (d >= n) return;
    const int g = ln >> 4;        // edge group
    const int c = ln & 15;        // 16B feature chunk
    const int beg = rowptr[d], end = rowptr[d + 1];

    f16x2 a0, a1, a2, a3, b0, b1, b2, b3;
    a0 = a1 = a2 = a3 = b0 = b1 = b2 = b3 = u2h(0u);
    if (g == 0) {                 // self-loop term
        uint4 v = tab[(size_t)d * 16 + c];
        a0 = u2h(v.x); a1 = u2h(v.y); a2 = u2h(v.z); a3 = u2h(v.w);
    }

    int j = beg;
    for (; j + 8 <= end; j += 8) {        // 8 edges per iteration (2 quads)
        int s0 = col[j + g];
        int s1 = col[j + 4 + g];
        uint4 v0 = tab[(size_t)s0 * 16 + c];
        uint4 v1 = tab[(size_t)s1 * 16 + c];
        a0 += u2h(v0.x); a1 += u2h(v0.y); a2 += u2h(v0.z); a3 += u2h(v0.w);
        b0 += u2h(v1.x); b1 += u2h(v1.y); b2 += u2h(v1.z); b3 += u2h(v1.w);
    }
    for (; j < end; j += 4) {             // tail quads (predicated)
        int jj = j + g;
        int s = col[min(jj, end - 1)];
        uint4 v = tab[(size_t)s * 16 + c];
        if (jj < end) {
            b0 += u2h(v.x); b1 += u2h(v.y); b2 += u2h(v.z); b3 += u2h(v.w);
        }
    }
    a0 += b0; a1 += b1; a2 += b2; a3 += b3;

    // merge the 4 edge-groups: lanes {c, c+16, c+32, c+48} hold partials
    a0 += u2h((unsigned)__shfl_xor((int)h2u(a0), 16));
    a1 += u2h((unsigned)__shfl_xor((int)h2u(a1), 16));
    a2 += u2h((unsigned)__shfl_xor((int)h2u(a2), 16));
    a3 += u2h((unsigned)__shfl_xor((int)h2u(a3), 16));
    a0 += u2h((unsigned)__shfl_xor((int)h2u(a0), 32));
    a1 += u2h((unsigned)__shfl_xor((int)h2u(a1), 32));
    a2 += u2h((unsigned)__shfl_xor((int)h2u(a2), 32));
    a3 += u2h((unsigned)__shfl_xor((int)h2u(a3), 32));

    if (g == 0) {
        const float dv = dinv[d];
        const float2* bp = (const float2*)&bias[c * 8];
        const float2 q0 = bp[0], q1 = bp[1], q2 = bp[2], q3 = bp[3];
        uint4 o;
        o.x = (unsigned)f2h(fmaxf(fmaf(dv, (float)a0[0], q0.x), 0.f))
            | ((unsigned)f2h(fmaxf(fmaf(dv, (float)a0[1], q0.y), 0.f)) << 16);
        o.y = (unsigned)f2h(fmaxf(fmaf(dv, (float)a1[0], q1.x), 0.f))
            | ((unsigned)f2h(fmaxf(fmaf(dv, (float)a1[1], q1.y), 0.f)) << 16);
        o.z = (unsigned)f2h(fmaxf(fmaf(dv, (float)a2[0], q2.x), 0.f))
            | ((unsigned)f2h(fmaxf(fmaf(dv, (float)a2[1], q2.y), 0.f)) << 16);
        o.w = (unsigned)f2h(fmaxf(fmaf(dv, (float)a3[0], q3.x), 0.f))
            | ((unsigned)f2h(fmaxf(fmaf(dv, (float)a3[1], q3.y), 0.f)) << 16);
        out[(size_t)d * 16 + c] = o;
    }
}

// ---- mean over rows, f16 input ----------------------------------------------
#define MP_NB 1024
__global__ __launch_bounds__(256) void mean_partial16(const uint4* __restrict__ h, int n,
                                                      float* __restrict__ partial) {
    const int t = threadIdx.x, b = blockIdx.x;
    const int c = t & 15;        // uint4 chunk (8 features)
    const int rl = t >> 4;       // 16 parallel row-lanes
    const int rpb = (n + MP_NB - 1) / MP_NB;
    const int r0 = b * rpb, r1 = min(n, r0 + rpb);
    float acc[8] = {0.f, 0.f, 0.f, 0.f, 0.f, 0.f, 0.f, 0.f};
    for (int r = r0 + rl; r < r1; r += 16) {
        uint4 v = h[(size_t)r * 16 + c];
        f16x2 p;
        p = u2h(v.x); acc[0] += (float)p[0]; acc[1] += (float)p[1];
        p = u2h(v.y); acc[2] += (float)p[0]; acc[3] += (float)p[1];
        p = u2h(v.z); acc[4] += (float)p[0]; acc[5] += (float)p[1];
        p = u2h(v.w); acc[6] += (float)p[0]; acc[7] += (float)p[1];
    }
    __shared__ float sh[16][128];
    #pragma unroll
    for (int k = 0; k < 8; ++k) sh[rl][c * 8 + k] = acc[k];
    __syncthreads();
    if (t < 128) {
        float s = 0.f;
        #pragma unroll
        for (int i = 0; i < 16; ++i) s += sh[i][t];
        partial[(size_t)b * 128 + t] = s;
    }
}

__global__ __launch_bounds__(256) void mean_finish(const float* __restrict__ partial, float inv_n,
                                                   float* __restrict__ out) {
    const int t = threadIdx.x;
    const int c4 = (t & 31) * 4;
    float4 acc = make_float4(0.f, 0.f, 0.f, 0.f);
    for (int r = (t >> 5); r < MP_NB; r += 8) {
        float4 v = *(const float4*)&partial[(size_t)r * 128 + c4];
        acc.x += v.x; acc.y += v.y; acc.z += v.z; acc.w += v.w;
    }
    __shared__ float4 sh[256];
    sh[t] = acc; __syncthreads();
    for (int off = 128; off >= 32; off >>= 1) {
        if (t < off) {
            float4 a = sh[t], o = sh[t + off];
            a.x += o.x; a.y += o.y; a.z += o.z; a.w += o.w;
            sh[t] = a;
        }
        __syncthreads();
    }
    if (t < 32) {
        float4 a = sh[t];
        a.x *= inv_n; a.y *= inv_n; a.z *= inv_n; a.w *= inv_n;
        *(float4*)&out[c4] = a;
    }
}

// ---- parallel MLP: layer-1 partial over 64 k-slices -------------------------
#define MLP_NB 64
__global__ __launch_bounds__(256) void mlp_l1_partial(const float* __restrict__ in,
                                                      const float* __restrict__ w1, int IN,
                                                      float* __restrict__ partial) {
    const int b = blockIdx.x;
    const int t = threadIdx.x;
    const int f = t & 127;
    const int half = t >> 7;
    const int kpb = IN / MLP_NB;
    const int k0 = b * kpb;
    float acc = 0.f;
    #pragma unroll 4
    for (int k = k0 + half; k < k0 + kpb; k += 2)
        acc = fmaf(in[k], w1[(size_t)k * 128 + f], acc);
    __shared__ float sh[256];
    sh[t] = acc; __syncthreads();
    if (half == 0) partial[b * 128 + f] = sh[f] + sh[128 + f];
}

__global__ __launch_bounds__(128) void mlp_seq_finish(const float* __restrict__ partial,
                                                      const float* __restrict__ b1,
                                                      const float* __restrict__ w2,
                                                      const float* __restrict__ b2,
                                                      float* __restrict__ out) {
    const int t = threadIdx.x;
    __shared__ float h[128];
    float s = 0.f;
    #pragma unroll 8
    for (int i = 0; i < MLP_NB; ++i) s += partial[i * 128 + t];
    h[t] = fmaxf(s + b1[t], 0.f);
    __syncthreads();
    float acc = 0.f;
    #pragma unroll 8
    for (int k = 0; k < 128; ++k) acc = fmaf(h[k], w2[k * 128 + t], acc);
    out[t] = fmaxf(acc + b2[t], 0.f);
}

__global__ __launch_bounds__(128) void head_finish(const float* __restrict__ partial,
                                                   const float* __restrict__ fc1b,
                                                   const float* __restrict__ fc2w,
                                                   const float* __restrict__ fc2b,
                                                   float* __restrict__ out) {
    const int t = threadIdx.x;
    __shared__ float red[128];
    float s = 0.f;
    #pragma unroll 8
    for (int i = 0; i < MLP_NB; ++i) s += partial[i * 128 + t];
    float h = fmaxf(s + fc1b[t], 0.f);
    red[t] = h * fc2w[t];
    __syncthreads();
    for (int off = 64; off > 0; off >>= 1) {
        if (t < off) red[t] += red[t + off];
        __syncthreads();
    }
    if (t == 0) out[0] = red[0] + fc2b[0];
}

__global__ void concat4(const float* __restrict__ a, const float* __restrict__ b,
                        const float* __restrict__ c, const float* __restrict__ d,
                        float* __restrict__ out) {
    int t = threadIdx.x;
    out[t] = a[t]; out[128 + t] = b[t]; out[256 + t] = c[t]; out[384 + t] = d[t];
}

static inline size_t align_up(size_t x, size_t a) { return (x + a - 1) / a * a; }

extern "C" void kernel_launch(void* const* d_in, const int* in_sizes, int n_in,
                              void* d_out, int out_size, void* d_ws, size_t ws_size,
                              hipStream_t stream) {
    const float* px   = (const float*)d_in[0];
    const int*   pei  = (const int*)d_in[1];
    const float* dx   = (const float*)d_in[2];
    const int*   dei  = (const int*)d_in[3];
    const float* pseq = (const float*)d_in[4];
    const float* dseq = (const float*)d_in[5];
    const float* pc1w = (const float*)d_in[6];  const float* pc1b = (const float*)d_in[7];
    const float* pc2w = (const float*)d_in[8];  const float* pc2b = (const float*)d_in[9];
    const float* dc1w = (const float*)d_in[10]; const float* dc1b = (const float*)d_in[11];
    const float* dc2w = (const float*)d_in[12]; const float* dc2b = (const float*)d_in[13];
    const float* psw1 = (const float*)d_in[14]; const float* psb1 = (const float*)d_in[15];
    const float* psw2 = (const float*)d_in[16]; const float* psb2 = (const float*)d_in[17];
    const float* dsw1 = (const float*)d_in[18]; const float* dsb1 = (const float*)d_in[19];
    const float* dsw2 = (const float*)d_in[20]; const float* dsb2 = (const float*)d_in[21];
    const float* fc1w = (const float*)d_in[22]; const float* fc1b = (const float*)d_in[23];
    const float* fc2w = (const float*)d_in[24]; const float* fc2b = (const float*)d_in[25];

    const int Np = in_sizes[0] / 128, Ep = in_sizes[1] / 2;
    const int Nd = in_sizes[2] / 64,  Ed = in_sizes[3] / 2;
    const int Psd = in_sizes[4], Dsd = in_sizes[5];

    char* w = (char*)d_ws;
    size_t off = 0;
    auto carve = [&](size_t bytes) -> void* {
        void* p = w + off;
        off = align_up(off + bytes, 256);
        return p;
    };
    unsigned short* bufA = (unsigned short*)carve((size_t)Np * 128 * 2);  // f16 msg table
    unsigned short* bufB = (unsigned short*)carve((size_t)Np * 128 * 2);  // f16 hidden
    int*   col     = (int*)carve((size_t)Ep * 4);
    unsigned* ebuf = (unsigned*)carve((size_t)Ep * 4);
    int*   bcnt    = (int*)carve((size_t)NCB * 256 * 4);
    int*   bbase   = (int*)carve(257 * 4);
    int*   rowptr  = (int*)carve(((size_t)Np + 1) * 4);
    float* dinv    = (float*)carve((size_t)Np * 4);
    float* partial = (float*)carve((size_t)MP_NB * 128 * 4);
    float* mlpp    = (float*)carve((size_t)MLP_NB * 128 * 4);
    float* pmean   = (float*)carve(512);
    float* dmean   = (float*)carve(512);
    float* pseqo   = (float*)carve(512);
    float* dseqo   = (float*)carve(512);
    float* comb    = (float*)carve(2048);
    (void)ws_size; (void)n_in; (void)out_size;

    auto run_gcn = [&](const float* x, const int* ei, int n, int E, int IN,
                       const float* W1, const float* b1,
                       const float* W2, const float* b2, float* meano) {
        const int* srcp = ei;
        const int* dstp = ei + E;
        const int chunk = (((E + NCB - 1) / NCB) + 255) & ~255;
        const int nbk = (n + BW - 1) >> BSH;
        const int nwb = (n + 3) / 4;   // wave-per-node blocks

        csr_hist <<<NCB, 256, 0, stream>>>(dstp, E, chunk, bcnt);
        csr_scan <<<1, 256, 0, stream>>>(bcnt, bbase);
        csr_place<<<NCB, 256, 0, stream>>>(srcp, dstp, E, chunk, bcnt, bbase, ebuf);
        csr_finish<<<nbk, 256, 0, stream>>>(ebuf, bbase, n, E, rowptr, dinv, col);

        // conv1: x (f32) @ W1 -> f16 table; agg -> h1 (f16)
        if (IN == 128) xw_mfma<128, false><<<(n + 63) / 64, 256, 0, stream>>>(x, W1, dinv, bufA, n);
        else           xw_mfma<64,  false><<<(n + 63) / 64, 256, 0, stream>>>(x, W1, dinv, bufA, n);
        gcn_agg4<<<nwb, 256, 0, stream>>>((const uint4*)bufA, rowptr, col, dinv, b1,
                                          (uint4*)bufB, n);
        // conv2: h1 (f16) @ W2 -> f16 table; agg -> h2 (f16)
        xw_mfma<128, true><<<(n + 63) / 64, 256, 0, stream>>>(bufB, W2, dinv, bufA, n);
        gcn_agg4<<<nwb, 256, 0, stream>>>((const uint4*)bufA, rowptr, col, dinv, b2,
                                          (uint4*)bufB, n);
        // mean over nodes (f16 input)
        mean_partial16<<<MP_NB, 256, 0, stream>>>((const uint4*)bufB, n, partial);
        mean_finish<<<1, 256, 0, stream>>>(partial, 1.0f / (float)n, meano);
    };

    run_gcn(px, pei, Np, Ep, 128, pc1w, pc1b, pc2w, pc2b, pmean);
    run_gcn(dx, dei, Nd, Ed, 64,  dc1w, dc1b, dc2w, dc2b, dmean);

    // seq MLPs (parallelized)
    mlp_l1_partial<<<MLP_NB, 256, 0, stream>>>(pseq, psw1, Psd, mlpp);
    mlp_seq_finish<<<1, 128, 0, stream>>>(mlpp, psb1, psw2, psb2, pseqo);
    mlp_l1_partial<<<MLP_NB, 256, 0, stream>>>(dseq, dsw1, Dsd, mlpp);
    mlp_seq_finish<<<1, 128, 0, stream>>>(mlpp, dsb1, dsw2, dsb2, dseqo);

    // head
    concat4<<<1, 128, 0, stream>>>(pmean, dmean, pseqo, dseqo, comb);
    mlp_l1_partial<<<MLP_NB, 256, 0, stream>>>(comb, fc1w, 512, mlpp);
    head_finish<<<1, 128, 0, stream>>>(mlpp, fc1b, fc2w, fc2b, (float*)d_out);
}

// Round 8
// 627.802 us; speedup vs baseline: 3.6163x; 1.2285x over previous
//
#include <hip/hip_runtime.h>
#include <cstdint>
#include <cstddef>

// ---------------------------------------------------------------------------
// GSF-DTA forward: 2x GCNConv (protein), 2x GCNConv (drug), 2 seq MLPs, head.
// R8: FUSION — protein+drug pipelines share every dispatch (block-segment
//     split): 27 launches -> 14. Kernel bodies identical to R7 (quad-edge
//     f16 gather, MFMA f16 xw, bucket-sort CSR). Launch-gap elimination.
// ---------------------------------------------------------------------------

#define NCB 256     // chunk blocks per graph for edge passes
#define BSH 9       // bucket shift: 512 nodes per bucket (needs n <= 131072)
#define BW  512     // 1 << BSH
#define MPP 1024    // mean partial blocks (protein)
#define MPD 512     // mean partial blocks (drug)

typedef __attribute__((ext_vector_type(8))) _Float16 f16x8;
typedef __attribute__((ext_vector_type(2))) _Float16 f16x2;
typedef __attribute__((ext_vector_type(4))) float f32x4;

static __device__ __forceinline__ unsigned short f2h(float f) {
    _Float16 h = (_Float16)f;
    return __builtin_bit_cast(unsigned short, h);
}
static __device__ __forceinline__ f16x2 u2h(unsigned u) {
    return __builtin_bit_cast(f16x2, u);
}
static __device__ __forceinline__ unsigned h2u(f16x2 h) {
    return __builtin_bit_cast(unsigned, h);
}

// ---- CSR build bodies (bucket sort by dst) ----------------------------------
static __device__ __forceinline__ void hist_body(int blk, const int* __restrict__ dst, int E,
                                                 int chunk, int* __restrict__ bcnt) {
    __shared__ int h[256];
    const int t = threadIdx.x;
    h[t] = 0; __syncthreads();
    const int e0 = blk * chunk;
    const int e1 = min(E, e0 + chunk);
    for (int e = e0 + t; e < e1; e += 256) atomicAdd(&h[dst[e] >> BSH], 1);
    __syncthreads();
    bcnt[blk * 256 + t] = h[t];
}

static __device__ __forceinline__ void scan_body(int* __restrict__ bcnt, int* __restrict__ bbase) {
    const int t = threadIdx.x;
    int run = 0;
    for (int blk = 0; blk < NCB; ++blk) {
        int idx = blk * 256 + t;
        int v = bcnt[idx]; bcnt[idx] = run; run += v;
    }
    __shared__ int sh[256];
    sh[t] = run; __syncthreads();
    for (int off = 1; off < 256; off <<= 1) {
        int add = (t >= off) ? sh[t - off] : 0;
        __syncthreads(); sh[t] += add; __syncthreads();
    }
    bbase[t] = sh[t] - run;
    if (t == 255) bbase[256] = sh[255];
}

static __device__ __forceinline__ void place_body(int blk, const int* __restrict__ src,
                                                  const int* __restrict__ dst, int E, int chunk,
                                                  const int* __restrict__ bcnt,
                                                  const int* __restrict__ bbase,
                                                  unsigned* __restrict__ ebuf) {
    __shared__ int cur[256];
    const int t = threadIdx.x;
    cur[t] = bbase[t] + bcnt[blk * 256 + t];
    __syncthreads();
    const int e0 = blk * chunk;
    const int e1 = min(E, e0 + chunk);
    for (int e = e0 + t; e < e1; e += 256) {
        int d = dst[e];
        int b = d >> BSH;
        int pos = atomicAdd(&cur[b], 1);
        ebuf[pos] = ((unsigned)src[e] << BSH) | (unsigned)(d & (BW - 1));
    }
}

static __device__ __forceinline__ void finish_body(int b, const unsigned* __restrict__ ebuf,
                                                   const int* __restrict__ bbase, int n, int E,
                                                   int* __restrict__ rowptr,
                                                   float* __restrict__ dinv,
                                                   int* __restrict__ col) {
    __shared__ int hist[BW];
    __shared__ int cur[BW];
    __shared__ int sh[256];
    const int t = threadIdx.x;
    const int nb = b << BSH;
    const int w = min(BW, n - nb);
    const int rb = bbase[b], re = bbase[b + 1];
    hist[2 * t] = 0; hist[2 * t + 1] = 0;
    __syncthreads();
    for (int i = rb + t; i < re; i += 256) atomicAdd(&hist[ebuf[i] & (BW - 1)], 1);
    __syncthreads();
    const int a0 = hist[2 * t], a1 = hist[2 * t + 1];
    if (2 * t     < w) dinv[nb + 2 * t]     = rsqrtf((float)(a0 + 1));
    if (2 * t + 1 < w) dinv[nb + 2 * t + 1] = rsqrtf((float)(a1 + 1));
    sh[t] = a0 + a1; __syncthreads();
    for (int off = 1; off < 256; off <<= 1) {
        int add = (t >= off) ? sh[t - off] : 0;
        __syncthreads(); sh[t] += add; __syncthreads();
    }
    int base = t ? sh[t - 1] : 0;
    const int p0 = rb + base, p1 = rb + base + a0;
    if (2 * t     < w) rowptr[nb + 2 * t]     = p0;
    if (2 * t + 1 < w) rowptr[nb + 2 * t + 1] = p1;
    cur[2 * t] = p0; cur[2 * t + 1] = p1;
    __syncthreads();
    for (int i = rb + t; i < re; i += 256) {
        unsigned r = ebuf[i];
        int pos = atomicAdd(&cur[r & (BW - 1)], 1);
        col[pos] = (int)(r >> BSH);
    }
    if (b == 0 && t == 0) rowptr[n] = E;
}

// ---- fused CSR kernels ------------------------------------------------------
__global__ __launch_bounds__(256) void csr_hist2(const int* dp, int Ep_, int chp, int* bcp,
                                                 const int* dd, int Ed_, int chd, int* bcd) {
    int b = blockIdx.x;
    if (b < NCB) hist_body(b, dp, Ep_, chp, bcp);
    else         hist_body(b - NCB, dd, Ed_, chd, bcd);
}

__global__ __launch_bounds__(256) void csr_scan2(int* bcp, int* bbp, int* bcd, int* bbd) {
    if (blockIdx.x == 0) scan_body(bcp, bbp);
    else                 scan_body(bcd, bbd);
}

__global__ __launch_bounds__(256) void csr_place2(const int* sp, const int* dp, int Ep_, int chp,
                                                  const int* bcp, const int* bbp, unsigned* ebp,
                                                  const int* sd, const int* dd, int Ed_, int chd,
                                                  const int* bcd, const int* bbd, unsigned* ebd) {
    int b = blockIdx.x;
    if (b < NCB) place_body(b, sp, dp, Ep_, chp, bcp, bbp, ebp);
    else         place_body(b - NCB, sd, dd, Ed_, chd, bcd, bbd, ebd);
}

__global__ __launch_bounds__(256) void csr_finish2(const unsigned* ebp, const int* bbp, int np_,
                                                   int Ep_, int* rpp, float* dvp, int* clp, int nbkp,
                                                   const unsigned* ebd, const int* bbd, int nd_,
                                                   int Ed_, int* rpd, float* dvd, int* cld) {
    int b = blockIdx.x;
    if (b < nbkp) finish_body(b, ebp, bbp, np_, Ep_, rpp, dvp, clp);
    else          finish_body(b - nbkp, ebd, bbd, nd_, Ed_, rpd, dvd, cld);
}

// ---- x@W via MFMA f16 body --------------------------------------------------
template <int K, bool IN16>
static __device__ __forceinline__ void xw_body(_Float16* __restrict__ Wt, int bid,
                                               const void* __restrict__ xv,
                                               const float* __restrict__ W,
                                               const float* __restrict__ dinv,
                                               unsigned short* __restrict__ out, int n) {
    constexpr int CH = K / 8;
    constexpr int KS = K / 32;
    const int tid = threadIdx.x;

    for (int i = tid; i < 128 * CH; i += 256) {
        const int col = i / CH, ch = i % CH;
        f16x8 v;
        #pragma unroll
        for (int j = 0; j < 8; ++j) v[j] = (_Float16)W[(ch * 8 + j) * 128 + col];
        *(f16x8*)&Wt[(col * CH + (ch ^ (col & (CH - 1)))) * 8] = v;
    }
    __syncthreads();

    const int wv = tid >> 6, ln = tid & 63;
    const int r0 = bid * 64 + wv * 16;
    const int row = r0 + (ln & 15);
    const int kg = (ln >> 4) * 8;

    f16x8 a[KS];
    if (row < n) {
        if constexpr (IN16) {
            const unsigned short* xr = (const unsigned short*)xv + (size_t)row * K;
            #pragma unroll
            for (int ks = 0; ks < KS; ++ks)
                a[ks] = *(const f16x8*)&xr[ks * 32 + kg];
        } else {
            const float* xr = (const float*)xv + (size_t)row * K;
            #pragma unroll
            for (int ks = 0; ks < KS; ++ks) {
                float4 u0 = *(const float4*)&xr[ks * 32 + kg];
                float4 u1 = *(const float4*)&xr[ks * 32 + kg + 4];
                f16x8 v;
                v[0] = (_Float16)u0.x; v[1] = (_Float16)u0.y;
                v[2] = (_Float16)u0.z; v[3] = (_Float16)u0.w;
                v[4] = (_Float16)u1.x; v[5] = (_Float16)u1.y;
                v[6] = (_Float16)u1.z; v[7] = (_Float16)u1.w;
                a[ks] = v;
            }
        }
    } else {
        #pragma unroll
        for (int ks = 0; ks < KS; ++ks) {
            f16x8 v;
            #pragma unroll
            for (int j = 0; j < 8; ++j) v[j] = (_Float16)0.f;
            a[ks] = v;
        }
    }

    const int rw0 = r0 + (ln >> 4) * 4;
    float dv[4];
    #pragma unroll
    for (int r = 0; r < 4; ++r) dv[r] = (rw0 + r < n) ? dinv[rw0 + r] : 0.f;

    const int cl = ln & 15;
    #pragma unroll
    for (int nt = 0; nt < 8; ++nt) {
        const int col = nt * 16 + cl;
        f32x4 c = {0.f, 0.f, 0.f, 0.f};
        #pragma unroll
        for (int ks = 0; ks < KS; ++ks) {
            const int ch = ks * 4 + (ln >> 4);
            f16x8 b = *(const f16x8*)&Wt[(col * CH + (ch ^ (col & (CH - 1)))) * 8];
            c = __builtin_amdgcn_mfma_f32_16x16x32_f16(a[ks], b, c, 0, 0, 0);
        }
        #pragma unroll
        for (int r = 0; r < 4; ++r) {
            const int rr = rw0 + r;
            if (rr < n) out[(size_t)rr * 128 + col] = f2h(c[r] * dv[r]);
        }
    }
}

__global__ __launch_bounds__(256) void xw1_fused(const float* xp, const float* Wp,
                                                 const float* dvp, unsigned short* op,
                                                 int np_, int nbp,
                                                 const float* xd, const float* Wd,
                                                 const float* dvd, unsigned short* od, int nd_) {
    __shared__ _Float16 Wt[128 * 128];
    int b = blockIdx.x;
    if (b < nbp) xw_body<128, false>(Wt, b, xp, Wp, dvp, op, np_);
    else         xw_body<64,  false>(Wt, b - nbp, xd, Wd, dvd, od, nd_);
}

__global__ __launch_bounds__(256) void xw2_fused(const unsigned short* xp, const float* Wp,
                                                 const float* dvp, unsigned short* op,
                                                 int np_, int nbp,
                                                 const unsigned short* xd, const float* Wd,
                                                 const float* dvd, unsigned short* od, int nd_) {
    __shared__ _Float16 Wt[128 * 128];
    int b = blockIdx.x;
    if (b < nbp) xw_body<128, true>(Wt, b, xp, Wp, dvp, op, np_);
    else         xw_body<128, true>(Wt, b - nbp, xd, Wd, dvd, od, nd_);
}

// ---- aggregation body: one wave per node, quad-edge gather ------------------
static __device__ __forceinline__ void agg_body(int bid, const uint4* __restrict__ tab,
                                                const int* __restrict__ rowptr,
                                                const int* __restrict__ col,
                                                const float* __restrict__ dinv,
                                                const float* __restrict__ bias,
                                                uint4* __restrict__ out, int n) {
    const int wv = threadIdx.x >> 6, ln = threadIdx.x & 63;
    const int d = bid * 4 + wv;
    if (d >= n) return;
    const int g = ln >> 4;
    const int c = ln & 15;
    const int beg = rowptr[d], end = rowptr[d + 1];

    f16x2 a0, a1, a2, a3, b0, b1, b2, b3;
    a0 = a1 = a2 = a3 = b0 = b1 = b2 = b3 = u2h(0u);
    if (g == 0) {
        uint4 v = tab[(size_t)d * 16 + c];
        a0 = u2h(v.x); a1 = u2h(v.y); a2 = u2h(v.z); a3 = u2h(v.w);
    }

    int j = beg;
    for (; j + 8 <= end; j += 8) {
        int s0 = col[j + g];
        int s1 = col[j + 4 + g];
        uint4 v0 = tab[(size_t)s0 * 16 + c];
        uint4 v1 = tab[(size_t)s1 * 16 + c];
        a0 += u2h(v0.x); a1 += u2h(v0.y); a2 += u2h(v0.z); a3 += u2h(v0.w);
        b0 += u2h(v1.x); b1 += u2h(v1.y); b2 += u2h(v1.z); b3 += u2h(v1.w);
    }
    for (; j < end; j += 4) {
        int jj = j + g;
        int s = col[min(jj, end - 1)];
        uint4 v = tab[(size_t)s * 16 + c];
        if (jj < end) {
            b0 += u2h(v.x); b1 += u2h(v.y); b2 += u2h(v.z); b3 += u2h(v.w);
        }
    }
    a0 += b0; a1 += b1; a2 += b2; a3 += b3;

    a0 += u2h((unsigned)__shfl_xor((int)h2u(a0), 16));
    a1 += u2h((unsigned)__shfl_xor((int)h2u(a1), 16));
    a2 += u2h((unsigned)__shfl_xor((int)h2u(a2), 16));
    a3 += u2h((unsigned)__shfl_xor((int)h2u(a3), 16));
    a0 += u2h((unsigned)__shfl_xor((int)h2u(a0), 32));
    a1 += u2h((unsigned)__shfl_xor((int)h2u(a1), 32));
    a2 += u2h((unsigned)__shfl_xor((int)h2u(a2), 32));
    a3 += u2h((unsigned)__shfl_xor((int)h2u(a3), 32));

    if (g == 0) {
        const float dv = dinv[d];
        const float2* bp = (const float2*)&bias[c * 8];
        const float2 q0 = bp[0], q1 = bp[1], q2 = bp[2], q3 = bp[3];
        uint4 o;
        o.x = (unsigned)f2h(fmaxf(fmaf(dv, (float)a0[0], q0.x), 0.f))
            | ((unsigned)f2h(fmaxf(fmaf(dv, (float)a0[1], q0.y), 0.f)) << 16);
        o.y = (unsigned)f2h(fmaxf(fmaf(dv, (float)a1[0], q1.x), 0.f))
            | ((unsigned)f2h(fmaxf(fmaf(dv, (float)a1[1], q1.y), 0.f)) << 16);
        o.z = (unsigned)f2h(fmaxf(fmaf(dv, (float)a2[0], q2.x), 0.f))
            | ((unsigned)f2h(fmaxf(fmaf(dv, (float)a2[1], q2.y), 0.f)) << 16);
        o.w = (unsigned)f2h(fmaxf(fmaf(dv, (float)a3[0], q3.x), 0.f))
            | ((unsigned)f2h(fmaxf(fmaf(dv, (float)a3[1], q3.y), 0.f)) << 16);
        out[(size_t)d * 16 + c] = o;
    }
}

__global__ __launch_bounds__(256) void agg_fused(const uint4* tp, const int* rpp, const int* clp,
                                                 const float* dvp, const float* bp, uint4* op,
                                                 int np_, int nwbp,
                                                 const uint4* td, const int* rpd, const int* cld,
                                                 const float* dvd, const float* bd, uint4* od,
                                                 int nd_) {
    int b = blockIdx.x;
    if (b < nwbp) agg_body(b, tp, rpp, clp, dvp, bp, op, np_);
    else          agg_body(b - nwbp, td, rpd, cld, dvd, bd, od, nd_);
}

// ---- mean over rows, f16 input ----------------------------------------------
static __device__ __forceinline__ void meanp_body(int bid, const uint4* __restrict__ h, int n,
                                                  int nblk, float* __restrict__ partial) {
    const int t = threadIdx.x;
    const int c = t & 15;
    const int rl = t >> 4;
    const int rpb = (n + nblk - 1) / nblk;
    const int r0 = bid * rpb, r1 = min(n, r0 + rpb);
    float acc[8] = {0.f, 0.f, 0.f, 0.f, 0.f, 0.f, 0.f, 0.f};
    for (int r = r0 + rl; r < r1; r += 16) {
        uint4 v = h[(size_t)r * 16 + c];
        f16x2 p;
        p = u2h(v.x); acc[0] += (float)p[0]; acc[1] += (float)p[1];
        p = u2h(v.y); acc[2] += (float)p[0]; acc[3] += (float)p[1];
        p = u2h(v.z); acc[4] += (float)p[0]; acc[5] += (float)p[1];
        p = u2h(v.w); acc[6] += (float)p[0]; acc[7] += (float)p[1];
    }
    __shared__ float sh[16][128];
    #pragma unroll
    for (int k = 0; k < 8; ++k) sh[rl][c * 8 + k] = acc[k];
    __syncthreads();
    if (t < 128) {
        float s = 0.f;
        #pragma unroll
        for (int i = 0; i < 16; ++i) s += sh[i][t];
        partial[(size_t)bid * 128 + t] = s;
    }
}

__global__ __launch_bounds__(256) void meanp_fused(const uint4* hp, int np_, float* pp,
                                                   const uint4* hd, int nd_, float* pd) {
    int b = blockIdx.x;
    if (b < MPP) meanp_body(b, hp, np_, MPP, pp);
    else         meanp_body(b - MPP, hd, nd_, MPD, pd);
}

static __device__ __forceinline__ void meanf_body(const float* __restrict__ partial, int nrows,
                                                  float inv_n, float* __restrict__ out) {
    const int t = threadIdx.x;
    const int c4 = (t & 31) * 4;
    float4 acc = make_float4(0.f, 0.f, 0.f, 0.f);
    for (int r = (t >> 5); r < nrows; r += 8) {
        float4 v = *(const float4*)&partial[(size_t)r * 128 + c4];
        acc.x += v.x; acc.y += v.y; acc.z += v.z; acc.w += v.w;
    }
    __shared__ float4 sh[256];
    sh[t] = acc; __syncthreads();
    for (int off = 128; off >= 32; off >>= 1) {
        if (t < off) {
            float4 a = sh[t], o = sh[t + off];
            a.x += o.x; a.y += o.y; a.z += o.z; a.w += o.w;
            sh[t] = a;
        }
        __syncthreads();
    }
    if (t < 32) {
        float4 a = sh[t];
        a.x *= inv_n; a.y *= inv_n; a.z *= inv_n; a.w *= inv_n;
        *(float4*)&out[c4] = a;
    }
}

__global__ __launch_bounds__(256) void meanf_fused(const float* pp, int nrp, float invp, float* omp,
                                                   const float* pd, int nrd, float invd, float* omd) {
    if (blockIdx.x == 0) meanf_body(pp, nrp, invp, omp);
    else                 meanf_body(pd, nrd, invd, omd);
}

// ---- MLPs -------------------------------------------------------------------
#define MLP_NB 64
static __device__ __forceinline__ void l1_body(int bid, const float* __restrict__ in,
                                               const float* __restrict__ w1, int IN,
                                               float* __restrict__ partial) {
    const int t = threadIdx.x;
    const int f = t & 127;
    const int half = t >> 7;
    const int kpb = IN / MLP_NB;
    const int k0 = bid * kpb;
    float acc = 0.f;
    #pragma unroll 4
    for (int k = k0 + half; k < k0 + kpb; k += 2)
        acc = fmaf(in[k], w1[(size_t)k * 128 + f], acc);
    __shared__ float sh[256];
    sh[t] = acc; __syncthreads();
    if (half == 0) partial[bid * 128 + f] = sh[f] + sh[128 + f];
}

__global__ __launch_bounds__(256) void seql1_fused(const float* inp, const float* w1p, int INp,
                                                   float* pp,
                                                   const float* ind, const float* w1d, int INd,
                                                   float* pd) {
    int b = blockIdx.x;
    if (b < MLP_NB) l1_body(b, inp, w1p, INp, pp);
    else            l1_body(b - MLP_NB, ind, w1d, INd, pd);
}

static __device__ __forceinline__ void seqfin_body(const float* __restrict__ partial,
                                                   const float* __restrict__ b1,
                                                   const float* __restrict__ w2,
                                                   const float* __restrict__ b2,
                                                   float* __restrict__ out) {
    const int t = threadIdx.x;
    __shared__ float h[128];
    float s = 0.f;
    #pragma unroll 8
    for (int i = 0; i < MLP_NB; ++i) s += partial[i * 128 + t];
    h[t] = fmaxf(s + b1[t], 0.f);
    __syncthreads();
    float acc = 0.f;
    #pragma unroll 8
    for (int k = 0; k < 128; ++k) acc = fmaf(h[k], w2[k * 128 + t], acc);
    out[t] = fmaxf(acc + b2[t], 0.f);
}

__global__ __launch_bounds__(128) void seqfin_fused(const float* pp, const float* b1p,
                                                    const float* w2p, const float* b2p, float* op,
                                                    const float* pd, const float* b1d,
                                                    const float* w2d, const float* b2d, float* od) {
    if (blockIdx.x == 0) seqfin_body(pp, b1p, w2p, b2p, op);
    else                 seqfin_body(pd, b1d, w2d, b2d, od);
}

// head l1: concat folded in (sources selected by k-range; kpb=8 never crosses)
__global__ __launch_bounds__(256) void headl1(const float* s0, const float* s1,
                                              const float* s2, const float* s3,
                                              const float* w1, float* partial) {
    const int b = blockIdx.x, t = threadIdx.x;
    const int f = t & 127, half = t >> 7;
    const int k0 = b * 8;
    const float* sp = (k0 < 128) ? s0 : (k0 < 256) ? s1 : (k0 < 384) ? s2 : s3;
    const int o0 = k0 & 127;
    float acc = 0.f;
    #pragma unroll
    for (int k = half; k < 8; k += 2)
        acc = fmaf(sp[o0 + k], w1[(size_t)(k0 + k) * 128 + f], acc);
    __shared__ float sh[256];
    sh[t] = acc; __syncthreads();
    if (half == 0) partial[b * 128 + f] = sh[f] + sh[128 + f];
}

__global__ __launch_bounds__(128) void head_finish(const float* __restrict__ partial,
                                                   const float* __restrict__ fc1b,
                                                   const float* __restrict__ fc2w,
                                                   const float* __restrict__ fc2b,
                                                   float* __restrict__ out) {
    const int t = threadIdx.x;
    __shared__ float red[128];
    float s = 0.f;
    #pragma unroll 8
    for (int i = 0; i < MLP_NB; ++i) s += partial[i * 128 + t];
    float h = fmaxf(s + fc1b[t], 0.f);
    red[t] = h * fc2w[t];
    __syncthreads();
    for (int off = 64; off > 0; off >>= 1) {
        if (t < off) red[t] += red[t + off];
        __syncthreads();
    }
    if (t == 0) out[0] = red[0] + fc2b[0];
}

static inline size_t align_up(size_t x, size_t a) { return (x + a - 1) / a * a; }

extern "C" void kernel_launch(void* const* d_in, const int* in_sizes, int n_in,
                              void* d_out, int out_size, void* d_ws, size_t ws_size,
                              hipStream_t stream) {
    const float* px   = (const float*)d_in[0];
    const int*   pei  = (const int*)d_in[1];
    const float* dx   = (const float*)d_in[2];
    const int*   dei  = (const int*)d_in[3];
    const float* pseq = (const float*)d_in[4];
    const float* dseq = (const float*)d_in[5];
    const float* pc1w = (const float*)d_in[6];  const float* pc1b = (const float*)d_in[7];
    const float* pc2w = (const float*)d_in[8];  const float* pc2b = (const float*)d_in[9];
    const float* dc1w = (const float*)d_in[10]; const float* dc1b = (const float*)d_in[11];
    const float* dc2w = (const float*)d_in[12]; const float* dc2b = (const float*)d_in[13];
    const float* psw1 = (const float*)d_in[14]; const float* psb1 = (const float*)d_in[15];
    const float* psw2 = (const float*)d_in[16]; const float* psb2 = (const float*)d_in[17];
    const float* dsw1 = (const float*)d_in[18]; const float* dsb1 = (const float*)d_in[19];
    const float* dsw2 = (const float*)d_in[20]; const float* dsb2 = (const float*)d_in[21];
    const float* fc1w = (const float*)d_in[22]; const float* fc1b = (const float*)d_in[23];
    const float* fc2w = (const float*)d_in[24]; const float* fc2b = (const float*)d_in[25];

    const int Np = in_sizes[0] / 128, Ep = in_sizes[1] / 2;
    const int Nd = in_sizes[2] / 64,  Ed = in_sizes[3] / 2;
    const int Psd = in_sizes[4], Dsd = in_sizes[5];

    char* w = (char*)d_ws;
    size_t off = 0;
    auto carve = [&](size_t bytes) -> void* {
        void* p = w + off;
        off = align_up(off + bytes, 256);
        return p;
    };
    unsigned short* bufA_p = (unsigned short*)carve((size_t)Np * 128 * 2);
    unsigned short* bufB_p = (unsigned short*)carve((size_t)Np * 128 * 2);
    unsigned short* bufA_d = (unsigned short*)carve((size_t)Nd * 128 * 2);
    unsigned short* bufB_d = (unsigned short*)carve((size_t)Nd * 128 * 2);
    int*      col_p  = (int*)carve((size_t)Ep * 4);
    unsigned* ebuf_p = (unsigned*)carve((size_t)Ep * 4);
    int*      col_d  = (int*)carve((size_t)Ed * 4);
    unsigned* ebuf_d = (unsigned*)carve((size_t)Ed * 4);
    int*   bcnt_p   = (int*)carve((size_t)NCB * 256 * 4);
    int*   bcnt_d   = (int*)carve((size_t)NCB * 256 * 4);
    int*   bbase_p  = (int*)carve(257 * 4);
    int*   bbase_d  = (int*)carve(257 * 4);
    int*   rowptr_p = (int*)carve(((size_t)Np + 1) * 4);
    int*   rowptr_d = (int*)carve(((size_t)Nd + 1) * 4);
    float* dinv_p   = (float*)carve((size_t)Np * 4);
    float* dinv_d   = (float*)carve((size_t)Nd * 4);
    float* part_p   = (float*)carve((size_t)MPP * 128 * 4);
    float* part_d   = (float*)carve((size_t)MPD * 128 * 4);
    float* mlpp_p   = (float*)carve((size_t)MLP_NB * 128 * 4);
    float* mlpp_d   = (float*)carve((size_t)MLP_NB * 128 * 4);
    float* mlpp_h   = (float*)carve((size_t)MLP_NB * 128 * 4);
    float* pmean    = (float*)carve(512);
    float* dmean    = (float*)carve(512);
    float* pseqo    = (float*)carve(512);
    float* dseqo    = (float*)carve(512);
    (void)ws_size; (void)n_in; (void)out_size;

    const int* psrc = pei; const int* pdst = pei + Ep;
    const int* dsrc = dei; const int* ddst = dei + Ed;
    const int chp = (((Ep + NCB - 1) / NCB) + 255) & ~255;
    const int chd = (((Ed + NCB - 1) / NCB) + 255) & ~255;
    const int nbkp = (Np + BW - 1) >> BSH, nbkd = (Nd + BW - 1) >> BSH;
    const int nbp = (Np + 63) / 64, nbd = (Nd + 63) / 64;
    const int nwbp = (Np + 3) / 4, nwbd = (Nd + 3) / 4;

    // CSR build (both graphs per dispatch)
    csr_hist2 <<<2 * NCB, 256, 0, stream>>>(pdst, Ep, chp, bcnt_p, ddst, Ed, chd, bcnt_d);
    csr_scan2 <<<2, 256, 0, stream>>>(bcnt_p, bbase_p, bcnt_d, bbase_d);
    csr_place2<<<2 * NCB, 256, 0, stream>>>(psrc, pdst, Ep, chp, bcnt_p, bbase_p, ebuf_p,
                                            dsrc, ddst, Ed, chd, bcnt_d, bbase_d, ebuf_d);
    csr_finish2<<<nbkp + nbkd, 256, 0, stream>>>(ebuf_p, bbase_p, Np, Ep, rowptr_p, dinv_p, col_p,
                                                 nbkp, ebuf_d, bbase_d, Nd, Ed, rowptr_d, dinv_d,
                                                 col_d);

    // conv1
    xw1_fused<<<nbp + nbd, 256, 0, stream>>>(px, pc1w, dinv_p, bufA_p, Np, nbp,
                                             dx, dc1w, dinv_d, bufA_d, Nd);
    agg_fused<<<nwbp + nwbd, 256, 0, stream>>>((const uint4*)bufA_p, rowptr_p, col_p, dinv_p, pc1b,
                                               (uint4*)bufB_p, Np, nwbp,
                                               (const uint4*)bufA_d, rowptr_d, col_d, dinv_d, dc1b,
                                               (uint4*)bufB_d, Nd);
    // conv2
    xw2_fused<<<nbp + nbd, 256, 0, stream>>>(bufB_p, pc2w, dinv_p, bufA_p, Np, nbp,
                                             bufB_d, dc2w, dinv_d, bufA_d, Nd);
    agg_fused<<<nwbp + nwbd, 256, 0, stream>>>((const uint4*)bufA_p, rowptr_p, col_p, dinv_p, pc2b,
                                               (uint4*)bufB_p, Np, nwbp,
                                               (const uint4*)bufA_d, rowptr_d, col_d, dinv_d, dc2b,
                                               (uint4*)bufB_d, Nd);
    // means
    meanp_fused<<<MPP + MPD, 256, 0, stream>>>((const uint4*)bufB_p, Np, part_p,
                                               (const uint4*)bufB_d, Nd, part_d);
    meanf_fused<<<2, 256, 0, stream>>>(part_p, MPP, 1.0f / (float)Np, pmean,
                                       part_d, MPD, 1.0f / (float)Nd, dmean);

    // seq MLPs
    seql1_fused<<<2 * MLP_NB, 256, 0, stream>>>(pseq, psw1, Psd, mlpp_p,
                                                dseq, dsw1, Dsd, mlpp_d);
    seqfin_fused<<<2, 128, 0, stream>>>(mlpp_p, psb1, psw2, psb2, pseqo,
                                        mlpp_d, dsb1, dsw2, dsb2, dseqo);

    // head (concat folded into l1)
    headl1<<<MLP_NB, 256, 0, stream>>>(pmean, dmean, pseqo, dseqo, fc1w, mlpp_h);
    head_finish<<<1, 128, 0, stream>>>(mlpp_h, fc1b, fc2w, fc2b, (float*)d_out);
}

// Round 9
// 530.397 us; speedup vs baseline: 4.2804x; 1.1836x over previous
//
#include <hip/hip_runtime.h>
#include <cstdint>
#include <cstddef>

// ---------------------------------------------------------------------------
// GSF-DTA forward: 2x GCNConv (protein), 2x GCNConv (drug), 2 seq MLPs, head.
// R9: fp8-e4m3 message table (rows 128B) — halves random-gather FETCH; agg
//     accumulates f32 via v_cvt_pk_f32_fp8. xw epilogue packs fp8 in LDS.
//     Tail fusion: meanf+seqfin one dispatch, single-block head. 12 launches.
// Fused protein+drug dispatches (R8); bucket-sort CSR (R4); MFMA f16 xw (R6).
// ---------------------------------------------------------------------------

#define NCB 256     // chunk blocks per graph for edge passes
#define BSH 9       // bucket shift: 512 nodes per bucket (needs n <= 131072)
#define BW  512     // 1 << BSH
#define MPP 1024    // mean partial blocks (protein)
#define MPD 512     // mean partial blocks (drug)
#define MLP_NB 64

typedef __attribute__((ext_vector_type(8))) _Float16 f16x8;
typedef __attribute__((ext_vector_type(2))) float f32x2;
typedef __attribute__((ext_vector_type(4))) float f32x4;

static __device__ __forceinline__ unsigned short f2h(float f) {
    _Float16 h = (_Float16)f;
    return __builtin_bit_cast(unsigned short, h);
}

// accumulate 8 fp8 (one uint2) into 8 f32
static __device__ __forceinline__ void acc8(float* a, unsigned u0, unsigned u1) {
    f32x2 p;
    p = __builtin_amdgcn_cvt_pk_f32_fp8((int)u0, false); a[0] += p[0]; a[1] += p[1];
    p = __builtin_amdgcn_cvt_pk_f32_fp8((int)u0, true);  a[2] += p[0]; a[3] += p[1];
    p = __builtin_amdgcn_cvt_pk_f32_fp8((int)u1, false); a[4] += p[0]; a[5] += p[1];
    p = __builtin_amdgcn_cvt_pk_f32_fp8((int)u1, true);  a[6] += p[0]; a[7] += p[1];
}

// ---- CSR build bodies (bucket sort by dst) ----------------------------------
static __device__ __forceinline__ void hist_body(int blk, const int* __restrict__ dst, int E,
                                                 int chunk, int* __restrict__ bcnt) {
    __shared__ int h[256];
    const int t = threadIdx.x;
    h[t] = 0; __syncthreads();
    const int e0 = blk * chunk;
    const int e1 = min(E, e0 + chunk);
    for (int e = e0 + t; e < e1; e += 256) atomicAdd(&h[dst[e] >> BSH], 1);
    __syncthreads();
    bcnt[blk * 256 + t] = h[t];
}

static __device__ __forceinline__ void scan_body(int* __restrict__ bcnt, int* __restrict__ bbase) {
    const int t = threadIdx.x;
    int run = 0;
    for (int blk = 0; blk < NCB; ++blk) {
        int idx = blk * 256 + t;
        int v = bcnt[idx]; bcnt[idx] = run; run += v;
    }
    __shared__ int sh[256];
    sh[t] = run; __syncthreads();
    for (int off = 1; off < 256; off <<= 1) {
        int add = (t >= off) ? sh[t - off] : 0;
        __syncthreads(); sh[t] += add; __syncthreads();
    }
    bbase[t] = sh[t] - run;
    if (t == 255) bbase[256] = sh[255];
}

static __device__ __forceinline__ void place_body(int blk, const int* __restrict__ src,
                                                  const int* __restrict__ dst, int E, int chunk,
                                                  const int* __restrict__ bcnt,
                                                  const int* __restrict__ bbase,
                                                  unsigned* __restrict__ ebuf) {
    __shared__ int cur[256];
    const int t = threadIdx.x;
    cur[t] = bbase[t] + bcnt[blk * 256 + t];
    __syncthreads();
    const int e0 = blk * chunk;
    const int e1 = min(E, e0 + chunk);
    for (int e = e0 + t; e < e1; e += 256) {
        int d = dst[e];
        int b = d >> BSH;
        int pos = atomicAdd(&cur[b], 1);
        ebuf[pos] = ((unsigned)src[e] << BSH) | (unsigned)(d & (BW - 1));
    }
}

static __device__ __forceinline__ void finish_body(int b, const unsigned* __restrict__ ebuf,
                                                   const int* __restrict__ bbase, int n, int E,
                                                   int* __restrict__ rowptr,
                                                   float* __restrict__ dinv,
                                                   int* __restrict__ col) {
    __shared__ int hist[BW];
    __shared__ int cur[BW];
    __shared__ int sh[256];
    const int t = threadIdx.x;
    const int nb = b << BSH;
    const int w = min(BW, n - nb);
    const int rb = bbase[b], re = bbase[b + 1];
    hist[2 * t] = 0; hist[2 * t + 1] = 0;
    __syncthreads();
    for (int i = rb + t; i < re; i += 256) atomicAdd(&hist[ebuf[i] & (BW - 1)], 1);
    __syncthreads();
    const int a0 = hist[2 * t], a1 = hist[2 * t + 1];
    if (2 * t     < w) dinv[nb + 2 * t]     = rsqrtf((float)(a0 + 1));
    if (2 * t + 1 < w) dinv[nb + 2 * t + 1] = rsqrtf((float)(a1 + 1));
    sh[t] = a0 + a1; __syncthreads();
    for (int off = 1; off < 256; off <<= 1) {
        int add = (t >= off) ? sh[t - off] : 0;
        __syncthreads(); sh[t] += add; __syncthreads();
    }
    int base = t ? sh[t - 1] : 0;
    const int p0 = rb + base, p1 = rb + base + a0;
    if (2 * t     < w) rowptr[nb + 2 * t]     = p0;
    if (2 * t + 1 < w) rowptr[nb + 2 * t + 1] = p1;
    cur[2 * t] = p0; cur[2 * t + 1] = p1;
    __syncthreads();
    for (int i = rb + t; i < re; i += 256) {
        unsigned r = ebuf[i];
        int pos = atomicAdd(&cur[r & (BW - 1)], 1);
        col[pos] = (int)(r >> BSH);
    }
    if (b == 0 && t == 0) rowptr[n] = E;
}

__global__ __launch_bounds__(256) void csr_hist2(const int* dp, int Ep_, int chp, int* bcp,
                                                 const int* dd, int Ed_, int chd, int* bcd) {
    int b = blockIdx.x;
    if (b < NCB) hist_body(b, dp, Ep_, chp, bcp);
    else         hist_body(b - NCB, dd, Ed_, chd, bcd);
}

__global__ __launch_bounds__(256) void csr_scan2(int* bcp, int* bbp, int* bcd, int* bbd) {
    if (blockIdx.x == 0) scan_body(bcp, bbp);
    else                 scan_body(bcd, bbd);
}

__global__ __launch_bounds__(256) void csr_place2(const int* sp, const int* dp, int Ep_, int chp,
                                                  const int* bcp, const int* bbp, unsigned* ebp,
                                                  const int* sd, const int* dd, int Ed_, int chd,
                                                  const int* bcd, const int* bbd, unsigned* ebd) {
    int b = blockIdx.x;
    if (b < NCB) place_body(b, sp, dp, Ep_, chp, bcp, bbp, ebp);
    else         place_body(b - NCB, sd, dd, Ed_, chd, bcd, bbd, ebd);
}

__global__ __launch_bounds__(256) void csr_finish2(const unsigned* ebp, const int* bbp, int np_,
                                                   int Ep_, int* rpp, float* dvp, int* clp, int nbkp,
                                                   const unsigned* ebd, const int* bbd, int nd_,
                                                   int Ed_, int* rpd, float* dvd, int* cld) {
    int b = blockIdx.x;
    if (b < nbkp) finish_body(b, ebp, bbp, np_, Ep_, rpp, dvp, clp);
    else          finish_body(b - nbkp, ebd, bbd, nd_, Ed_, rpd, dvd, cld);
}

// ---- x@W via MFMA f16; out = fp8( dinv[row] * (x@W) ), rows 128B ------------
template <int K, bool IN16>
static __device__ __forceinline__ void xw_body(_Float16* __restrict__ Wt,
                                               unsigned char* __restrict__ T8, int bid,
                                               const void* __restrict__ xv,
                                               const float* __restrict__ W,
                                               const float* __restrict__ dinv,
                                               uint4* __restrict__ out8, int n) {
    constexpr int CH = K / 8;
    constexpr int KS = K / 32;
    const int tid = threadIdx.x;

    for (int i = tid; i < 128 * CH; i += 256) {
        const int col = i / CH, ch = i % CH;
        f16x8 v;
        #pragma unroll
        for (int j = 0; j < 8; ++j) v[j] = (_Float16)W[(ch * 8 + j) * 128 + col];
        *(f16x8*)&Wt[(col * CH + (ch ^ (col & (CH - 1)))) * 8] = v;
    }
    __syncthreads();

    const int wv = tid >> 6, ln = tid & 63;
    const int r0 = bid * 64 + wv * 16;
    const int row = r0 + (ln & 15);
    const int kg = (ln >> 4) * 8;

    f16x8 a[KS];
    if (row < n) {
        if constexpr (IN16) {
            const unsigned short* xr = (const unsigned short*)xv + (size_t)row * K;
            #pragma unroll
            for (int ks = 0; ks < KS; ++ks)
                a[ks] = *(const f16x8*)&xr[ks * 32 + kg];
        } else {
            const float* xr = (const float*)xv + (size_t)row * K;
            #pragma unroll
            for (int ks = 0; ks < KS; ++ks) {
                float4 u0 = *(const float4*)&xr[ks * 32 + kg];
                float4 u1 = *(const float4*)&xr[ks * 32 + kg + 4];
                f16x8 v;
                v[0] = (_Float16)u0.x; v[1] = (_Float16)u0.y;
                v[2] = (_Float16)u0.z; v[3] = (_Float16)u0.w;
                v[4] = (_Float16)u1.x; v[5] = (_Float16)u1.y;
                v[6] = (_Float16)u1.z; v[7] = (_Float16)u1.w;
                a[ks] = v;
            }
        }
    } else {
        #pragma unroll
        for (int ks = 0; ks < KS; ++ks) {
            f16x8 v;
            #pragma unroll
            for (int j = 0; j < 8; ++j) v[j] = (_Float16)0.f;
            a[ks] = v;
        }
    }

    const int rw0l = wv * 16 + (ln >> 4) * 4;   // local row of lane's 4 outputs
    float dv[4];
    #pragma unroll
    for (int r = 0; r < 4; ++r) dv[r] = (bid * 64 + rw0l + r < n) ? dinv[bid * 64 + rw0l + r] : 0.f;

    const int cl = ln & 15;
    #pragma unroll
    for (int nt = 0; nt < 8; ++nt) {
        const int col = nt * 16 + cl;
        f32x4 c = {0.f, 0.f, 0.f, 0.f};
        #pragma unroll
        for (int ks = 0; ks < KS; ++ks) {
            const int ch = ks * 4 + (ln >> 4);
            f16x8 b = *(const f16x8*)&Wt[(col * CH + (ch ^ (col & (CH - 1)))) * 8];
            c = __builtin_amdgcn_mfma_f32_16x16x32_f16(a[ks], b, c, 0, 0, 0);
        }
        #pragma unroll
        for (int r = 0; r < 4; ++r) {
            int q = __builtin_amdgcn_cvt_pk_fp8_f32(c[r] * dv[r], 0.f, 0, false);
            T8[(rw0l + r) * 128 + col] = (unsigned char)q;
        }
    }
    __syncthreads();
    // bulk store: 64 rows x 128B = 512 uint4
    for (int i = tid; i < 512; i += 256) {
        const int lr = i >> 3, ch = i & 7;
        const int rr = bid * 64 + lr;
        if (rr < n) out8[(size_t)rr * 8 + ch] = *(const uint4*)&T8[lr * 128 + ch * 16];
    }
    __syncthreads();   // T8 safe for (non-existent) reuse; keeps block phases aligned
}

__global__ __launch_bounds__(256) void xw1_fused(const float* xp, const float* Wp,
                                                 const float* dvp, uint4* op, int np_, int nbp,
                                                 const float* xd, const float* Wd,
                                                 const float* dvd, uint4* od, int nd_) {
    __shared__ _Float16 Wt[128 * 128];
    __shared__ unsigned char T8[64 * 128];
    int b = blockIdx.x;
    if (b < nbp) xw_body<128, false>(Wt, T8, b, xp, Wp, dvp, op, np_);
    else         xw_body<64,  false>(Wt, T8, b - nbp, xd, Wd, dvd, od, nd_);
}

__global__ __launch_bounds__(256) void xw2_fused(const unsigned short* xp, const float* Wp,
                                                 const float* dvp, uint4* op, int np_, int nbp,
                                                 const unsigned short* xd, const float* Wd,
                                                 const float* dvd, uint4* od, int nd_) {
    __shared__ _Float16 Wt[128 * 128];
    __shared__ unsigned char T8[64 * 128];
    int b = blockIdx.x;
    if (b < nbp) xw_body<128, true>(Wt, T8, b, xp, Wp, dvp, op, np_);
    else         xw_body<128, true>(Wt, T8, b - nbp, xd, Wd, dvd, od, nd_);
}

// ---- aggregation: one wave per node, quad-edge fp8 gather, f32 accumulate ---
// tab row = 128B fp8 = 16 uint2. lane = (group g = ln>>4, chunk c = ln&15).
static __device__ __forceinline__ void agg_body(int bid, const uint2* __restrict__ tab,
                                                const int* __restrict__ rowptr,
                                                const int* __restrict__ col,
                                                const float* __restrict__ dinv,
                                                const float* __restrict__ bias,
                                                uint4* __restrict__ out, int n) {
    const int wv = threadIdx.x >> 6, ln = threadIdx.x & 63;
    const int d = bid * 4 + wv;
    if (d >= n) return;
    const int g = ln >> 4;
    const int c = ln & 15;
    const int beg = rowptr[d], end = rowptr[d + 1];

    float a[8] = {0.f, 0.f, 0.f, 0.f, 0.f, 0.f, 0.f, 0.f};
    float b[8] = {0.f, 0.f, 0.f, 0.f, 0.f, 0.f, 0.f, 0.f};
    if (g == 0) {                       // self-loop term
        uint2 v = tab[(size_t)d * 16 + c];
        acc8(a, v.x, v.y);
    }

    int j = beg;
    for (; j + 8 <= end; j += 8) {      // 8 edges per iteration
        int s0 = col[j + g];
        int s1 = col[j + 4 + g];
        uint2 v0 = tab[(size_t)s0 * 16 + c];
        uint2 v1 = tab[(size_t)s1 * 16 + c];
        acc8(a, v0.x, v0.y);
        acc8(b, v1.x, v1.y);
    }
    for (; j < end; j += 4) {           // tail quads (predicated)
        int jj = j + g;
        int s = col[min(jj, end - 1)];
        uint2 v = tab[(size_t)s * 16 + c];
        if (jj < end) acc8(b, v.x, v.y);
    }
    #pragma unroll
    for (int i = 0; i < 8; ++i) a[i] += b[i];

    #pragma unroll
    for (int i = 0; i < 8; ++i) a[i] += __shfl_xor(a[i], 16);
    #pragma unroll
    for (int i = 0; i < 8; ++i) a[i] += __shfl_xor(a[i], 32);

    if (g == 0) {
        const float dv = dinv[d];
        const float* bp = &bias[c * 8];
        uint4 o;
        o.x = (unsigned)f2h(fmaxf(fmaf(dv, a[0], bp[0]), 0.f))
            | ((unsigned)f2h(fmaxf(fmaf(dv, a[1], bp[1]), 0.f)) << 16);
        o.y = (unsigned)f2h(fmaxf(fmaf(dv, a[2], bp[2]), 0.f))
            | ((unsigned)f2h(fmaxf(fmaf(dv, a[3], bp[3]), 0.f)) << 16);
        o.z = (unsigned)f2h(fmaxf(fmaf(dv, a[4], bp[4]), 0.f))
            | ((unsigned)f2h(fmaxf(fmaf(dv, a[5], bp[5]), 0.f)) << 16);
        o.w = (unsigned)f2h(fmaxf(fmaf(dv, a[6], bp[6]), 0.f))
            | ((unsigned)f2h(fmaxf(fmaf(dv, a[7], bp[7]), 0.f)) << 16);
        out[(size_t)d * 16 + c] = o;
    }
}

__global__ __launch_bounds__(256) void agg_fused(const uint2* tp, const int* rpp, const int* clp,
                                                 const float* dvp, const float* bp, uint4* op,
                                                 int np_, int nwbp,
                                                 const uint2* td, const int* rpd, const int* cld,
                                                 const float* dvd, const float* bd, uint4* od,
                                                 int nd_) {
    int b = blockIdx.x;
    if (b < nwbp) agg_body(b, tp, rpp, clp, dvp, bp, op, np_);
    else          agg_body(b - nwbp, td, rpd, cld, dvd, bd, od, nd_);
}

// ---- mean over rows, f16 input ----------------------------------------------
typedef __attribute__((ext_vector_type(2))) _Float16 f16x2;
static __device__ __forceinline__ f16x2 u2h(unsigned u) {
    return __builtin_bit_cast(f16x2, u);
}

static __device__ __forceinline__ void meanp_body(int bid, const uint4* __restrict__ h, int n,
                                                  int nblk, float* __restrict__ partial) {
    const int t = threadIdx.x;
    const int c = t & 15;
    const int rl = t >> 4;
    const int rpb = (n + nblk - 1) / nblk;
    const int r0 = bid * rpb, r1 = min(n, r0 + rpb);
    float acc[8] = {0.f, 0.f, 0.f, 0.f, 0.f, 0.f, 0.f, 0.f};
    for (int r = r0 + rl; r < r1; r += 16) {
        uint4 v = h[(size_t)r * 16 + c];
        f16x2 p;
        p = u2h(v.x); acc[0] += (float)p[0]; acc[1] += (float)p[1];
        p = u2h(v.y); acc[2] += (float)p[0]; acc[3] += (float)p[1];
        p = u2h(v.z); acc[4] += (float)p[0]; acc[5] += (float)p[1];
        p = u2h(v.w); acc[6] += (float)p[0]; acc[7] += (float)p[1];
    }
    __shared__ float sh[16][128];
    #pragma unroll
    for (int k = 0; k < 8; ++k) sh[rl][c * 8 + k] = acc[k];
    __syncthreads();
    if (t < 128) {
        float s = 0.f;
        #pragma unroll
        for (int i = 0; i < 16; ++i) s += sh[i][t];
        partial[(size_t)bid * 128 + t] = s;
    }
}

__global__ __launch_bounds__(256) void meanp_fused(const uint4* hp, int np_, float* pp,
                                                   const uint4* hd, int nd_, float* pd) {
    int b = blockIdx.x;
    if (b < MPP) meanp_body(b, hp, np_, MPP, pp);
    else         meanp_body(b - MPP, hd, nd_, MPD, pd);
}

static __device__ __forceinline__ void meanf_body(const float* __restrict__ partial, int nrows,
                                                  float inv_n, float* __restrict__ out) {
    const int t = threadIdx.x;
    const int c4 = (t & 31) * 4;
    float4 acc = make_float4(0.f, 0.f, 0.f, 0.f);
    for (int r = (t >> 5); r < nrows; r += 8) {
        float4 v = *(const float4*)&partial[(size_t)r * 128 + c4];
        acc.x += v.x; acc.y += v.y; acc.z += v.z; acc.w += v.w;
    }
    __shared__ float4 sh[256];
    sh[t] = acc; __syncthreads();
    for (int off = 128; off >= 32; off >>= 1) {
        if (t < off) {
            float4 a = sh[t], o = sh[t + off];
            a.x += o.x; a.y += o.y; a.z += o.z; a.w += o.w;
            sh[t] = a;
        }
        __syncthreads();
    }
    if (t < 32) {
        float4 a = sh[t];
        a.x *= inv_n; a.y *= inv_n; a.z *= inv_n; a.w *= inv_n;
        *(float4*)&out[c4] = a;
    }
}

static __device__ __forceinline__ void seqfin_body(const float* __restrict__ partial,
                                                   const float* __restrict__ b1,
                                                   const float* __restrict__ w2,
                                                   const float* __restrict__ b2,
                                                   float* __restrict__ out) {
    const int t = threadIdx.x;          // 256; only t<128 active around syncs
    __shared__ float h[128];
    if (t < 128) {
        float s = 0.f;
        #pragma unroll 8
        for (int i = 0; i < MLP_NB; ++i) s += partial[i * 128 + t];
        h[t] = fmaxf(s + b1[t], 0.f);
    }
    __syncthreads();
    if (t < 128) {
        float acc = 0.f;
        #pragma unroll 8
        for (int k = 0; k < 128; ++k) acc = fmaf(h[k], w2[k * 128 + t], acc);
        out[t] = fmaxf(acc + b2[t], 0.f);
    }
}

// block 0: meanf protein, 1: meanf drug, 2: seqfin protein, 3: seqfin drug
__global__ __launch_bounds__(256) void finish_fused(const float* pp, float invp, float* omp,
                                                    const float* pd, float invd, float* omd,
                                                    const float* sp, const float* b1p,
                                                    const float* w2p, const float* b2p, float* osp,
                                                    const float* sd, const float* b1d,
                                                    const float* w2d, const float* b2d, float* osd) {
    const int b = blockIdx.x;
    if      (b == 0) meanf_body(pp, MPP, invp, omp);
    else if (b == 1) meanf_body(pd, MPD, invd, omd);
    else if (b == 2) seqfin_body(sp, b1p, w2p, b2p, osp);
    else             seqfin_body(sd, b1d, w2d, b2d, osd);
}

// ---- seq MLP layer 1 --------------------------------------------------------
static __device__ __forceinline__ void l1_body(int bid, const float* __restrict__ in,
                                               const float* __restrict__ w1, int IN,
                                               float* __restrict__ partial) {
    const int t = threadIdx.x;
    const int f = t & 127;
    const int half = t >> 7;
    const int kpb = IN / MLP_NB;
    const int k0 = bid * kpb;
    float acc = 0.f;
    #pragma unroll 4
    for (int k = k0 + half; k < k0 + kpb; k += 2)
        acc = fmaf(in[k], w1[(size_t)k * 128 + f], acc);
    __shared__ float sh[256];
    sh[t] = acc; __syncthreads();
    if (half == 0) partial[bid * 128 + f] = sh[f] + sh[128 + f];
}

__global__ __launch_bounds__(256) void seql1_fused(const float* inp, const float* w1p, int INp,
                                                   float* pp,
                                                   const float* ind, const float* w1d, int INd,
                                                   float* pd) {
    int b = blockIdx.x;
    if (b < MLP_NB) l1_body(b, inp, w1p, INp, pp);
    else            l1_body(b - MLP_NB, ind, w1d, INd, pd);
}

// ---- head: one block, both layers -------------------------------------------
__global__ __launch_bounds__(256) void head_one(const float* pm, const float* dm,
                                                const float* ps, const float* ds2,
                                                const float* fc1w, const float* fc1b,
                                                const float* fc2w, const float* fc2b,
                                                float* out) {
    const int t = threadIdx.x;          // 256
    __shared__ float comb[512];
    if (t < 128) {
        comb[t] = pm[t]; comb[128 + t] = dm[t];
        comb[256 + t] = ps[t]; comb[384 + t] = ds2[t];
    }
    __syncthreads();
    const int f = t & 127, half = t >> 7;
    float acc = 0.f;
    const int kb = half * 256;
    #pragma unroll 8
    for (int k = kb; k < kb + 256; ++k)
        acc = fmaf(comb[k], fc1w[(size_t)k * 128 + f], acc);
    __shared__ float hs[256];
    hs[t] = acc; __syncthreads();
    __shared__ float red[128];
    if (t < 128) {
        float h = fmaxf(hs[t] + hs[128 + t] + fc1b[t], 0.f);
        red[t] = h * fc2w[t];
    }
    __syncthreads();
    for (int off = 64; off > 0; off >>= 1) {
        if (t < off) red[t] += red[t + off];
        __syncthreads();
    }
    if (t == 0) out[0] = red[0] + fc2b[0];
}

static inline size_t align_up(size_t x, size_t a) { return (x + a - 1) / a * a; }

extern "C" void kernel_launch(void* const* d_in, const int* in_sizes, int n_in,
                              void* d_out, int out_size, void* d_ws, size_t ws_size,
                              hipStream_t stream) {
    const float* px   = (const float*)d_in[0];
    const int*   pei  = (const int*)d_in[1];
    const float* dx   = (const float*)d_in[2];
    const int*   dei  = (const int*)d_in[3];
    const float* pseq = (const float*)d_in[4];
    const float* dseq = (const float*)d_in[5];
    const float* pc1w = (const float*)d_in[6];  const float* pc1b = (const float*)d_in[7];
    const float* pc2w = (const float*)d_in[8];  const float* pc2b = (const float*)d_in[9];
    const float* dc1w = (const float*)d_in[10]; const float* dc1b = (const float*)d_in[11];
    const float* dc2w = (const float*)d_in[12]; const float* dc2b = (const float*)d_in[13];
    const float* psw1 = (const float*)d_in[14]; const float* psb1 = (const float*)d_in[15];
    const float* psw2 = (const float*)d_in[16]; const float* psb2 = (const float*)d_in[17];
    const float* dsw1 = (const float*)d_in[18]; const float* dsb1 = (const float*)d_in[19];
    const float* dsw2 = (const float*)d_in[20]; const float* dsb2 = (const float*)d_in[21];
    const float* fc1w = (const float*)d_in[22]; const float* fc1b = (const float*)d_in[23];
    const float* fc2w = (const float*)d_in[24]; const float* fc2b = (const float*)d_in[25];

    const int Np = in_sizes[0] / 128, Ep = in_sizes[1] / 2;
    const int Nd = in_sizes[2] / 64,  Ed = in_sizes[3] / 2;
    const int Psd = in_sizes[4], Dsd = in_sizes[5];

    char* w = (char*)d_ws;
    size_t off = 0;
    auto carve = [&](size_t bytes) -> void* {
        void* p = w + off;
        off = align_up(off + bytes, 256);
        return p;
    };
    unsigned char* tab_p  = (unsigned char*)carve((size_t)Np * 128);      // fp8 msg table
    unsigned short* buf_p = (unsigned short*)carve((size_t)Np * 128 * 2); // f16 hidden
    unsigned char* tab_d  = (unsigned char*)carve((size_t)Nd * 128);
    unsigned short* buf_d = (unsigned short*)carve((size_t)Nd * 128 * 2);
    int*      col_p  = (int*)carve((size_t)Ep * 4);
    unsigned* ebuf_p = (unsigned*)carve((size_t)Ep * 4);
    int*      col_d  = (int*)carve((size_t)Ed * 4);
    unsigned* ebuf_d = (unsigned*)carve((size_t)Ed * 4);
    int*   bcnt_p   = (int*)carve((size_t)NCB * 256 * 4);
    int*   bcnt_d   = (int*)carve((size_t)NCB * 256 * 4);
    int*   bbase_p  = (int*)carve(257 * 4);
    int*   bbase_d  = (int*)carve(257 * 4);
    int*   rowptr_p = (int*)carve(((size_t)Np + 1) * 4);
    int*   rowptr_d = (int*)carve(((size_t)Nd + 1) * 4);
    float* dinv_p   = (float*)carve((size_t)Np * 4);
    float* dinv_d   = (float*)carve((size_t)Nd * 4);
    float* part_p   = (float*)carve((size_t)MPP * 128 * 4);
    float* part_d   = (float*)carve((size_t)MPD * 128 * 4);
    float* mlpp_p   = (float*)carve((size_t)MLP_NB * 128 * 4);
    float* mlpp_d   = (float*)carve((size_t)MLP_NB * 128 * 4);
    float* pmean    = (float*)carve(512);
    float* dmean    = (float*)carve(512);
    float* pseqo    = (float*)carve(512);
    float* dseqo    = (float*)carve(512);
    (void)ws_size; (void)n_in; (void)out_size;

    const int* psrc = pei; const int* pdst = pei + Ep;
    const int* dsrc = dei; const int* ddst = dei + Ed;
    const int chp = (((Ep + NCB - 1) / NCB) + 255) & ~255;
    const int chd = (((Ed + NCB - 1) / NCB) + 255) & ~255;
    const int nbkp = (Np + BW - 1) >> BSH, nbkd = (Nd + BW - 1) >> BSH;
    const int nbp = (Np + 63) / 64, nbd = (Nd + 63) / 64;
    const int nwbp = (Np + 3) / 4, nwbd = (Nd + 3) / 4;

    // CSR build (both graphs per dispatch)
    csr_hist2 <<<2 * NCB, 256, 0, stream>>>(pdst, Ep, chp, bcnt_p, ddst, Ed, chd, bcnt_d);
    csr_scan2 <<<2, 256, 0, stream>>>(bcnt_p, bbase_p, bcnt_d, bbase_d);
    csr_place2<<<2 * NCB, 256, 0, stream>>>(psrc, pdst, Ep, chp, bcnt_p, bbase_p, ebuf_p,
                                            dsrc, ddst, Ed, chd, bcnt_d, bbase_d, ebuf_d);
    csr_finish2<<<nbkp + nbkd, 256, 0, stream>>>(ebuf_p, bbase_p, Np, Ep, rowptr_p, dinv_p, col_p,
                                                 nbkp, ebuf_d, bbase_d, Nd, Ed, rowptr_d, dinv_d,
                                                 col_d);

    // conv1
    xw1_fused<<<nbp + nbd, 256, 0, stream>>>(px, pc1w, dinv_p, (uint4*)tab_p, Np, nbp,
                                             dx, dc1w, dinv_d, (uint4*)tab_d, Nd);
    agg_fused<<<nwbp + nwbd, 256, 0, stream>>>((const uint2*)tab_p, rowptr_p, col_p, dinv_p, pc1b,
                                               (uint4*)buf_p, Np, nwbp,
                                               (const uint2*)tab_d, rowptr_d, col_d, dinv_d, dc1b,
                                               (uint4*)buf_d, Nd);
    // conv2
    xw2_fused<<<nbp + nbd, 256, 0, stream>>>(buf_p, pc2w, dinv_p, (uint4*)tab_p, Np, nbp,
                                             buf_d, dc2w, dinv_d, (uint4*)tab_d, Nd);
    agg_fused<<<nwbp + nwbd, 256, 0, stream>>>((const uint2*)tab_p, rowptr_p, col_p, dinv_p, pc2b,
                                               (uint4*)buf_p, Np, nwbp,
                                               (const uint2*)tab_d, rowptr_d, col_d, dinv_d, dc2b,
                                               (uint4*)buf_d, Nd);
    // means
    meanp_fused<<<MPP + MPD, 256, 0, stream>>>((const uint4*)buf_p, Np, part_p,
                                               (const uint4*)buf_d, Nd, part_d);
    // seq MLPs layer 1
    seql1_fused<<<2 * MLP_NB, 256, 0, stream>>>(pseq, psw1, Psd, mlpp_p,
                                                dseq, dsw1, Dsd, mlpp_d);
    // mean finish + seq finish (one dispatch)
    finish_fused<<<4, 256, 0, stream>>>(part_p, 1.0f / (float)Np, pmean,
                                        part_d, 1.0f / (float)Nd, dmean,
                                        mlpp_p, psb1, psw2, psb2, pseqo,
                                        mlpp_d, dsb1, dsw2, dsb2, dseqo);
    // head (single block, both layers)
    head_one<<<1, 256, 0, stream>>>(pmean, dmean, pseqo, dseqo, fc1w, fc1b, fc2w, fc2b,
                                    (float*)d_out);
}

// Round 10
// 529.084 us; speedup vs baseline: 4.2910x; 1.0025x over previous
//
#include <hip/hip_runtime.h>
#include <cstdint>
#include <cstddef>

// ---------------------------------------------------------------------------
// GSF-DTA forward: 2x GCNConv (protein), 2x GCNConv (drug), 2 seq MLPs, head.
// R10: packed f32x2 accumulate in agg (v_pk_add_f32: 12 -> 8 VALU per 8 fp8;
//      R9 agg was VALU-bound: 56% VALU, 24% HBM). meanp+seql1 merged (11
//      launches).
// fp8 msg table (R9); fused protein+drug dispatches (R8); bucket CSR (R4).
// ---------------------------------------------------------------------------

#define NCB 256     // chunk blocks per graph for edge passes
#define BSH 9       // bucket shift: 512 nodes per bucket (needs n <= 131072)
#define BW  512     // 1 << BSH
#define MPP 1024    // mean partial blocks (protein)
#define MPD 512     // mean partial blocks (drug)
#define MLP_NB 64

typedef __attribute__((ext_vector_type(8))) _Float16 f16x8;
typedef __attribute__((ext_vector_type(2))) _Float16 f16x2;
typedef __attribute__((ext_vector_type(2))) float f32x2;
typedef __attribute__((ext_vector_type(4))) float f32x4;

static __device__ __forceinline__ unsigned short f2h(float f) {
    _Float16 h = (_Float16)f;
    return __builtin_bit_cast(unsigned short, h);
}
static __device__ __forceinline__ f16x2 u2h(unsigned u) {
    return __builtin_bit_cast(f16x2, u);
}

// accumulate 8 fp8 (one uint2) into 4 packed f32x2 (v_pk_add_f32)
static __device__ __forceinline__ void acc8v(f32x2* a, unsigned u0, unsigned u1) {
    a[0] += __builtin_amdgcn_cvt_pk_f32_fp8((int)u0, false);
    a[1] += __builtin_amdgcn_cvt_pk_f32_fp8((int)u0, true);
    a[2] += __builtin_amdgcn_cvt_pk_f32_fp8((int)u1, false);
    a[3] += __builtin_amdgcn_cvt_pk_f32_fp8((int)u1, true);
}

// ---- CSR build bodies (bucket sort by dst) ----------------------------------
static __device__ __forceinline__ void hist_body(int blk, const int* __restrict__ dst, int E,
                                                 int chunk, int* __restrict__ bcnt) {
    __shared__ int h[256];
    const int t = threadIdx.x;
    h[t] = 0; __syncthreads();
    const int e0 = blk * chunk;
    const int e1 = min(E, e0 + chunk);
    for (int e = e0 + t; e < e1; e += 256) atomicAdd(&h[dst[e] >> BSH], 1);
    __syncthreads();
    bcnt[blk * 256 + t] = h[t];
}

static __device__ __forceinline__ void scan_body(int* __restrict__ bcnt, int* __restrict__ bbase) {
    const int t = threadIdx.x;
    int run = 0;
    for (int blk = 0; blk < NCB; ++blk) {
        int idx = blk * 256 + t;
        int v = bcnt[idx]; bcnt[idx] = run; run += v;
    }
    __shared__ int sh[256];
    sh[t] = run; __syncthreads();
    for (int off = 1; off < 256; off <<= 1) {
        int add = (t >= off) ? sh[t - off] : 0;
        __syncthreads(); sh[t] += add; __syncthreads();
    }
    bbase[t] = sh[t] - run;
    if (t == 255) bbase[256] = sh[255];
}

static __device__ __forceinline__ void place_body(int blk, const int* __restrict__ src,
                                                  const int* __restrict__ dst, int E, int chunk,
                                                  const int* __restrict__ bcnt,
                                                  const int* __restrict__ bbase,
                                                  unsigned* __restrict__ ebuf) {
    __shared__ int cur[256];
    const int t = threadIdx.x;
    cur[t] = bbase[t] + bcnt[blk * 256 + t];
    __syncthreads();
    const int e0 = blk * chunk;
    const int e1 = min(E, e0 + chunk);
    for (int e = e0 + t; e < e1; e += 256) {
        int d = dst[e];
        int b = d >> BSH;
        int pos = atomicAdd(&cur[b], 1);
        ebuf[pos] = ((unsigned)src[e] << BSH) | (unsigned)(d & (BW - 1));
    }
}

static __device__ __forceinline__ void finish_body(int b, const unsigned* __restrict__ ebuf,
                                                   const int* __restrict__ bbase, int n, int E,
                                                   int* __restrict__ rowptr,
                                                   float* __restrict__ dinv,
                                                   int* __restrict__ col) {
    __shared__ int hist[BW];
    __shared__ int cur[BW];
    __shared__ int sh[256];
    const int t = threadIdx.x;
    const int nb = b << BSH;
    const int w = min(BW, n - nb);
    const int rb = bbase[b], re = bbase[b + 1];
    hist[2 * t] = 0; hist[2 * t + 1] = 0;
    __syncthreads();
    for (int i = rb + t; i < re; i += 256) atomicAdd(&hist[ebuf[i] & (BW - 1)], 1);
    __syncthreads();
    const int a0 = hist[2 * t], a1 = hist[2 * t + 1];
    if (2 * t     < w) dinv[nb + 2 * t]     = rsqrtf((float)(a0 + 1));
    if (2 * t + 1 < w) dinv[nb + 2 * t + 1] = rsqrtf((float)(a1 + 1));
    sh[t] = a0 + a1; __syncthreads();
    for (int off = 1; off < 256; off <<= 1) {
        int add = (t >= off) ? sh[t - off] : 0;
        __syncthreads(); sh[t] += add; __syncthreads();
    }
    int base = t ? sh[t - 1] : 0;
    const int p0 = rb + base, p1 = rb + base + a0;
    if (2 * t     < w) rowptr[nb + 2 * t]     = p0;
    if (2 * t + 1 < w) rowptr[nb + 2 * t + 1] = p1;
    cur[2 * t] = p0; cur[2 * t + 1] = p1;
    __syncthreads();
    for (int i = rb + t; i < re; i += 256) {
        unsigned r = ebuf[i];
        int pos = atomicAdd(&cur[r & (BW - 1)], 1);
        col[pos] = (int)(r >> BSH);
    }
    if (b == 0 && t == 0) rowptr[n] = E;
}

__global__ __launch_bounds__(256) void csr_hist2(const int* dp, int Ep_, int chp, int* bcp,
                                                 const int* dd, int Ed_, int chd, int* bcd) {
    int b = blockIdx.x;
    if (b < NCB) hist_body(b, dp, Ep_, chp, bcp);
    else         hist_body(b - NCB, dd, Ed_, chd, bcd);
}

__global__ __launch_bounds__(256) void csr_scan2(int* bcp, int* bbp, int* bcd, int* bbd) {
    if (blockIdx.x == 0) scan_body(bcp, bbp);
    else                 scan_body(bcd, bbd);
}

__global__ __launch_bounds__(256) void csr_place2(const int* sp, const int* dp, int Ep_, int chp,
                                                  const int* bcp, const int* bbp, unsigned* ebp,
                                                  const int* sd, const int* dd, int Ed_, int chd,
                                                  const int* bcd, const int* bbd, unsigned* ebd) {
    int b = blockIdx.x;
    if (b < NCB) place_body(b, sp, dp, Ep_, chp, bcp, bbp, ebp);
    else         place_body(b - NCB, sd, dd, Ed_, chd, bcd, bbd, ebd);
}

__global__ __launch_bounds__(256) void csr_finish2(const unsigned* ebp, const int* bbp, int np_,
                                                   int Ep_, int* rpp, float* dvp, int* clp, int nbkp,
                                                   const unsigned* ebd, const int* bbd, int nd_,
                                                   int Ed_, int* rpd, float* dvd, int* cld) {
    int b = blockIdx.x;
    if (b < nbkp) finish_body(b, ebp, bbp, np_, Ep_, rpp, dvp, clp);
    else          finish_body(b - nbkp, ebd, bbd, nd_, Ed_, rpd, dvd, cld);
}

// ---- x@W via MFMA f16; out = fp8( dinv[row] * (x@W) ), rows 128B ------------
template <int K, bool IN16>
static __device__ __forceinline__ void xw_body(_Float16* __restrict__ Wt,
                                               unsigned char* __restrict__ T8, int bid,
                                               const void* __restrict__ xv,
                                               const float* __restrict__ W,
                                               const float* __restrict__ dinv,
                                               uint4* __restrict__ out8, int n) {
    constexpr int CH = K / 8;
    constexpr int KS = K / 32;
    const int tid = threadIdx.x;

    for (int i = tid; i < 128 * CH; i += 256) {
        const int col = i / CH, ch = i % CH;
        f16x8 v;
        #pragma unroll
        for (int j = 0; j < 8; ++j) v[j] = (_Float16)W[(ch * 8 + j) * 128 + col];
        *(f16x8*)&Wt[(col * CH + (ch ^ (col & (CH - 1)))) * 8] = v;
    }
    __syncthreads();

    const int wv = tid >> 6, ln = tid & 63;
    const int r0 = bid * 64 + wv * 16;
    const int row = r0 + (ln & 15);
    const int kg = (ln >> 4) * 8;

    f16x8 a[KS];
    if (row < n) {
        if constexpr (IN16) {
            const unsigned short* xr = (const unsigned short*)xv + (size_t)row * K;
            #pragma unroll
            for (int ks = 0; ks < KS; ++ks)
                a[ks] = *(const f16x8*)&xr[ks * 32 + kg];
        } else {
            const float* xr = (const float*)xv + (size_t)row * K;
            #pragma unroll
            for (int ks = 0; ks < KS; ++ks) {
                float4 u0 = *(const float4*)&xr[ks * 32 + kg];
                float4 u1 = *(const float4*)&xr[ks * 32 + kg + 4];
                f16x8 v;
                v[0] = (_Float16)u0.x; v[1] = (_Float16)u0.y;
                v[2] = (_Float16)u0.z; v[3] = (_Float16)u0.w;
                v[4] = (_Float16)u1.x; v[5] = (_Float16)u1.y;
                v[6] = (_Float16)u1.z; v[7] = (_Float16)u1.w;
                a[ks] = v;
            }
        }
    } else {
        #pragma unroll
        for (int ks = 0; ks < KS; ++ks) {
            f16x8 v;
            #pragma unroll
            for (int j = 0; j < 8; ++j) v[j] = (_Float16)0.f;
            a[ks] = v;
        }
    }

    const int rw0l = wv * 16 + (ln >> 4) * 4;   // local row of lane's 4 outputs
    float dv[4];
    #pragma unroll
    for (int r = 0; r < 4; ++r) dv[r] = (bid * 64 + rw0l + r < n) ? dinv[bid * 64 + rw0l + r] : 0.f;

    const int cl = ln & 15;
    #pragma unroll
    for (int nt = 0; nt < 8; ++nt) {
        const int col = nt * 16 + cl;
        f32x4 c = {0.f, 0.f, 0.f, 0.f};
        #pragma unroll
        for (int ks = 0; ks < KS; ++ks) {
            const int ch = ks * 4 + (ln >> 4);
            f16x8 b = *(const f16x8*)&Wt[(col * CH + (ch ^ (col & (CH - 1)))) * 8];
            c = __builtin_amdgcn_mfma_f32_16x16x32_f16(a[ks], b, c, 0, 0, 0);
        }
        #pragma unroll
        for (int r = 0; r < 4; ++r) {
            int q = __builtin_amdgcn_cvt_pk_fp8_f32(c[r] * dv[r], 0.f, 0, false);
            T8[(rw0l + r) * 128 + col] = (unsigned char)q;
        }
    }
    __syncthreads();
    // bulk store: 64 rows x 128B = 512 uint4
    for (int i = tid; i < 512; i += 256) {
        const int lr = i >> 3, ch = i & 7;
        const int rr = bid * 64 + lr;
        if (rr < n) out8[(size_t)rr * 8 + ch] = *(const uint4*)&T8[lr * 128 + ch * 16];
    }
    __syncthreads();
}

__global__ __launch_bounds__(256) void xw1_fused(const float* xp, const float* Wp,
                                                 const float* dvp, uint4* op, int np_, int nbp,
                                                 const float* xd, const float* Wd,
                                                 const float* dvd, uint4* od, int nd_) {
    __shared__ _Float16 Wt[128 * 128];
    __shared__ unsigned char T8[64 * 128];
    int b = blockIdx.x;
    if (b < nbp) xw_body<128, false>(Wt, T8, b, xp, Wp, dvp, op, np_);
    else         xw_body<64,  false>(Wt, T8, b - nbp, xd, Wd, dvd, od, nd_);
}

__global__ __launch_bounds__(256) void xw2_fused(const unsigned short* xp, const float* Wp,
                                                 const float* dvp, uint4* op, int np_, int nbp,
                                                 const unsigned short* xd, const float* Wd,
                                                 const float* dvd, uint4* od, int nd_) {
    __shared__ _Float16 Wt[128 * 128];
    __shared__ unsigned char T8[64 * 128];
    int b = blockIdx.x;
    if (b < nbp) xw_body<128, true>(Wt, T8, b, xp, Wp, dvp, op, np_);
    else         xw_body<128, true>(Wt, T8, b - nbp, xd, Wd, dvd, od, nd_);
}

// ---- aggregation: one wave per node, quad-edge fp8 gather, packed f32 acc ---
// tab row = 128B fp8 = 16 uint2. lane = (group g = ln>>4, chunk c = ln&15).
static __device__ __forceinline__ void agg_body(int bid, const uint2* __restrict__ tab,
                                                const int* __restrict__ rowptr,
                                                const int* __restrict__ col,
                                                const float* __restrict__ dinv,
                                                const float* __restrict__ bias,
                                                uint4* __restrict__ out, int n) {
    const int wv = threadIdx.x >> 6, ln = threadIdx.x & 63;
    const int d = bid * 4 + wv;
    if (d >= n) return;
    const int g = ln >> 4;
    const int c = ln & 15;
    const int beg = rowptr[d], end = rowptr[d + 1];

    f32x2 a[4], b[4];
    #pragma unroll
    for (int i = 0; i < 4; ++i) { a[i] = (f32x2){0.f, 0.f}; b[i] = (f32x2){0.f, 0.f}; }
    if (g == 0) {                       // self-loop term
        uint2 v = tab[(size_t)d * 16 + c];
        acc8v(a, v.x, v.y);
    }

    int j = beg;
    for (; j + 8 <= end; j += 8) {      // 8 edges per iteration
        int s0 = col[j + g];
        int s1 = col[j + 4 + g];
        uint2 v0 = tab[(size_t)s0 * 16 + c];
        uint2 v1 = tab[(size_t)s1 * 16 + c];
        acc8v(a, v0.x, v0.y);
        acc8v(b, v1.x, v1.y);
    }
    for (; j < end; j += 4) {           // tail quads (predicated)
        int jj = j + g;
        int s = col[min(jj, end - 1)];
        uint2 v = tab[(size_t)s * 16 + c];
        if (jj < end) acc8v(b, v.x, v.y);
    }
    #pragma unroll
    for (int i = 0; i < 4; ++i) a[i] += b[i];

    float r[8];
    #pragma unroll
    for (int i = 0; i < 4; ++i) { r[2 * i] = a[i][0]; r[2 * i + 1] = a[i][1]; }
    #pragma unroll
    for (int i = 0; i < 8; ++i) r[i] += __shfl_xor(r[i], 16);
    #pragma unroll
    for (int i = 0; i < 8; ++i) r[i] += __shfl_xor(r[i], 32);

    if (g == 0) {
        const float dv = dinv[d];
        const float* bp = &bias[c * 8];
        uint4 o;
        o.x = (unsigned)f2h(fmaxf(fmaf(dv, r[0], bp[0]), 0.f))
            | ((unsigned)f2h(fmaxf(fmaf(dv, r[1], bp[1]), 0.f)) << 16);
        o.y = (unsigned)f2h(fmaxf(fmaf(dv, r[2], bp[2]), 0.f))
            | ((unsigned)f2h(fmaxf(fmaf(dv, r[3], bp[3]), 0.f)) << 16);
        o.z = (unsigned)f2h(fmaxf(fmaf(dv, r[4], bp[4]), 0.f))
            | ((unsigned)f2h(fmaxf(fmaf(dv, r[5], bp[5]), 0.f)) << 16);
        o.w = (unsigned)f2h(fmaxf(fmaf(dv, r[6], bp[6]), 0.f))
            | ((unsigned)f2h(fmaxf(fmaf(dv, r[7], bp[7]), 0.f)) << 16);
        out[(size_t)d * 16 + c] = o;
    }
}

__global__ __launch_bounds__(256) void agg_fused(const uint2* tp, const int* rpp, const int* clp,
                                                 const float* dvp, const float* bp, uint4* op,
                                                 int np_, int nwbp,
                                                 const uint2* td, const int* rpd, const int* cld,
                                                 const float* dvd, const float* bd, uint4* od,
                                                 int nd_) {
    int b = blockIdx.x;
    if (b < nwbp) agg_body(b, tp, rpp, clp, dvp, bp, op, np_);
    else          agg_body(b - nwbp, td, rpd, cld, dvd, bd, od, nd_);
}

// ---- mean over rows (f16 input) + seq MLP l1, merged ------------------------
static __device__ __forceinline__ void meanp_body(int bid, const uint4* __restrict__ h, int n,
                                                  int nblk, float* __restrict__ partial) {
    const int t = threadIdx.x;
    const int c = t & 15;
    const int rl = t >> 4;
    const int rpb = (n + nblk - 1) / nblk;
    const int r0 = bid * rpb, r1 = min(n, r0 + rpb);
    float acc[8] = {0.f, 0.f, 0.f, 0.f, 0.f, 0.f, 0.f, 0.f};
    for (int r = r0 + rl; r < r1; r += 16) {
        uint4 v = h[(size_t)r * 16 + c];
        f16x2 p;
        p = u2h(v.x); acc[0] += (float)p[0]; acc[1] += (float)p[1];
        p = u2h(v.y); acc[2] += (float)p[0]; acc[3] += (float)p[1];
        p = u2h(v.z); acc[4] += (float)p[0]; acc[5] += (float)p[1];
        p = u2h(v.w); acc[6] += (float)p[0]; acc[7] += (float)p[1];
    }
    __shared__ float sh[16][128];
    #pragma unroll
    for (int k = 0; k < 8; ++k) sh[rl][c * 8 + k] = acc[k];
    __syncthreads();
    if (t < 128) {
        float s = 0.f;
        #pragma unroll
        for (int i = 0; i < 16; ++i) s += sh[i][t];
        partial[(size_t)bid * 128 + t] = s;
    }
}

static __device__ __forceinline__ void l1_body(int bid, const float* __restrict__ in,
                                               const float* __restrict__ w1, int IN,
                                               float* __restrict__ partial) {
    const int t = threadIdx.x;
    const int f = t & 127;
    const int half = t >> 7;
    const int kpb = IN / MLP_NB;
    const int k0 = bid * kpb;
    float acc = 0.f;
    #pragma unroll 4
    for (int k = k0 + half; k < k0 + kpb; k += 2)
        acc = fmaf(in[k], w1[(size_t)k * 128 + f], acc);
    __shared__ float sh2[256];
    sh2[t] = acc; __syncthreads();
    if (half == 0) partial[bid * 128 + f] = sh2[f] + sh2[128 + f];
}

__global__ __launch_bounds__(256) void meansq_fused(const uint4* hp, int np_, float* pp,
                                                    const uint4* hd, int nd_, float* pd,
                                                    const float* inp, const float* w1p, int INp,
                                                    float* mp,
                                                    const float* ind, const float* w1d, int INd,
                                                    float* md) {
    int b = blockIdx.x;
    if      (b < MPP)                 meanp_body(b, hp, np_, MPP, pp);
    else if (b < MPP + MPD)           meanp_body(b - MPP, hd, nd_, MPD, pd);
    else if (b < MPP + MPD + MLP_NB)  l1_body(b - MPP - MPD, inp, w1p, INp, mp);
    else                              l1_body(b - MPP - MPD - MLP_NB, ind, w1d, INd, md);
}

// ---- mean finish + seq finish -----------------------------------------------
static __device__ __forceinline__ void meanf_body(const float* __restrict__ partial, int nrows,
                                                  float inv_n, float* __restrict__ out) {
    const int t = threadIdx.x;
    const int c4 = (t & 31) * 4;
    float4 acc = make_float4(0.f, 0.f, 0.f, 0.f);
    for (int r = (t >> 5); r < nrows; r += 8) {
        float4 v = *(const float4*)&partial[(size_t)r * 128 + c4];
        acc.x += v.x; acc.y += v.y; acc.z += v.z; acc.w += v.w;
    }
    __shared__ float4 sh[256];
    sh[t] = acc; __syncthreads();
    for (int off = 128; off >= 32; off >>= 1) {
        if (t < off) {
            float4 a = sh[t], o = sh[t + off];
            a.x += o.x; a.y += o.y; a.z += o.z; a.w += o.w;
            sh[t] = a;
        }
        __syncthreads();
    }
    if (t < 32) {
        float4 a = sh[t];
        a.x *= inv_n; a.y *= inv_n; a.z *= inv_n; a.w *= inv_n;
        *(float4*)&out[c4] = a;
    }
}

static __device__ __forceinline__ void seqfin_body(const float* __restrict__ partial,
                                                   const float* __restrict__ b1,
                                                   const float* __restrict__ w2,
                                                   const float* __restrict__ b2,
                                                   float* __restrict__ out) {
    const int t = threadIdx.x;          // 256; only t<128 active around syncs
    __shared__ float h[128];
    if (t < 128) {
        float s = 0.f;
        #pragma unroll 8
        for (int i = 0; i < MLP_NB; ++i) s += partial[i * 128 + t];
        h[t] = fmaxf(s + b1[t], 0.f);
    }
    __syncthreads();
    if (t < 128) {
        float acc = 0.f;
        #pragma unroll 8
        for (int k = 0; k < 128; ++k) acc = fmaf(h[k], w2[k * 128 + t], acc);
        out[t] = fmaxf(acc + b2[t], 0.f);
    }
}

__global__ __launch_bounds__(256) void finish_fused(const float* pp, float invp, float* omp,
                                                    const float* pd, float invd, float* omd,
                                                    const float* sp, const float* b1p,
                                                    const float* w2p, const float* b2p, float* osp,
                                                    const float* sd, const float* b1d,
                                                    const float* w2d, const float* b2d, float* osd) {
    const int b = blockIdx.x;
    if      (b == 0) meanf_body(pp, MPP, invp, omp);
    else if (b == 1) meanf_body(pd, MPD, invd, omd);
    else if (b == 2) seqfin_body(sp, b1p, w2p, b2p, osp);
    else             seqfin_body(sd, b1d, w2d, b2d, osd);
}

// ---- head: one block, both layers -------------------------------------------
__global__ __launch_bounds__(256) void head_one(const float* pm, const float* dm,
                                                const float* ps, const float* ds2,
                                                const float* fc1w, const float* fc1b,
                                                const float* fc2w, const float* fc2b,
                                                float* out) {
    const int t = threadIdx.x;          // 256
    __shared__ float comb[512];
    if (t < 128) {
        comb[t] = pm[t]; comb[128 + t] = dm[t];
        comb[256 + t] = ps[t]; comb[384 + t] = ds2[t];
    }
    __syncthreads();
    const int f = t & 127, half = t >> 7;
    float acc = 0.f;
    const int kb = half * 256;
    #pragma unroll 8
    for (int k = kb; k < kb + 256; ++k)
        acc = fmaf(comb[k], fc1w[(size_t)k * 128 + f], acc);
    __shared__ float hs[256];
    hs[t] = acc; __syncthreads();
    __shared__ float red[128];
    if (t < 128) {
        float h = fmaxf(hs[t] + hs[128 + t] + fc1b[t], 0.f);
        red[t] = h * fc2w[t];
    }
    __syncthreads();
    for (int off = 64; off > 0; off >>= 1) {
        if (t < off) red[t] += red[t + off];
        __syncthreads();
    }
    if (t == 0) out[0] = red[0] + fc2b[0];
}

static inline size_t align_up(size_t x, size_t a) { return (x + a - 1) / a * a; }

extern "C" void kernel_launch(void* const* d_in, const int* in_sizes, int n_in,
                              void* d_out, int out_size, void* d_ws, size_t ws_size,
                              hipStream_t stream) {
    const float* px   = (const float*)d_in[0];
    const int*   pei  = (const int*)d_in[1];
    const float* dx   = (const float*)d_in[2];
    const int*   dei  = (const int*)d_in[3];
    const float* pseq = (const float*)d_in[4];
    const float* dseq = (const float*)d_in[5];
    const float* pc1w = (const float*)d_in[6];  const float* pc1b = (const float*)d_in[7];
    const float* pc2w = (const float*)d_in[8];  const float* pc2b = (const float*)d_in[9];
    const float* dc1w = (const float*)d_in[10]; const float* dc1b = (const float*)d_in[11];
    const float* dc2w = (const float*)d_in[12]; const float* dc2b = (const float*)d_in[13];
    const float* psw1 = (const float*)d_in[14]; const float* psb1 = (const float*)d_in[15];
    const float* psw2 = (const float*)d_in[16]; const float* psb2 = (const float*)d_in[17];
    const float* dsw1 = (const float*)d_in[18]; const float* dsb1 = (const float*)d_in[19];
    const float* dsw2 = (const float*)d_in[20]; const float* dsb2 = (const float*)d_in[21];
    const float* fc1w = (const float*)d_in[22]; const float* fc1b = (const float*)d_in[23];
    const float* fc2w = (const float*)d_in[24]; const float* fc2b = (const float*)d_in[25];

    const int Np = in_sizes[0] / 128, Ep = in_sizes[1] / 2;
    const int Nd = in_sizes[2] / 64,  Ed = in_sizes[3] / 2;
    const int Psd = in_sizes[4], Dsd = in_sizes[5];

    char* w = (char*)d_ws;
    size_t off = 0;
    auto carve = [&](size_t bytes) -> void* {
        void* p = w + off;
        off = align_up(off + bytes, 256);
        return p;
    };
    unsigned char* tab_p  = (unsigned char*)carve((size_t)Np * 128);      // fp8 msg table
    unsigned short* buf_p = (unsigned short*)carve((size_t)Np * 128 * 2); // f16 hidden
    unsigned char* tab_d  = (unsigned char*)carve((size_t)Nd * 128);
    unsigned short* buf_d = (unsigned short*)carve((size_t)Nd * 128 * 2);
    int*      col_p  = (int*)carve((size_t)Ep * 4);
    unsigned* ebuf_p = (unsigned*)carve((size_t)Ep * 4);
    int*      col_d  = (int*)carve((size_t)Ed * 4);
    unsigned* ebuf_d = (unsigned*)carve((size_t)Ed * 4);
    int*   bcnt_p   = (int*)carve((size_t)NCB * 256 * 4);
    int*   bcnt_d   = (int*)carve((size_t)NCB * 256 * 4);
    int*   bbase_p  = (int*)carve(257 * 4);
    int*   bbase_d  = (int*)carve(257 * 4);
    int*   rowptr_p = (int*)carve(((size_t)Np + 1) * 4);
    int*   rowptr_d = (int*)carve(((size_t)Nd + 1) * 4);
    float* dinv_p   = (float*)carve((size_t)Np * 4);
    float* dinv_d   = (float*)carve((size_t)Nd * 4);
    float* part_p   = (float*)carve((size_t)MPP * 128 * 4);
    float* part_d   = (float*)carve((size_t)MPD * 128 * 4);
    float* mlpp_p   = (float*)carve((size_t)MLP_NB * 128 * 4);
    float* mlpp_d   = (float*)carve((size_t)MLP_NB * 128 * 4);
    float* pmean    = (float*)carve(512);
    float* dmean    = (float*)carve(512);
    float* pseqo    = (float*)carve(512);
    float* dseqo    = (float*)carve(512);
    (void)ws_size; (void)n_in; (void)out_size;

    const int* psrc = pei; const int* pdst = pei + Ep;
    const int* dsrc = dei; const int* ddst = dei + Ed;
    const int chp = (((Ep + NCB - 1) / NCB) + 255) & ~255;
    const int chd = (((Ed + NCB - 1) / NCB) + 255) & ~255;
    const int nbkp = (Np + BW - 1) >> BSH, nbkd = (Nd + BW - 1) >> BSH;
    const int nbp = (Np + 63) / 64, nbd = (Nd + 63) / 64;
    const int nwbp = (Np + 3) / 4, nwbd = (Nd + 3) / 4;

    // CSR build (both graphs per dispatch)
    csr_hist2 <<<2 * NCB, 256, 0, stream>>>(pdst, Ep, chp, bcnt_p, ddst, Ed, chd, bcnt_d);
    csr_scan2 <<<2, 256, 0, stream>>>(bcnt_p, bbase_p, bcnt_d, bbase_d);
    csr_place2<<<2 * NCB, 256, 0, stream>>>(psrc, pdst, Ep, chp, bcnt_p, bbase_p, ebuf_p,
                                            dsrc, ddst, Ed, chd, bcnt_d, bbase_d, ebuf_d);
    csr_finish2<<<nbkp + nbkd, 256, 0, stream>>>(ebuf_p, bbase_p, Np, Ep, rowptr_p, dinv_p, col_p,
                                                 nbkp, ebuf_d, bbase_d, Nd, Ed, rowptr_d, dinv_d,
                                                 col_d);

    // conv1
    xw1_fused<<<nbp + nbd, 256, 0, stream>>>(px, pc1w, dinv_p, (uint4*)tab_p, Np, nbp,
                                             dx, dc1w, dinv_d, (uint4*)tab_d, Nd);
    agg_fused<<<nwbp + nwbd, 256, 0, stream>>>((const uint2*)tab_p, rowptr_p, col_p, dinv_p, pc1b,
                                               (uint4*)buf_p, Np, nwbp,
                                               (const uint2*)tab_d, rowptr_d, col_d, dinv_d, dc1b,
                                               (uint4*)buf_d, Nd);
    // conv2
    xw2_fused<<<nbp + nbd, 256, 0, stream>>>(buf_p, pc2w, dinv_p, (uint4*)tab_p, Np, nbp,
                                             buf_d, dc2w, dinv_d, (uint4*)tab_d, Nd);
    agg_fused<<<nwbp + nwbd, 256, 0, stream>>>((const uint2*)tab_p, rowptr_p, col_p, dinv_p, pc2b,
                                               (uint4*)buf_p, Np, nwbp,
                                               (const uint2*)tab_d, rowptr_d, col_d, dinv_d, dc2b,
                                               (uint4*)buf_d, Nd);
    // means + seq MLP layer 1 (one dispatch)
    meansq_fused<<<MPP + MPD + 2 * MLP_NB, 256, 0, stream>>>(
        (const uint4*)buf_p, Np, part_p, (const uint4*)buf_d, Nd, part_d,
        pseq, psw1, Psd, mlpp_p, dseq, dsw1, Dsd, mlpp_d);
    // mean finish + seq finish (one dispatch)
    finish_fused<<<4, 256, 0, stream>>>(part_p, 1.0f / (float)Np, pmean,
                                        part_d, 1.0f / (float)Nd, dmean,
                                        mlpp_p, psb1, psw2, psb2, pseqo,
                                        mlpp_d, dsb1, dsw2, dsb2, dseqo);
    // head (single block, both layers)
    head_one<<<1, 256, 0, stream>>>(pmean, dmean, pseqo, dseqo, fc1w, fc1b, fc2w, fc2b,
                                    (float*)d_out);
}